// Round 7
// baseline (392.933 us; speedup 1.0000x reference)
//
#include <hip/hip_runtime.h>
#include <hip/hip_bf16.h>
#include <cstdint>

// Problem constants (B=2,S=1024,D=1024; L=2,E=8,F=2048; k=2)
#define T_TOKENS 2048
#define DDIM 1024
#define FDIM 2048
#define NEXP 8
#define NLAYER 2
#define BMPAD 64           // per-expert row padding granularity
#define RMAX 4608          // 2048*2 + 8*63 = 4537 -> 64-multiple
#define RALLOC 4736        // +128 slack rows: 128-row M-tiles may overhang

// A-operand tiles: 64 rows x 32 k, 2048 el (4 KB), order ((ksel*64+row)*8 + (k&7)),
//   ksel=(k>>3)&3 -- exactly MFMA fragment order for 16x16x32 bf16.
// B-operand tiles: 128 cols x 32 k, 4096 el (8 KB), order ((ksel*128+col)*8 + (k&7)).
// A linear LDS copy of a tile is fragment-readable conflict-free (b128, 16B x 16 lanes).
#define ATILE_EL 2048
#define BTILE_EL 4096

typedef unsigned short u16;
typedef short bf16x8 __attribute__((ext_vector_type(8)));
typedef u16 u16x8 __attribute__((ext_vector_type(8)));
typedef u16 u16x4v __attribute__((ext_vector_type(4)));
typedef float f32x4 __attribute__((ext_vector_type(4)));

__device__ __forceinline__ u16 bf16_rn(float f) {
  unsigned u = __builtin_bit_cast(unsigned, f);
  u += 0x7fffu + ((u >> 16) & 1u);
  return (u16)(u >> 16);
}
__device__ __forceinline__ float bf16_f(u16 h) {
  unsigned u = ((unsigned)h) << 16;
  return __builtin_bit_cast(float, u);
}

__device__ __forceinline__ void gl16(const void* g, void* l) {
  __builtin_amdgcn_global_load_lds((const __attribute__((address_space(1))) void*)g,
                                   (__attribute__((address_space(3))) void*)l, 16, 0, 0);
}

// ---------------- routing ----------------
__global__ __launch_bounds__(256) void route_kernel(
    const float* __restrict__ x, const float* __restrict__ protos,
    int* __restrict__ eid, float* __restrict__ wgt) {
  const int t = blockIdx.x;
  const int tid = threadIdx.x;
  const float* xr = x + (size_t)t * DDIM;
  __shared__ float red[NEXP][256];
  float acc[NEXP];
#pragma unroll
  for (int e = 0; e < NEXP; ++e) acc[e] = 0.f;
  for (int d = tid; d < DDIM; d += 256) {
    float xv = xr[d];
#pragma unroll
    for (int e = 0; e < NEXP; ++e) acc[e] += xv * protos[e * DDIM + d];
  }
#pragma unroll
  for (int e = 0; e < NEXP; ++e) red[e][tid] = acc[e];
  __syncthreads();
  for (int s = 128; s > 0; s >>= 1) {
    if (tid < s) {
#pragma unroll
      for (int e = 0; e < NEXP; ++e) red[e][tid] += red[e][tid + s];
    }
    __syncthreads();
  }
  if (tid == 0) {
    float m1 = -1.f, m2 = -1.f;
    int i1 = 0, i2 = 0;
#pragma unroll
    for (int e = 0; e < NEXP; ++e) {
      float s = fabsf(red[e][0]);
      if (s > m1) { m2 = m1; i2 = i1; m1 = s; i1 = e; }
      else if (s > m2) { m2 = s; i2 = e; }
    }
    float e2 = __expf(m2 - m1);
    float z = 1.f + e2;
    eid[t * 2] = i1;
    eid[t * 2 + 1] = i2;
    wgt[t * 2] = 1.f / z;
    wgt[t * 2 + 1] = e2 / z;
  }
}

// ------------- compaction (padded to 64) -------------
__global__ __launch_bounds__(256) void compact_kernel(
    const int* __restrict__ eid, int* __restrict__ cnt, int* __restrict__ offp,
    int* __restrict__ row2token, int* __restrict__ pos) {
  __shared__ int lcnt[NEXP][256];
  __shared__ int s_off[NEXP], s_tot[NEXP];
  const int tid = threadIdx.x;
  const int base = tid * 16;

  int my[16];
#pragma unroll
  for (int i = 0; i < 4; ++i)
    *(int4*)&my[i * 4] = *(const int4*)(eid + base + i * 4);

#pragma unroll
  for (int e = 0; e < NEXP; ++e) {
    int c = 0;
#pragma unroll
    for (int i = 0; i < 16; ++i) c += (my[i] == e) ? 1 : 0;
    lcnt[e][tid] = c;
  }

  for (int r = tid; r < RMAX; r += 256) row2token[r] = -1;
  __syncthreads();

  if (tid < NEXP) {
    int run = 0;
    for (int i = 0; i < 256; ++i) {
      int v = lcnt[tid][i];
      lcnt[tid][i] = run;
      run += v;
    }
    s_tot[tid] = run;
  }
  __syncthreads();
  if (tid == 0) {
    int o = 0;
    for (int e = 0; e < NEXP; ++e) {
      s_off[e] = o;
      o += (s_tot[e] + BMPAD - 1) & ~(BMPAD - 1);
    }
  }
  __syncthreads();

  int myoff[NEXP];
#pragma unroll
  for (int e = 0; e < NEXP; ++e) myoff[e] = s_off[e] + lcnt[e][tid];
#pragma unroll
  for (int i = 0; i < 16; ++i) {
    int r = 0;
#pragma unroll
    for (int e = 0; e < NEXP; ++e) r = (my[i] == e) ? myoff[e] : r;
    row2token[r] = (base + i) >> 1;
    pos[base + i] = r;
#pragma unroll
    for (int e = 0; e < NEXP; ++e) myoff[e] += (my[i] == e) ? 1 : 0;
  }

  if (tid < NEXP) {
    cnt[tid] = s_tot[tid];
    offp[tid] = s_off[tid];
  }
}

// ------------- gather x rows -> bf16 hi/lo A-tiled buffers -------------
__global__ __launch_bounds__(256) void gather_kernel(
    const float* __restrict__ x, const int* __restrict__ row2token,
    u16* __restrict__ Ahi, u16* __restrict__ Alo) {
  const int r = blockIdx.x;
  const int t = row2token[r];
  const int c = threadIdx.x * 4;
  float4 v = make_float4(0.f, 0.f, 0.f, 0.f);
  if (t >= 0) v = *(const float4*)(x + (size_t)t * DDIM + c);
  float vv[4] = {v.x, v.y, v.z, v.w};
  u16x4v hi, lo;
#pragma unroll
  for (int i = 0; i < 4; ++i) {
    u16 h = bf16_rn(vv[i]);
    hi[i] = h;
    lo[i] = bf16_rn(vv[i] - bf16_f(h));
  }
  const size_t el = ((size_t)(r >> 6) * (DDIM >> 5) + (c >> 5)) * ATILE_EL +
                    (size_t)(((c >> 3) & 3) * 64 + (r & 63)) * 8 + (c & 7);
  *(u16x4v*)(Ahi + el) = hi;
  *(u16x4v*)(Alo + el) = lo;
}

// ------------- W convert: f32 [e][K][N] -> bf16 hi(/lo) B-tiled [e][N/128][K/32] -------------
template <bool LO>
__global__ __launch_bounds__(256) void wconv_kernel(
    const float* __restrict__ W, u16* __restrict__ Hi, u16* __restrict__ Lo,
    int K, int N) {
  const int e = blockIdx.z, nb = blockIdx.x, kb = blockIdx.y;
  const float* Wp = W + ((size_t)e * K + (size_t)kb * 32) * N + nb * 128;
  __shared__ float tile[32][129];
  const int t = threadIdx.x;
#pragma unroll
  for (int i = 0; i < 4; ++i) {
    const int f4 = i * 256 + t;        // 1024 float4 = 32 rows x 32 f4
    const int kr = f4 >> 5;
    const int c4 = (f4 & 31) * 4;
    float4 v = *(const float4*)(Wp + (size_t)kr * N + c4);
    *(float4*)&tile[kr][c4] = v;
  }
  __syncthreads();
  const size_t tb = (((size_t)e * (N >> 7) + nb) * (K >> 5) + kb) * BTILE_EL;
#pragma unroll
  for (int j = 0; j < 2; ++j) {
    const int cid = j * 256 + t;       // 512 chunks of 8
    const int n = cid & 127, ksel = cid >> 7;
    u16x8 hv, lv;
#pragma unroll
    for (int i = 0; i < 8; ++i) {
      float f = tile[ksel * 8 + i][n];
      u16 h = bf16_rn(f);
      hv[i] = h;
      if (LO) lv[i] = bf16_rn(f - bf16_f(h));
    }
    *(u16x8*)(Hi + tb + (size_t)cid * 8) = hv;
    if (LO) *(u16x8*)(Lo + tb + (size_t)cid * 8) = lv;
  }
}

// ------------- grouped MFMA GEMM: 128x128 block, 64x64 waves, BK=32, dbuf -------------
// SPLIT: per staged tile, Ah*Bh + Ah*Bl + Al*Bh (48 MFMA / 16 ds_reads per wave-iter).
// OUTMODE 0: f32 partial [sk][RALLOC][N]; 1: bf16 hi+lo A-tiled; 2: bf16 hi A-tiled.
// SKF: split-K factor, blockIdx.z = e*SKF + sk.
template <bool RELU, bool SPLIT, int OUTMODE, int SKF>
__global__ __launch_bounds__(256, SPLIT ? 2 : 4) void gemm_mfma(
    const u16* __restrict__ Ahi, const u16* __restrict__ Alo,
    const u16* __restrict__ Bhi, const u16* __restrict__ Blo,
    u16* __restrict__ OutHi, u16* __restrict__ OutLo, float* __restrict__ OutF,
    const int* __restrict__ cnt, const int* __restrict__ offp, int K, int N) {
  const int z = blockIdx.z;
  const int e = z / SKF, sk = z % SKF;
  const int cp = (cnt[e] + 63) & ~63;
  if ((int)(blockIdx.y * 128) >= cp) return;
  const int row0 = offp[e] + blockIdx.y * 128;
  const int rend = offp[e] + cp;
  const int n0 = blockIdx.x * 128;
  const int nkb = K >> 5;
  const int kbN = nkb / SKF;
  const int kb0 = sk * kbN;

  constexpr int BUF_EL = SPLIT ? 16384 : 8192;  // 32 KB / 16 KB per buffer
  __shared__ u16 lds[2 * BUF_EL];

  const int tid = threadIdx.x;
  const int lane = tid & 63;
  const int wid = tid >> 6;
  const int wr = wid >> 1, wc = wid & 1;     // 2x2 waves, 64x64 each
  const int lr = lane & 15, kg = lane >> 4;
  const int lo16 = lane << 4;

  f32x4 acc[4][4];
#pragma unroll
  for (int i = 0; i < 4; ++i)
#pragma unroll
    for (int j = 0; j < 4; ++j)
#pragma unroll
      for (int r = 0; r < 4; ++r) acc[i][j][r] = 0.f;

  const int at0 = row0 >> 6;  // two consecutive A 64-row tiles per block
  const size_t bbase = ((size_t)e * (N >> 7) + (n0 >> 7)) * nkb;

  // staging: each wave owns one 8 KB quarter (SPLIT) / 4 KB quarter (plain)
  auto STAGE = [&](int kb, int b) {
    char* d = (char*)(lds + b * BUF_EL);
    if constexpr (SPLIT) {
      if (wid == 0) {
#pragma unroll
        for (int t = 0; t < 2; ++t) {
          const char* g = (const char*)(Ahi + ((size_t)(at0 + t) * nkb + kb) * ATILE_EL);
#pragma unroll
          for (int i = 0; i < 4; ++i) gl16(g + i * 1024 + lo16, d + t * 4096 + i * 1024);
        }
      } else if (wid == 1) {
#pragma unroll
        for (int t = 0; t < 2; ++t) {
          const char* g = (const char*)(Alo + ((size_t)(at0 + t) * nkb + kb) * ATILE_EL);
#pragma unroll
          for (int i = 0; i < 4; ++i) gl16(g + i * 1024 + lo16, d + 8192 + t * 4096 + i * 1024);
        }
      } else if (wid == 2) {
        const char* g = (const char*)(Bhi + (bbase + kb) * BTILE_EL);
#pragma unroll
        for (int i = 0; i < 8; ++i) gl16(g + i * 1024 + lo16, d + 16384 + i * 1024);
      } else {
        const char* g = (const char*)(Blo + (bbase + kb) * BTILE_EL);
#pragma unroll
        for (int i = 0; i < 8; ++i) gl16(g + i * 1024 + lo16, d + 24576 + i * 1024);
      }
    } else {
      if (wid < 2) {
        const char* g = (const char*)(Ahi + ((size_t)(at0 + wid) * nkb + kb) * ATILE_EL);
#pragma unroll
        for (int i = 0; i < 4; ++i) gl16(g + i * 1024 + lo16, d + wid * 4096 + i * 1024);
      } else {
        const char* g = (const char*)(Bhi + (bbase + kb) * BTILE_EL) + (wid - 2) * 4096;
#pragma unroll
        for (int i = 0; i < 4; ++i) gl16(g + i * 1024 + lo16, d + 8192 + (wid - 2) * 4096 + i * 1024);
      }
    }
  };

  STAGE(kb0, 0);
  __syncthreads();  // vmcnt(0): buf0 ready

  int cur = 0;
  for (int kb = kb0; kb < kb0 + kbN; ++kb) {
    if (kb + 1 < kb0 + kbN) STAGE(kb + 1, cur ^ 1);  // prefetch overlaps compute

    const u16* buf = lds + cur * BUF_EL;
    const u16* AsH = buf + wr * 2048;                    // this wave's 64-row A tile
    const u16* BsH = buf + (SPLIT ? 8192 : 4096);
    const int arow = (kg * 64 + lr) * 8;
    const int bcol = (kg * 128 + wc * 64 + lr) * 8;

    bf16x8 ah[4], bh[4];
#pragma unroll
    for (int i = 0; i < 4; ++i) ah[i] = *(const bf16x8*)&AsH[arow + i * 128];
#pragma unroll
    for (int j = 0; j < 4; ++j) bh[j] = *(const bf16x8*)&BsH[bcol + j * 128];
#pragma unroll
    for (int i = 0; i < 4; ++i)
#pragma unroll
      for (int j = 0; j < 4; ++j)
        acc[i][j] = __builtin_amdgcn_mfma_f32_16x16x32_bf16(ah[i], bh[j], acc[i][j], 0, 0, 0);

    if constexpr (SPLIT) {
      const u16* AsL = buf + 4096 + wr * 2048;
      const u16* BsL = buf + 12288;
      bf16x8 bl[4];
#pragma unroll
      for (int j = 0; j < 4; ++j) bl[j] = *(const bf16x8*)&BsL[bcol + j * 128];
#pragma unroll
      for (int i = 0; i < 4; ++i)
#pragma unroll
        for (int j = 0; j < 4; ++j)
          acc[i][j] = __builtin_amdgcn_mfma_f32_16x16x32_bf16(ah[i], bl[j], acc[i][j], 0, 0, 0);
      bf16x8 al[4];
#pragma unroll
      for (int i = 0; i < 4; ++i) al[i] = *(const bf16x8*)&AsL[arow + i * 128];
#pragma unroll
      for (int i = 0; i < 4; ++i)
#pragma unroll
        for (int j = 0; j < 4; ++j)
          acc[i][j] = __builtin_amdgcn_mfma_f32_16x16x32_bf16(al[i], bh[j], acc[i][j], 0, 0, 0);
    }
    __syncthreads();  // drains vmcnt(0) -> prefetch landed; all reads of buf done
    cur ^= 1;
  }

  // ---- epilogue: frag D: col=lr, row=kg*4+r; guard rows past expert end ----
  const int nkbO = N >> 5;
#pragma unroll
  for (int i = 0; i < 4; ++i) {
#pragma unroll
    for (int j = 0; j < 4; ++j) {
      const int Cj = n0 + wc * 64 + j * 16 + lr;
      f32x4 v = acc[i][j];
#pragma unroll
      for (int r = 0; r < 4; ++r) {
        const int R = row0 + wr * 64 + i * 16 + kg * 4 + r;
        if (R >= rend) continue;
        float f = v[r];
        if (RELU) f = fmaxf(f, 0.f);
        if constexpr (OUTMODE == 0) {
          OutF[((size_t)sk * RALLOC + R) * N + Cj] = f;
        } else {
          const size_t el = ((size_t)(R >> 6) * nkbO + (Cj >> 5)) * ATILE_EL +
                            (size_t)(((Cj >> 3) & 3) * 64 + (R & 63)) * 8 + (Cj & 7);
          u16 h = bf16_rn(f);
          OutHi[el] = h;
          if constexpr (OUTMODE == 1) OutLo[el] = bf16_rn(f - bf16_f(h));
        }
      }
    }
  }
}

// ------------- apply: x[t] += w0*(P0+P1)[pos0] + w1*(P0+P1)[pos1] -------------
__global__ __launch_bounds__(256) void apply_kernel(
    const float* __restrict__ part, const int* __restrict__ pos,
    const float* __restrict__ wgt, float* __restrict__ x) {
  const int t = blockIdx.x;
  const int c = threadIdx.x * 4;
  const int p0 = pos[t * 2], p1 = pos[t * 2 + 1];
  const float w0 = wgt[t * 2], w1 = wgt[t * 2 + 1];
  const float* P0 = part;
  const float* P1 = part + (size_t)RALLOC * DDIM;
  float4 xa = *(float4*)(x + (size_t)t * DDIM + c);
  const float4 a0 = *(const float4*)(P0 + (size_t)p0 * DDIM + c);
  const float4 b0 = *(const float4*)(P1 + (size_t)p0 * DDIM + c);
  const float4 a1 = *(const float4*)(P0 + (size_t)p1 * DDIM + c);
  const float4 b1 = *(const float4*)(P1 + (size_t)p1 * DDIM + c);
  xa.x += w0 * (a0.x + b0.x) + w1 * (a1.x + b1.x);
  xa.y += w0 * (a0.y + b0.y) + w1 * (a1.y + b1.y);
  xa.z += w0 * (a0.z + b0.z) + w1 * (a1.z + b1.z);
  xa.w += w0 * (a0.w + b0.w) + w1 * (a1.w + b1.w);
  *(float4*)(x + (size_t)t * DDIM + c) = xa;
}

extern "C" void kernel_launch(void* const* d_in, const int* in_sizes, int n_in,
                              void* d_out, int out_size, void* d_ws, size_t ws_size,
                              hipStream_t stream) {
  const float* x = (const float*)d_in[0];
  const float* protos = (const float*)d_in[1];
  const float* W1 = (const float*)d_in[2];
  const float* W2 = (const float*)d_in[3];
  float* xcur = (float*)d_out;

  // ws (~164 MB): W hi/lo 33.5 ea; Ag hi/lo 9.7 ea; h hi/lo 19.4 ea; part 38.8; meta
  u16* W_hi = (u16*)d_ws;
  u16* W_lo = W_hi + (size_t)NEXP * DDIM * FDIM;
  u16* Ag_hi = W_lo + (size_t)NEXP * DDIM * FDIM;
  u16* Ag_lo = Ag_hi + (size_t)RALLOC * DDIM;
  u16* h_hi = Ag_lo + (size_t)RALLOC * DDIM;
  u16* h_lo = h_hi + (size_t)RALLOC * FDIM;
  float* part = (float*)(h_lo + (size_t)RALLOC * FDIM);
  float* wgt = part + (size_t)2 * RALLOC * DDIM;
  int* eid = (int*)(wgt + T_TOKENS * 2);
  int* pos = eid + T_TOKENS * 2;
  int* cnt = pos + T_TOKENS * 2;
  int* offp = cnt + NEXP;
  int* row2token = offp + NEXP;

  hipMemcpyAsync(xcur, x, (size_t)T_TOKENS * DDIM * sizeof(float),
                 hipMemcpyDeviceToDevice, stream);

  for (int l = 0; l < NLAYER; ++l) {
    route_kernel<<<T_TOKENS, 256, 0, stream>>>(
        xcur, protos + (size_t)l * NEXP * DDIM, eid, wgt);
    compact_kernel<<<1, 256, 0, stream>>>(eid, cnt, offp, row2token, pos);
    gather_kernel<<<RMAX, 256, 0, stream>>>(xcur, row2token, Ag_hi, Ag_lo);
    const float* W1l = W1 + (size_t)l * NEXP * DDIM * FDIM;
    const float* W2l = W2 + (size_t)l * NEXP * FDIM * DDIM;
    if (l == 0) {
      // layer-1 output feeds layer-2 routing: fused-split (f32-grade) GEMMs
      wconv_kernel<true><<<dim3(FDIM / 128, DDIM / 32, NEXP), 256, 0, stream>>>(
          W1l, W_hi, W_lo, DDIM, FDIM);
      gemm_mfma<true, true, 1, 1><<<dim3(FDIM / 128, RMAX / 128, NEXP), 256, 0, stream>>>(
          Ag_hi, Ag_lo, W_hi, W_lo, h_hi, h_lo, nullptr, cnt, offp, DDIM, FDIM);
      wconv_kernel<true><<<dim3(DDIM / 128, FDIM / 32, NEXP), 256, 0, stream>>>(
          W2l, W_hi, W_lo, FDIM, DDIM);
      gemm_mfma<false, true, 0, 2><<<dim3(DDIM / 128, RMAX / 128, NEXP * 2), 256, 0, stream>>>(
          h_hi, h_lo, W_hi, W_lo, nullptr, nullptr, part, cnt, offp, FDIM, DDIM);
    } else {
      // layer-2 output only feeds the final check: plain bf16
      wconv_kernel<false><<<dim3(FDIM / 128, DDIM / 32, NEXP), 256, 0, stream>>>(
          W1l, W_hi, nullptr, DDIM, FDIM);
      gemm_mfma<true, false, 2, 1><<<dim3(FDIM / 128, RMAX / 128, NEXP), 256, 0, stream>>>(
          Ag_hi, nullptr, W_hi, nullptr, h_hi, nullptr, nullptr, cnt, offp, DDIM, FDIM);
      wconv_kernel<false><<<dim3(DDIM / 128, FDIM / 32, NEXP), 256, 0, stream>>>(
          W2l, W_hi, nullptr, FDIM, DDIM);
      gemm_mfma<false, false, 0, 2><<<dim3(DDIM / 128, RMAX / 128, NEXP * 2), 256, 0, stream>>>(
          h_hi, nullptr, W_hi, nullptr, nullptr, nullptr, part, cnt, offp, FDIM, DDIM);
    }
    apply_kernel<<<T_TOKENS, 256, 0, stream>>>(part, pos, wgt, xcur);
  }
}

// Round 8
// 371.826 us; speedup vs baseline: 1.0568x; 1.0568x over previous
//
#include <hip/hip_runtime.h>
#include <hip/hip_bf16.h>
#include <cstdint>

// Problem constants (B=2,S=1024,D=1024; L=2,E=8,F=2048; k=2)
#define T_TOKENS 2048
#define DDIM 1024
#define FDIM 2048
#define NEXP 8
#define NLAYER 2
#define BMPAD 64           // per-expert row padding granularity
#define RMAX 4608          // 2048*2 + 8*63 = 4537 -> 64-multiple
#define RALLOC 4736        // +128 slack rows (128-row M-tiles may overhang)

// A-operand tiles: 64 rows x 32 k, 2048 el (4 KB), order ((ksel*64+row)*8 + (k&7)),
//   ksel=(k>>3)&3 -- exactly MFMA fragment order for 16x16x32 bf16.
// B-operand tiles: 128 cols x 32 k, 4096 el (8 KB), order ((ksel*128+col)*8 + (k&7)).
// Linear LDS copy of a tile is fragment-readable conflict-free (b128, 16B x 16 lanes).
#define ATILE_EL 2048
#define BTILE_EL 4096

typedef unsigned short u16;
typedef short bf16x8 __attribute__((ext_vector_type(8)));
typedef u16 u16x8 __attribute__((ext_vector_type(8)));
typedef u16 u16x4v __attribute__((ext_vector_type(4)));
typedef float f32x4 __attribute__((ext_vector_type(4)));

__device__ __forceinline__ u16 bf16_rn(float f) {
  unsigned u = __builtin_bit_cast(unsigned, f);
  u += 0x7fffu + ((u >> 16) & 1u);
  return (u16)(u >> 16);
}
__device__ __forceinline__ float bf16_f(u16 h) {
  unsigned u = ((unsigned)h) << 16;
  return __builtin_bit_cast(float, u);
}

__device__ __forceinline__ void gl16(const void* g, void* l) {
  __builtin_amdgcn_global_load_lds((const __attribute__((address_space(1))) void*)g,
                                   (__attribute__((address_space(3))) void*)l, 16, 0, 0);
}

// XCD-aware bijective swizzle: nwg must be divisible by 8 (true for all our grids).
// Dispatch lin lands on XCD lin%8; remap so each XCD processes a CONTIGUOUS
// lexicographic chunk -> A-panel sharers (consecutive x) co-locate on one L2.
__device__ __forceinline__ void xcd_swizzle(int& bx, int& by, int& bz) {
  const unsigned gx = gridDim.x, gy = gridDim.y;
  const unsigned lin = blockIdx.x + gx * (blockIdx.y + gy * blockIdx.z);
  const unsigned nwg = gx * gy * gridDim.z;
  const unsigned nl = (lin & 7u) * (nwg >> 3) + (lin >> 3);
  bx = nl % gx;
  const unsigned t = nl / gx;
  by = t % gy;
  bz = t / gy;
}

// ---------------- routing ----------------
__global__ __launch_bounds__(256) void route_kernel(
    const float* __restrict__ x, const float* __restrict__ protos,
    int* __restrict__ eid, float* __restrict__ wgt) {
  const int t = blockIdx.x;
  const int tid = threadIdx.x;
  const float4* xr4 = (const float4*)(x + (size_t)t * DDIM);
  const float4* pr4 = (const float4*)protos;
  __shared__ float red[NEXP][256];
  const float4 xv = xr4[tid];
  float acc[NEXP];
#pragma unroll
  for (int e = 0; e < NEXP; ++e) {
    const float4 p = pr4[e * 256 + tid];
    acc[e] = xv.x * p.x + xv.y * p.y + xv.z * p.z + xv.w * p.w;
  }
#pragma unroll
  for (int e = 0; e < NEXP; ++e) red[e][tid] = acc[e];
  __syncthreads();
  for (int s = 128; s > 0; s >>= 1) {
    if (tid < s) {
#pragma unroll
      for (int e = 0; e < NEXP; ++e) red[e][tid] += red[e][tid + s];
    }
    __syncthreads();
  }
  if (tid == 0) {
    float m1 = -1.f, m2 = -1.f;
    int i1 = 0, i2 = 0;
#pragma unroll
    for (int e = 0; e < NEXP; ++e) {
      float s = fabsf(red[e][0]);
      if (s > m1) { m2 = m1; i2 = i1; m1 = s; i1 = e; }
      else if (s > m2) { m2 = s; i2 = e; }
    }
    float e2 = __expf(m2 - m1);
    float z = 1.f + e2;
    eid[t * 2] = i1;
    eid[t * 2 + 1] = i2;
    wgt[t * 2] = 1.f / z;
    wgt[t * 2 + 1] = e2 / z;
  }
}

// ------------- compaction (padded to 64) -------------
__global__ __launch_bounds__(256) void compact_kernel(
    const int* __restrict__ eid, int* __restrict__ cnt, int* __restrict__ offp,
    int* __restrict__ row2token, int* __restrict__ pos) {
  __shared__ int lcnt[NEXP][256];
  __shared__ int s_off[NEXP], s_tot[NEXP];
  const int tid = threadIdx.x;
  const int base = tid * 16;

  int my[16];
#pragma unroll
  for (int i = 0; i < 4; ++i)
    *(int4*)&my[i * 4] = *(const int4*)(eid + base + i * 4);

#pragma unroll
  for (int e = 0; e < NEXP; ++e) {
    int c = 0;
#pragma unroll
    for (int i = 0; i < 16; ++i) c += (my[i] == e) ? 1 : 0;
    lcnt[e][tid] = c;
  }

  for (int r = tid; r < RMAX; r += 256) row2token[r] = -1;
  __syncthreads();

  if (tid < NEXP) {
    int run = 0;
    for (int i = 0; i < 256; ++i) {
      int v = lcnt[tid][i];
      lcnt[tid][i] = run;
      run += v;
    }
    s_tot[tid] = run;
  }
  __syncthreads();
  if (tid == 0) {
    int o = 0;
    for (int e = 0; e < NEXP; ++e) {
      s_off[e] = o;
      o += (s_tot[e] + BMPAD - 1) & ~(BMPAD - 1);
    }
  }
  __syncthreads();

  int myoff[NEXP];
#pragma unroll
  for (int e = 0; e < NEXP; ++e) myoff[e] = s_off[e] + lcnt[e][tid];
#pragma unroll
  for (int i = 0; i < 16; ++i) {
    int r = 0;
#pragma unroll
    for (int e = 0; e < NEXP; ++e) r = (my[i] == e) ? myoff[e] : r;
    row2token[r] = (base + i) >> 1;
    pos[base + i] = r;
#pragma unroll
    for (int e = 0; e < NEXP; ++e) myoff[e] += (my[i] == e) ? 1 : 0;
  }

  if (tid < NEXP) {
    cnt[tid] = s_tot[tid];
    offp[tid] = s_off[tid];
  }
}

// ------------- gather x rows -> bf16 hi/lo A-tiled buffers -------------
__global__ __launch_bounds__(256) void gather_kernel(
    const float* __restrict__ x, const int* __restrict__ row2token,
    u16* __restrict__ Ahi, u16* __restrict__ Alo) {
  const int r = blockIdx.x;
  const int t = row2token[r];
  const int c = threadIdx.x * 4;
  float4 v = make_float4(0.f, 0.f, 0.f, 0.f);
  if (t >= 0) v = *(const float4*)(x + (size_t)t * DDIM + c);
  float vv[4] = {v.x, v.y, v.z, v.w};
  u16x4v hi, lo;
#pragma unroll
  for (int i = 0; i < 4; ++i) {
    u16 h = bf16_rn(vv[i]);
    hi[i] = h;
    lo[i] = bf16_rn(vv[i] - bf16_f(h));
  }
  const size_t el = ((size_t)(r >> 6) * (DDIM >> 5) + (c >> 5)) * ATILE_EL +
                    (size_t)(((c >> 3) & 3) * 64 + (r & 63)) * 8 + (c & 7);
  *(u16x4v*)(Ahi + el) = hi;
  *(u16x4v*)(Alo + el) = lo;
}

// ------------- W convert: f32 [e][K][N] -> bf16 hi(/lo) B-tiled [e][N/128][K/32] -------------
template <bool LO>
__global__ __launch_bounds__(256) void wconv_kernel(
    const float* __restrict__ W, u16* __restrict__ Hi, u16* __restrict__ Lo,
    int K, int N) {
  const int e = blockIdx.z, nb = blockIdx.x, kb = blockIdx.y;
  const float* Wp = W + ((size_t)e * K + (size_t)kb * 32) * N + nb * 128;
  __shared__ float tile[32][129];
  const int t = threadIdx.x;
#pragma unroll
  for (int i = 0; i < 4; ++i) {
    const int f4 = i * 256 + t;
    const int kr = f4 >> 5;
    const int c4 = (f4 & 31) * 4;
    float4 v = *(const float4*)(Wp + (size_t)kr * N + c4);
    *(float4*)&tile[kr][c4] = v;
  }
  __syncthreads();
  const size_t tb = (((size_t)e * (N >> 7) + nb) * (K >> 5) + kb) * BTILE_EL;
#pragma unroll
  for (int j = 0; j < 2; ++j) {
    const int cid = j * 256 + t;
    const int n = cid & 127, ksel = cid >> 7;
    u16x8 hv, lv;
#pragma unroll
    for (int i = 0; i < 8; ++i) {
      float f = tile[ksel * 8 + i][n];
      u16 h = bf16_rn(f);
      hv[i] = h;
      if (LO) lv[i] = bf16_rn(f - bf16_f(h));
    }
    *(u16x8*)(Hi + tb + (size_t)cid * 8) = hv;
    if (LO) *(u16x8*)(Lo + tb + (size_t)cid * 8) = lv;
  }
}

// ------------- SPLIT GEMM (f32-grade): 64x128 block, 32x64 waves, BK=32, dbuf -------------
// C = Ah*Bh + Ah*Bl + Al*Bh per staged tile (tile staged once).
// OUTMODE 0: f32 part[0]; 1: bf16 hi+lo A-tiled.
template <bool RELU, int OUTMODE>
__global__ __launch_bounds__(256, 3) void gemm_split(
    const u16* __restrict__ Ahi, const u16* __restrict__ Alo,
    const u16* __restrict__ Bhi, const u16* __restrict__ Blo,
    u16* __restrict__ OutHi, u16* __restrict__ OutLo, float* __restrict__ OutF,
    const int* __restrict__ cnt, const int* __restrict__ offp, int K, int N) {
  int bx, by, bz;
  xcd_swizzle(bx, by, bz);
  const int e = bz;
  const int cp = (cnt[e] + 63) & ~63;
  if (by * 64 >= cp) return;
  const int row0 = offp[e] + by * 64;
  const int n0 = bx * 128;
  const int nkb = K >> 5;

  constexpr int BUF_EL = 12288;  // [AsH 4KB | AsL 4KB | BsH 8KB | BsL 8KB] = 24 KB
  __shared__ u16 lds[2 * BUF_EL];

  const int tid = threadIdx.x;
  const int lane = tid & 63;
  const int wid = tid >> 6;
  const int wr = wid >> 1, wc = wid & 1;     // 2x2 waves, 32x64 each
  const int lr = lane & 15, kg = lane >> 4;
  const int lo16 = lane << 4;

  f32x4 acc[2][4];
#pragma unroll
  for (int i = 0; i < 2; ++i)
#pragma unroll
    for (int j = 0; j < 4; ++j)
#pragma unroll
      for (int r = 0; r < 4; ++r) acc[i][j][r] = 0.f;

  const size_t abase = (size_t)(row0 >> 6) * nkb;
  const size_t bbase = ((size_t)e * (N >> 7) + (n0 >> 7)) * nkb;

  auto STAGE = [&](int kb, int b) {
    char* d = (char*)(lds + b * BUF_EL);
    if (wid == 0) {
      const char* gh = (const char*)(Ahi + (abase + kb) * ATILE_EL);
      const char* gl = (const char*)(Alo + (abase + kb) * ATILE_EL);
#pragma unroll
      for (int i = 0; i < 4; ++i) gl16(gh + i * 1024 + lo16, d + i * 1024);
#pragma unroll
      for (int i = 0; i < 4; ++i) gl16(gl + i * 1024 + lo16, d + 4096 + i * 1024);
    } else if (wid == 1) {
      const char* g = (const char*)(Bhi + (bbase + kb) * BTILE_EL);
#pragma unroll
      for (int i = 0; i < 8; ++i) gl16(g + i * 1024 + lo16, d + 8192 + i * 1024);
    } else if (wid == 2) {
      const char* g = (const char*)(Blo + (bbase + kb) * BTILE_EL);
#pragma unroll
      for (int i = 0; i < 8; ++i) gl16(g + i * 1024 + lo16, d + 16384 + i * 1024);
    }
  };

  STAGE(0, 0);
  __syncthreads();  // vmcnt(0): buf0 ready

  int cur = 0;
  for (int kb = 0; kb < nkb; ++kb) {
    if (kb + 1 < nkb) STAGE(kb + 1, cur ^ 1);  // prefetch overlaps compute below

    const u16* buf = lds + cur * BUF_EL;
    const u16* AsH = buf;
    const u16* AsL = buf + 2048;
    const u16* BsH = buf + 4096;
    const u16* BsL = buf + 8192;
    const int arow = (kg * 64 + wr * 32 + lr) * 8;
    const int bcol = (kg * 128 + wc * 64 + lr) * 8;

    bf16x8 ah0 = *(const bf16x8*)&AsH[arow];
    bf16x8 ah1 = *(const bf16x8*)&AsH[arow + 128];
    bf16x8 bh[4];
#pragma unroll
    for (int j = 0; j < 4; ++j) bh[j] = *(const bf16x8*)&BsH[bcol + j * 128];
#pragma unroll
    for (int j = 0; j < 4; ++j) {
      acc[0][j] = __builtin_amdgcn_mfma_f32_16x16x32_bf16(ah0, bh[j], acc[0][j], 0, 0, 0);
      acc[1][j] = __builtin_amdgcn_mfma_f32_16x16x32_bf16(ah1, bh[j], acc[1][j], 0, 0, 0);
    }
    bf16x8 al0 = *(const bf16x8*)&AsL[arow];
    bf16x8 al1 = *(const bf16x8*)&AsL[arow + 128];
#pragma unroll
    for (int j = 0; j < 4; ++j) {
      bf16x8 bl = *(const bf16x8*)&BsL[bcol + j * 128];
      acc[0][j] = __builtin_amdgcn_mfma_f32_16x16x32_bf16(ah0, bl, acc[0][j], 0, 0, 0);
      acc[1][j] = __builtin_amdgcn_mfma_f32_16x16x32_bf16(ah1, bl, acc[1][j], 0, 0, 0);
      acc[0][j] = __builtin_amdgcn_mfma_f32_16x16x32_bf16(al0, bh[j], acc[0][j], 0, 0, 0);
      acc[1][j] = __builtin_amdgcn_mfma_f32_16x16x32_bf16(al1, bh[j], acc[1][j], 0, 0, 0);
    }
    __syncthreads();  // drains vmcnt(0) -> prefetch landed; all reads of buf done
    cur ^= 1;
  }

  // epilogue: frag D: col=lr, row=kg*4+r
  const int nkbO = N >> 5;
#pragma unroll
  for (int i = 0; i < 2; ++i) {
#pragma unroll
    for (int j = 0; j < 4; ++j) {
      const int Cj = n0 + wc * 64 + j * 16 + lr;
      f32x4 v = acc[i][j];
#pragma unroll
      for (int r = 0; r < 4; ++r) {
        const int R = row0 + wr * 32 + i * 16 + kg * 4 + r;
        float f = v[r];
        if (RELU) f = fmaxf(f, 0.f);
        if constexpr (OUTMODE == 0) {
          OutF[(size_t)R * N + Cj] = f;
        } else {
          const size_t el = ((size_t)(R >> 6) * nkbO + (Cj >> 5)) * ATILE_EL +
                            (size_t)(((Cj >> 3) & 3) * 64 + (R & 63)) * 8 + (Cj & 7);
          u16 h = bf16_rn(f);
          OutHi[el] = h;
          OutLo[el] = bf16_rn(f - bf16_f(h));
        }
      }
    }
  }
}

// ------------- PLAIN GEMM (bf16): 128x128 block, 64x64 waves, BK=32, dbuf -------------
// OUTMODE 0: f32 part[sk]; 2: bf16 hi A-tiled. SKF: split-K factor.
template <bool RELU, int OUTMODE, int SKF>
__global__ __launch_bounds__(256, 4) void gemm_plain(
    const u16* __restrict__ Ahi, const u16* __restrict__ Bhi,
    u16* __restrict__ OutHi, float* __restrict__ OutF,
    const int* __restrict__ cnt, const int* __restrict__ offp, int K, int N) {
  int bx, by, bz;
  xcd_swizzle(bx, by, bz);
  const int e = bz / SKF, sk = bz % SKF;
  const int cp = (cnt[e] + 63) & ~63;
  if (by * 128 >= cp) return;
  const int row0 = offp[e] + by * 128;
  const int rend = offp[e] + cp;
  const int n0 = bx * 128;
  const int nkb = K >> 5;
  const int kbN = nkb / SKF;
  const int kb0 = sk * kbN;

  constexpr int BUF_EL = 8192;  // [A0 4KB | A1 4KB | B 8KB] = 16 KB
  __shared__ u16 lds[2 * BUF_EL];

  const int tid = threadIdx.x;
  const int lane = tid & 63;
  const int wid = tid >> 6;
  const int wr = wid >> 1, wc = wid & 1;     // 2x2 waves, 64x64 each
  const int lr = lane & 15, kg = lane >> 4;
  const int lo16 = lane << 4;

  f32x4 acc[4][4];
#pragma unroll
  for (int i = 0; i < 4; ++i)
#pragma unroll
    for (int j = 0; j < 4; ++j)
#pragma unroll
      for (int r = 0; r < 4; ++r) acc[i][j][r] = 0.f;

  const int at0 = row0 >> 6;  // two consecutive 64-row A tiles
  const size_t bbase = ((size_t)e * (N >> 7) + (n0 >> 7)) * nkb;

  auto STAGE = [&](int kb, int b) {
    char* d = (char*)(lds + b * BUF_EL);
    if (wid < 2) {
      const char* g = (const char*)(Ahi + ((size_t)(at0 + wid) * nkb + kb) * ATILE_EL);
#pragma unroll
      for (int i = 0; i < 4; ++i) gl16(g + i * 1024 + lo16, d + wid * 4096 + i * 1024);
    } else {
      const char* g = (const char*)(Bhi + (bbase + kb) * BTILE_EL) + (wid - 2) * 4096;
#pragma unroll
      for (int i = 0; i < 4; ++i) gl16(g + i * 1024 + lo16, d + 8192 + (wid - 2) * 4096 + i * 1024);
    }
  };

  STAGE(kb0, 0);
  __syncthreads();

  int cur = 0;
  for (int kb = kb0; kb < kb0 + kbN; ++kb) {
    if (kb + 1 < kb0 + kbN) STAGE(kb + 1, cur ^ 1);

    const u16* buf = lds + cur * BUF_EL;
    const u16* AsH = buf + wr * 2048;
    const u16* BsH = buf + 4096;
    const int arow = (kg * 64 + lr) * 8;
    const int bcol = (kg * 128 + wc * 64 + lr) * 8;

    bf16x8 ah[4], bh[4];
#pragma unroll
    for (int i = 0; i < 4; ++i) ah[i] = *(const bf16x8*)&AsH[arow + i * 128];
#pragma unroll
    for (int j = 0; j < 4; ++j) bh[j] = *(const bf16x8*)&BsH[bcol + j * 128];
#pragma unroll
    for (int i = 0; i < 4; ++i)
#pragma unroll
      for (int j = 0; j < 4; ++j)
        acc[i][j] = __builtin_amdgcn_mfma_f32_16x16x32_bf16(ah[i], bh[j], acc[i][j], 0, 0, 0);
    __syncthreads();
    cur ^= 1;
  }

  const int nkbO = N >> 5;
#pragma unroll
  for (int i = 0; i < 4; ++i) {
#pragma unroll
    for (int j = 0; j < 4; ++j) {
      const int Cj = n0 + wc * 64 + j * 16 + lr;
      f32x4 v = acc[i][j];
#pragma unroll
      for (int r = 0; r < 4; ++r) {
        const int R = row0 + wr * 64 + i * 16 + kg * 4 + r;
        if (R >= rend) continue;  // 128-tile may overhang the 64-padded region
        float f = v[r];
        if (RELU) f = fmaxf(f, 0.f);
        if constexpr (OUTMODE == 0) {
          OutF[((size_t)sk * RALLOC + R) * N + Cj] = f;
        } else {
          const size_t el = ((size_t)(R >> 6) * nkbO + (Cj >> 5)) * ATILE_EL +
                            (size_t)(((Cj >> 3) & 3) * 64 + (R & 63)) * 8 + (Cj & 7);
          OutHi[el] = bf16_rn(f);
        }
      }
    }
  }
}

// ------------- apply: x[t] += w0*sum(P)[pos0] + w1*sum(P)[pos1] -------------
template <int NPART>
__global__ __launch_bounds__(256) void apply_kernel(
    const float* __restrict__ part, const int* __restrict__ pos,
    const float* __restrict__ wgt, float* __restrict__ x) {
  const int t = blockIdx.x;
  const int c = threadIdx.x * 4;
  const int p0 = pos[t * 2], p1 = pos[t * 2 + 1];
  const float w0 = wgt[t * 2], w1 = wgt[t * 2 + 1];
  float4 xa = *(float4*)(x + (size_t)t * DDIM + c);
  float4 y0 = *(const float4*)(part + (size_t)p0 * DDIM + c);
  float4 y1 = *(const float4*)(part + (size_t)p1 * DDIM + c);
  if (NPART == 2) {
    const float* P1 = part + (size_t)RALLOC * DDIM;
    const float4 b0 = *(const float4*)(P1 + (size_t)p0 * DDIM + c);
    const float4 b1 = *(const float4*)(P1 + (size_t)p1 * DDIM + c);
    y0.x += b0.x; y0.y += b0.y; y0.z += b0.z; y0.w += b0.w;
    y1.x += b1.x; y1.y += b1.y; y1.z += b1.z; y1.w += b1.w;
  }
  xa.x += w0 * y0.x + w1 * y1.x;
  xa.y += w0 * y0.y + w1 * y1.y;
  xa.z += w0 * y0.z + w1 * y1.z;
  xa.w += w0 * y0.w + w1 * y1.w;
  *(float4*)(x + (size_t)t * DDIM + c) = xa;
}

extern "C" void kernel_launch(void* const* d_in, const int* in_sizes, int n_in,
                              void* d_out, int out_size, void* d_ws, size_t ws_size,
                              hipStream_t stream) {
  const float* x = (const float*)d_in[0];
  const float* protos = (const float*)d_in[1];
  const float* W1 = (const float*)d_in[2];
  const float* W2 = (const float*)d_in[3];
  float* xcur = (float*)d_out;

  // ws (~164 MB): W hi/lo 33.5 ea; Ag hi/lo 9.7 ea; h hi/lo 19.4 ea; part 38.8; meta
  u16* W_hi = (u16*)d_ws;
  u16* W_lo = W_hi + (size_t)NEXP * DDIM * FDIM;
  u16* Ag_hi = W_lo + (size_t)NEXP * DDIM * FDIM;
  u16* Ag_lo = Ag_hi + (size_t)RALLOC * DDIM;
  u16* h_hi = Ag_lo + (size_t)RALLOC * DDIM;
  u16* h_lo = h_hi + (size_t)RALLOC * FDIM;
  float* part = (float*)(h_lo + (size_t)RALLOC * FDIM);
  float* wgt = part + (size_t)2 * RALLOC * DDIM;
  int* eid = (int*)(wgt + T_TOKENS * 2);
  int* pos = eid + T_TOKENS * 2;
  int* cnt = pos + T_TOKENS * 2;
  int* offp = cnt + NEXP;
  int* row2token = offp + NEXP;

  hipMemcpyAsync(xcur, x, (size_t)T_TOKENS * DDIM * sizeof(float),
                 hipMemcpyDeviceToDevice, stream);

  for (int l = 0; l < NLAYER; ++l) {
    route_kernel<<<T_TOKENS, 256, 0, stream>>>(
        xcur, protos + (size_t)l * NEXP * DDIM, eid, wgt);
    compact_kernel<<<1, 256, 0, stream>>>(eid, cnt, offp, row2token, pos);
    gather_kernel<<<RMAX, 256, 0, stream>>>(xcur, row2token, Ag_hi, Ag_lo);
    const float* W1l = W1 + (size_t)l * NEXP * DDIM * FDIM;
    const float* W2l = W2 + (size_t)l * NEXP * FDIM * DDIM;
    if (l == 0) {
      // layer-1 output feeds layer-2 routing: fused-split (f32-grade) GEMMs, 64-tile
      wconv_kernel<true><<<dim3(FDIM / 128, DDIM / 32, NEXP), 256, 0, stream>>>(
          W1l, W_hi, W_lo, DDIM, FDIM);
      gemm_split<true, 1><<<dim3(FDIM / 128, RMAX / 64, NEXP), 256, 0, stream>>>(
          Ag_hi, Ag_lo, W_hi, W_lo, h_hi, h_lo, nullptr, cnt, offp, DDIM, FDIM);
      wconv_kernel<true><<<dim3(DDIM / 128, FDIM / 32, NEXP), 256, 0, stream>>>(
          W2l, W_hi, W_lo, FDIM, DDIM);
      gemm_split<false, 0><<<dim3(DDIM / 128, RMAX / 64, NEXP), 256, 0, stream>>>(
          h_hi, h_lo, W_hi, W_lo, nullptr, nullptr, part, cnt, offp, FDIM, DDIM);
      apply_kernel<1><<<T_TOKENS, 256, 0, stream>>>(part, pos, wgt, xcur);
    } else {
      // layer-2 output only feeds the final check: plain bf16, 128-tile
      wconv_kernel<false><<<dim3(FDIM / 128, DDIM / 32, NEXP), 256, 0, stream>>>(
          W1l, W_hi, nullptr, DDIM, FDIM);
      gemm_plain<true, 2, 1><<<dim3(FDIM / 128, RMAX / 128, NEXP), 256, 0, stream>>>(
          Ag_hi, W_hi, h_hi, nullptr, cnt, offp, DDIM, FDIM);
      wconv_kernel<false><<<dim3(DDIM / 128, FDIM / 32, NEXP), 256, 0, stream>>>(
          W2l, W_hi, nullptr, FDIM, DDIM);
      gemm_plain<false, 0, 2><<<dim3(DDIM / 128, RMAX / 128, NEXP * 2), 256, 0, stream>>>(
          h_hi, W_hi, nullptr, part, cnt, offp, FDIM, DDIM);
      apply_kernel<2><<<T_TOKENS, 256, 0, stream>>>(part, pos, wgt, xcur);
    }
  }
}

// Round 9
// 366.718 us; speedup vs baseline: 1.0715x; 1.0139x over previous
//
#include <hip/hip_runtime.h>
#include <hip/hip_bf16.h>
#include <cstdint>

// Problem constants (B=2,S=1024,D=1024; L=2,E=8,F=2048; k=2)
#define T_TOKENS 2048
#define DDIM 1024
#define FDIM 2048
#define NEXP 8
#define NLAYER 2
#define BMPAD 64           // per-expert row padding granularity
#define RMAX 4608          // 2048*2 + 8*63 = 4537 -> 64-multiple
#define RALLOC 4736        // +128 slack rows (128-row M-tiles may overhang)

// A-operand tiles: 64 rows x 32 k, 2048 el (4 KB), order ((ksel*64+row)*8 + (k&7)),
//   ksel=(k>>3)&3 -- exactly MFMA fragment order for 16x16x32 bf16.
// B-operand tiles: 128 cols x 32 k, 4096 el (8 KB), order ((ksel*128+col)*8 + (k&7)).
// Linear LDS copy of a tile is fragment-readable conflict-free (b128, 16B x 16 lanes).
#define ATILE_EL 2048
#define BTILE_EL 4096

typedef unsigned short u16;
typedef short bf16x8 __attribute__((ext_vector_type(8)));
typedef u16 u16x8 __attribute__((ext_vector_type(8)));
typedef u16 u16x4v __attribute__((ext_vector_type(4)));
typedef float f32x4 __attribute__((ext_vector_type(4)));

__device__ __forceinline__ u16 bf16_rn(float f) {
  unsigned u = __builtin_bit_cast(unsigned, f);
  u += 0x7fffu + ((u >> 16) & 1u);
  return (u16)(u >> 16);
}
__device__ __forceinline__ float bf16_f(u16 h) {
  unsigned u = ((unsigned)h) << 16;
  return __builtin_bit_cast(float, u);
}

__device__ __forceinline__ void gl16(const void* g, void* l) {
  __builtin_amdgcn_global_load_lds((const __attribute__((address_space(1))) void*)g,
                                   (__attribute__((address_space(3))) void*)l, 16, 0, 0);
}

// XCD-aware bijective swizzle: nwg divisible by 8 for all our GEMM grids.
__device__ __forceinline__ void xcd_swizzle(int& bx, int& by, int& bz) {
  const unsigned gx = gridDim.x, gy = gridDim.y;
  const unsigned lin = blockIdx.x + gx * (blockIdx.y + gy * blockIdx.z);
  const unsigned nwg = gx * gy * gridDim.z;
  const unsigned nl = (lin & 7u) * (nwg >> 3) + (lin >> 3);
  bx = nl % gx;
  const unsigned t = nl / gx;
  by = t % gy;
  bz = t / gy;
}

// ---------------- routing layer 0: scores from f32 x directly ----------------
__global__ __launch_bounds__(256) void route_kernel(
    const float* __restrict__ x, const float* __restrict__ protos,
    int* __restrict__ eid, float* __restrict__ wgt) {
  const int t = blockIdx.x;
  const int tid = threadIdx.x;
  const float4* xr4 = (const float4*)(x + (size_t)t * DDIM);
  const float4* pr4 = (const float4*)protos;
  __shared__ float red[NEXP][256];
  const float4 xv = xr4[tid];
  float acc[NEXP];
#pragma unroll
  for (int e = 0; e < NEXP; ++e) {
    const float4 p = pr4[e * 256 + tid];
    acc[e] = xv.x * p.x + xv.y * p.y + xv.z * p.z + xv.w * p.w;
  }
#pragma unroll
  for (int e = 0; e < NEXP; ++e) red[e][tid] = acc[e];
  __syncthreads();
  for (int s = 128; s > 0; s >>= 1) {
    if (tid < s) {
#pragma unroll
      for (int e = 0; e < NEXP; ++e) red[e][tid] += red[e][tid + s];
    }
    __syncthreads();
  }
  if (tid == 0) {
    float m1 = -1.f, m2 = -1.f;
    int i1 = 0, i2 = 0;
#pragma unroll
    for (int e = 0; e < NEXP; ++e) {
      float s = fabsf(red[e][0]);
      if (s > m1) { m2 = m1; i2 = i1; m1 = s; i1 = e; }
      else if (s > m2) { m2 = s; i2 = e; }
    }
    float e2 = __expf(m2 - m1);
    float z = 1.f + e2;
    eid[t * 2] = i1;
    eid[t * 2 + 1] = i2;
    wgt[t * 2] = 1.f / z;
    wgt[t * 2 + 1] = e2 / z;
  }
}

// -------- routing layer 1: score2 = x0.p2 + sum_s w_s * (h[row_s] . P[e_s]) --------
// x0 = residual BEFORE layer-0 apply; h = f32-grade (hi+lo) relu(x0@W1);
// P[e1][e2][f] = W2[e1][f][:] . p2[e2][:]  (precomputed f32).
__global__ __launch_bounds__(256) void route2_kernel(
    const float* __restrict__ x, const float* __restrict__ protos2,
    const u16* __restrict__ h_hi, const u16* __restrict__ h_lo,
    const float* __restrict__ P, const int* __restrict__ eidA,
    const int* __restrict__ pos, const float* __restrict__ wgtA,
    int* __restrict__ eidB, float* __restrict__ wgtB) {
  const int t = blockIdx.x;
  const int tid = threadIdx.x;
  __shared__ float red[NEXP][256];
  // part 1: x0 . proto2
  const float4 xv = ((const float4*)(x + (size_t)t * DDIM))[tid];
  float acc[NEXP];
#pragma unroll
  for (int e = 0; e < NEXP; ++e) {
    const float4 p = ((const float4*)protos2)[e * 256 + tid];
    acc[e] = xv.x * p.x + xv.y * p.y + xv.z * p.z + xv.w * p.w;
  }
  // part 2: correction via P (replaces y . proto2 exactly)
  const int p0 = pos[t * 2], p1 = pos[t * 2 + 1];
  const int e0 = eidA[t * 2], e1 = eidA[t * 2 + 1];
  const float w0 = wgtA[t * 2], w1 = wgtA[t * 2 + 1];
  const int f0 = tid * 8;  // this thread's 8-wide f-slice of F=2048
  const int nkbF = FDIM >> 5;
  float h0[8], h1[8];
  {
    const size_t el0 = ((size_t)(p0 >> 6) * nkbF + (f0 >> 5)) * ATILE_EL +
                       (size_t)((((f0 >> 3) & 3) * 64 + (p0 & 63)) * 8);
    const size_t el1 = ((size_t)(p1 >> 6) * nkbF + (f0 >> 5)) * ATILE_EL +
                       (size_t)((((f0 >> 3) & 3) * 64 + (p1 & 63)) * 8);
    u16x8 a = *(const u16x8*)&h_hi[el0], b = *(const u16x8*)&h_lo[el0];
    u16x8 c = *(const u16x8*)&h_hi[el1], d = *(const u16x8*)&h_lo[el1];
#pragma unroll
    for (int j = 0; j < 8; ++j) {
      h0[j] = bf16_f(a[j]) + bf16_f(b[j]);
      h1[j] = bf16_f(c[j]) + bf16_f(d[j]);
    }
  }
#pragma unroll
  for (int e2 = 0; e2 < NEXP; ++e2) {
    const float* P0 = P + ((size_t)(e0 * NEXP + e2)) * FDIM + f0;
    const float* P1 = P + ((size_t)(e1 * NEXP + e2)) * FDIM + f0;
    float c = 0.f;
#pragma unroll
    for (int j = 0; j < 8; ++j) c += w0 * h0[j] * P0[j] + w1 * h1[j] * P1[j];
    acc[e2] += c;
  }
#pragma unroll
  for (int e = 0; e < NEXP; ++e) red[e][tid] = acc[e];
  __syncthreads();
  for (int s = 128; s > 0; s >>= 1) {
    if (tid < s) {
#pragma unroll
      for (int e = 0; e < NEXP; ++e) red[e][tid] += red[e][tid + s];
    }
    __syncthreads();
  }
  if (tid == 0) {
    float m1 = -1.f, m2 = -1.f;
    int i1 = 0, i2 = 0;
#pragma unroll
    for (int e = 0; e < NEXP; ++e) {
      float s = fabsf(red[e][0]);
      if (s > m1) { m2 = m1; i2 = i1; m1 = s; i1 = e; }
      else if (s > m2) { m2 = s; i2 = e; }
    }
    float e2 = __expf(m2 - m1);
    float z = 1.f + e2;
    eidB[t * 2] = i1;
    eidB[t * 2 + 1] = i2;
    wgtB[t * 2] = 1.f / z;
    wgtB[t * 2 + 1] = e2 / z;
  }
}

// ------------- compaction (padded to 64) -------------
__global__ __launch_bounds__(256) void compact_kernel(
    const int* __restrict__ eid, int* __restrict__ cnt, int* __restrict__ offp,
    int* __restrict__ row2token, int* __restrict__ pos) {
  __shared__ int lcnt[NEXP][256];
  __shared__ int s_off[NEXP], s_tot[NEXP];
  const int tid = threadIdx.x;
  const int base = tid * 16;

  int my[16];
#pragma unroll
  for (int i = 0; i < 4; ++i)
    *(int4*)&my[i * 4] = *(const int4*)(eid + base + i * 4);

#pragma unroll
  for (int e = 0; e < NEXP; ++e) {
    int c = 0;
#pragma unroll
    for (int i = 0; i < 16; ++i) c += (my[i] == e) ? 1 : 0;
    lcnt[e][tid] = c;
  }

  for (int r = tid; r < RMAX; r += 256) row2token[r] = -1;
  __syncthreads();

  if (tid < NEXP) {
    int run = 0;
    for (int i = 0; i < 256; ++i) {
      int v = lcnt[tid][i];
      lcnt[tid][i] = run;
      run += v;
    }
    s_tot[tid] = run;
  }
  __syncthreads();
  if (tid == 0) {
    int o = 0;
    for (int e = 0; e < NEXP; ++e) {
      s_off[e] = o;
      o += (s_tot[e] + BMPAD - 1) & ~(BMPAD - 1);
    }
  }
  __syncthreads();

  int myoff[NEXP];
#pragma unroll
  for (int e = 0; e < NEXP; ++e) myoff[e] = s_off[e] + lcnt[e][tid];
#pragma unroll
  for (int i = 0; i < 16; ++i) {
    int r = 0;
#pragma unroll
    for (int e = 0; e < NEXP; ++e) r = (my[i] == e) ? myoff[e] : r;
    row2token[r] = (base + i) >> 1;
    pos[base + i] = r;
#pragma unroll
    for (int e = 0; e < NEXP; ++e) myoff[e] += (my[i] == e) ? 1 : 0;
  }

  if (tid < NEXP) {
    cnt[tid] = s_tot[tid];
    offp[tid] = s_off[tid];
  }
}

// ------------- gather x rows -> bf16 hi(/lo) A-tiled buffers -------------
template <bool LO>
__global__ __launch_bounds__(256) void gather_kernel(
    const float* __restrict__ x, const int* __restrict__ row2token,
    u16* __restrict__ Ahi, u16* __restrict__ Alo) {
  const int r = blockIdx.x;
  const int t = row2token[r];
  const int c = threadIdx.x * 4;
  float4 v = make_float4(0.f, 0.f, 0.f, 0.f);
  if (t >= 0) v = *(const float4*)(x + (size_t)t * DDIM + c);
  float vv[4] = {v.x, v.y, v.z, v.w};
  u16x4v hi, lo;
#pragma unroll
  for (int i = 0; i < 4; ++i) {
    u16 h = bf16_rn(vv[i]);
    hi[i] = h;
    if (LO) lo[i] = bf16_rn(vv[i] - bf16_f(h));
  }
  const size_t el = ((size_t)(r >> 6) * (DDIM >> 5) + (c >> 5)) * ATILE_EL +
                    (size_t)(((c >> 3) & 3) * 64 + (r & 63)) * 8 + (c & 7);
  *(u16x4v*)(Ahi + el) = hi;
  if (LO) *(u16x4v*)(Alo + el) = lo;
}

// ------------- W convert: f32 [e][K][N] -> bf16 hi(/lo) B-tiled [e][N/128][K/32] -------------
template <bool LO>
__global__ __launch_bounds__(256) void wconv_kernel(
    const float* __restrict__ W, u16* __restrict__ Hi, u16* __restrict__ Lo,
    int K, int N) {
  const int e = blockIdx.z, nb = blockIdx.x, kb = blockIdx.y;
  const float* Wp = W + ((size_t)e * K + (size_t)kb * 32) * N + nb * 128;
  __shared__ float tile[32][129];
  const int t = threadIdx.x;
#pragma unroll
  for (int i = 0; i < 4; ++i) {
    const int f4 = i * 256 + t;
    const int kr = f4 >> 5;
    const int c4 = (f4 & 31) * 4;
    float4 v = *(const float4*)(Wp + (size_t)kr * N + c4);
    *(float4*)&tile[kr][c4] = v;
  }
  __syncthreads();
  const size_t tb = (((size_t)e * (N >> 7) + nb) * (K >> 5) + kb) * BTILE_EL;
#pragma unroll
  for (int j = 0; j < 2; ++j) {
    const int cid = j * 256 + t;
    const int n = cid & 127, ksel = cid >> 7;
    u16x8 hv, lv;
#pragma unroll
    for (int i = 0; i < 8; ++i) {
      float f = tile[ksel * 8 + i][n];
      u16 h = bf16_rn(f);
      hv[i] = h;
      if (LO) lv[i] = bf16_rn(f - bf16_f(h));
    }
    *(u16x8*)(Hi + tb + (size_t)cid * 8) = hv;
    if (LO) *(u16x8*)(Lo + tb + (size_t)cid * 8) = lv;
  }
}

// ------------- W2 convert (hi only) + P partials: Ppart[nb][e1][e2][kb*32+f] -------------
// P[e1][e2][f] = sum_n W2[e1][f][n] * proto2[e2][n]; each block contributes its n-slice.
__global__ __launch_bounds__(256) void wconv_p_kernel(
    const float* __restrict__ W, u16* __restrict__ Hi,
    const float* __restrict__ proto2, float* __restrict__ Ppart, int K, int N) {
  const int e = blockIdx.z, nb = blockIdx.x, kb = blockIdx.y;
  const float* Wp = W + ((size_t)e * K + (size_t)kb * 32) * N + nb * 128;
  __shared__ float tile[32][129];
  __shared__ float pr[NEXP][128];
  const int t = threadIdx.x;
#pragma unroll
  for (int i = 0; i < 4; ++i) {
    const int f4 = i * 256 + t;
    const int kr = f4 >> 5;
    const int c4 = (f4 & 31) * 4;
    float4 v = *(const float4*)(Wp + (size_t)kr * N + c4);
    *(float4*)&tile[kr][c4] = v;
  }
  {  // stage proto2 slice: pr[e2][n] = proto2[e2][nb*128+n]
    const int idx = t * 4;
    const int e2 = idx >> 7, n = idx & 127;
    *(float4*)&pr[e2][n] = *(const float4*)(proto2 + (size_t)e2 * DDIM + nb * 128 + n);
  }
  __syncthreads();
  const size_t tb = (((size_t)e * (N >> 7) + nb) * (K >> 5) + kb) * BTILE_EL;
#pragma unroll
  for (int j = 0; j < 2; ++j) {
    const int cid = j * 256 + t;
    const int n = cid & 127, ksel = cid >> 7;
    u16x8 hv;
#pragma unroll
    for (int i = 0; i < 8; ++i) hv[i] = bf16_rn(tile[ksel * 8 + i][n]);
    *(u16x8*)(Hi + tb + (size_t)cid * 8) = hv;
  }
  // P partial: thread (e2 = t>>5, f = t&31)
  const int e2 = t >> 5, f = t & 31;
  float s = 0.f;
#pragma unroll 16
  for (int n = 0; n < 128; ++n) s += tile[f][n] * pr[e2][n];
  Ppart[(((size_t)nb * NEXP + e) * NEXP + e2) * FDIM + kb * 32 + f] = s;
}

// ------------- reduce P partials over nb (deterministic order) -------------
__global__ __launch_bounds__(256) void reduce_p_kernel(
    const float* __restrict__ Ppart, float* __restrict__ P) {
  const int i = blockIdx.x * 256 + threadIdx.x;  // [0, 8*8*2048)
  float s = 0.f;
#pragma unroll
  for (int nb = 0; nb < 8; ++nb) s += Ppart[(size_t)nb * (NEXP * NEXP * FDIM) + i];
  P[i] = s;
}

// ------------- SPLIT GEMM (f32-grade): 64x128 block, 32x64 waves, BK=32, dbuf -------------
// C = Ah*Bh + Ah*Bl + Al*Bh per staged tile. Output: bf16 hi+lo A-tiled (+relu).
__global__ __launch_bounds__(256, 3) void gemm_split(
    const u16* __restrict__ Ahi, const u16* __restrict__ Alo,
    const u16* __restrict__ Bhi, const u16* __restrict__ Blo,
    u16* __restrict__ OutHi, u16* __restrict__ OutLo,
    const int* __restrict__ cnt, const int* __restrict__ offp, int K, int N) {
  int bx, by, bz;
  xcd_swizzle(bx, by, bz);
  const int e = bz;
  const int cp = (cnt[e] + 63) & ~63;
  if (by * 64 >= cp) return;
  const int row0 = offp[e] + by * 64;
  const int n0 = bx * 128;
  const int nkb = K >> 5;

  constexpr int BUF_EL = 12288;  // [AsH 4KB | AsL 4KB | BsH 8KB | BsL 8KB] = 24 KB
  __shared__ u16 lds[2 * BUF_EL];

  const int tid = threadIdx.x;
  const int lane = tid & 63;
  const int wid = tid >> 6;
  const int wr = wid >> 1, wc = wid & 1;     // 2x2 waves, 32x64 each
  const int lr = lane & 15, kg = lane >> 4;
  const int lo16 = lane << 4;

  f32x4 acc[2][4];
#pragma unroll
  for (int i = 0; i < 2; ++i)
#pragma unroll
    for (int j = 0; j < 4; ++j)
#pragma unroll
      for (int r = 0; r < 4; ++r) acc[i][j][r] = 0.f;

  const size_t abase = (size_t)(row0 >> 6) * nkb;
  const size_t bbase = ((size_t)e * (N >> 7) + (n0 >> 7)) * nkb;

  auto STAGE = [&](int kb, int b) {
    char* d = (char*)(lds + b * BUF_EL);
    if (wid == 0) {
      const char* gh = (const char*)(Ahi + (abase + kb) * ATILE_EL);
      const char* gl = (const char*)(Alo + (abase + kb) * ATILE_EL);
#pragma unroll
      for (int i = 0; i < 4; ++i) gl16(gh + i * 1024 + lo16, d + i * 1024);
#pragma unroll
      for (int i = 0; i < 4; ++i) gl16(gl + i * 1024 + lo16, d + 4096 + i * 1024);
    } else if (wid == 1) {
      const char* g = (const char*)(Bhi + (bbase + kb) * BTILE_EL);
#pragma unroll
      for (int i = 0; i < 8; ++i) gl16(g + i * 1024 + lo16, d + 8192 + i * 1024);
    } else if (wid == 2) {
      const char* g = (const char*)(Blo + (bbase + kb) * BTILE_EL);
#pragma unroll
      for (int i = 0; i < 8; ++i) gl16(g + i * 1024 + lo16, d + 16384 + i * 1024);
    }
  };

  STAGE(0, 0);
  __syncthreads();  // vmcnt(0): buf0 ready

  int cur = 0;
  for (int kb = 0; kb < nkb; ++kb) {
    if (kb + 1 < nkb) STAGE(kb + 1, cur ^ 1);  // prefetch overlaps compute below

    const u16* buf = lds + cur * BUF_EL;
    const u16* AsH = buf;
    const u16* AsL = buf + 2048;
    const u16* BsH = buf + 4096;
    const u16* BsL = buf + 8192;
    const int arow = (kg * 64 + wr * 32 + lr) * 8;
    const int bcol = (kg * 128 + wc * 64 + lr) * 8;

    bf16x8 ah0 = *(const bf16x8*)&AsH[arow];
    bf16x8 ah1 = *(const bf16x8*)&AsH[arow + 128];
    bf16x8 bh[4];
#pragma unroll
    for (int j = 0; j < 4; ++j) bh[j] = *(const bf16x8*)&BsH[bcol + j * 128];
#pragma unroll
    for (int j = 0; j < 4; ++j) {
      acc[0][j] = __builtin_amdgcn_mfma_f32_16x16x32_bf16(ah0, bh[j], acc[0][j], 0, 0, 0);
      acc[1][j] = __builtin_amdgcn_mfma_f32_16x16x32_bf16(ah1, bh[j], acc[1][j], 0, 0, 0);
    }
    bf16x8 al0 = *(const bf16x8*)&AsL[arow];
    bf16x8 al1 = *(const bf16x8*)&AsL[arow + 128];
#pragma unroll
    for (int j = 0; j < 4; ++j) {
      bf16x8 bl = *(const bf16x8*)&BsL[bcol + j * 128];
      acc[0][j] = __builtin_amdgcn_mfma_f32_16x16x32_bf16(ah0, bl, acc[0][j], 0, 0, 0);
      acc[1][j] = __builtin_amdgcn_mfma_f32_16x16x32_bf16(ah1, bl, acc[1][j], 0, 0, 0);
      acc[0][j] = __builtin_amdgcn_mfma_f32_16x16x32_bf16(al0, bh[j], acc[0][j], 0, 0, 0);
      acc[1][j] = __builtin_amdgcn_mfma_f32_16x16x32_bf16(al1, bh[j], acc[1][j], 0, 0, 0);
    }
    __syncthreads();  // drains vmcnt(0) -> prefetch landed; all reads of buf done
    cur ^= 1;
  }

  // epilogue: relu + hi/lo A-tiled write
  const int nkbO = N >> 5;
#pragma unroll
  for (int i = 0; i < 2; ++i) {
#pragma unroll
    for (int j = 0; j < 4; ++j) {
      const int Cj = n0 + wc * 64 + j * 16 + lr;
      f32x4 v = acc[i][j];
#pragma unroll
      for (int r = 0; r < 4; ++r) {
        const int R = row0 + wr * 32 + i * 16 + kg * 4 + r;
        float f = fmaxf(v[r], 0.f);
        const size_t el = ((size_t)(R >> 6) * nkbO + (Cj >> 5)) * ATILE_EL +
                          (size_t)(((Cj >> 3) & 3) * 64 + (R & 63)) * 8 + (Cj & 7);
        u16 h = bf16_rn(f);
        OutHi[el] = h;
        OutLo[el] = bf16_rn(f - bf16_f(h));
      }
    }
  }
}

// ------------- PLAIN GEMM (bf16): 128x128 block, 64x64 waves, BK=32, dbuf -------------
// OUTMODE 0: f32 part[sk]; 2: bf16 hi A-tiled. SKF: split-K factor.
template <bool RELU, int OUTMODE, int SKF>
__global__ __launch_bounds__(256, 4) void gemm_plain(
    const u16* __restrict__ Ahi, const u16* __restrict__ Bhi,
    u16* __restrict__ OutHi, float* __restrict__ OutF,
    const int* __restrict__ cnt, const int* __restrict__ offp, int K, int N) {
  int bx, by, bz;
  xcd_swizzle(bx, by, bz);
  const int e = bz / SKF, sk = bz % SKF;
  const int cp = (cnt[e] + 63) & ~63;
  if (by * 128 >= cp) return;
  const int row0 = offp[e] + by * 128;
  const int rend = offp[e] + cp;
  const int n0 = bx * 128;
  const int nkb = K >> 5;
  const int kbN = nkb / SKF;
  const int kb0 = sk * kbN;

  constexpr int BUF_EL = 8192;  // [A0 4KB | A1 4KB | B 8KB] = 16 KB
  __shared__ u16 lds[2 * BUF_EL];

  const int tid = threadIdx.x;
  const int lane = tid & 63;
  const int wid = tid >> 6;
  const int wr = wid >> 1, wc = wid & 1;     // 2x2 waves, 64x64 each
  const int lr = lane & 15, kg = lane >> 4;
  const int lo16 = lane << 4;

  f32x4 acc[4][4];
#pragma unroll
  for (int i = 0; i < 4; ++i)
#pragma unroll
    for (int j = 0; j < 4; ++j)
#pragma unroll
      for (int r = 0; r < 4; ++r) acc[i][j][r] = 0.f;

  const int at0 = row0 >> 6;  // two consecutive 64-row A tiles
  const size_t bbase = ((size_t)e * (N >> 7) + (n0 >> 7)) * nkb;

  auto STAGE = [&](int kb, int b) {
    char* d = (char*)(lds + b * BUF_EL);
    if (wid < 2) {
      const char* g = (const char*)(Ahi + ((size_t)(at0 + wid) * nkb + kb) * ATILE_EL);
#pragma unroll
      for (int i = 0; i < 4; ++i) gl16(g + i * 1024 + lo16, d + wid * 4096 + i * 1024);
    } else {
      const char* g = (const char*)(Bhi + (bbase + kb) * BTILE_EL) + (wid - 2) * 4096;
#pragma unroll
      for (int i = 0; i < 4; ++i) gl16(g + i * 1024 + lo16, d + 8192 + (wid - 2) * 4096 + i * 1024);
    }
  };

  STAGE(kb0, 0);
  __syncthreads();

  int cur = 0;
  for (int kb = kb0; kb < kb0 + kbN; ++kb) {
    if (kb + 1 < kb0 + kbN) STAGE(kb + 1, cur ^ 1);

    const u16* buf = lds + cur * BUF_EL;
    const u16* AsH = buf + wr * 2048;
    const u16* BsH = buf + 4096;
    const int arow = (kg * 64 + lr) * 8;
    const int bcol = (kg * 128 + wc * 64 + lr) * 8;

    bf16x8 ah[4], bh[4];
#pragma unroll
    for (int i = 0; i < 4; ++i) ah[i] = *(const bf16x8*)&AsH[arow + i * 128];
#pragma unroll
    for (int j = 0; j < 4; ++j) bh[j] = *(const bf16x8*)&BsH[bcol + j * 128];
#pragma unroll
    for (int i = 0; i < 4; ++i)
#pragma unroll
      for (int j = 0; j < 4; ++j)
        acc[i][j] = __builtin_amdgcn_mfma_f32_16x16x32_bf16(ah[i], bh[j], acc[i][j], 0, 0, 0);
    __syncthreads();
    cur ^= 1;
  }

  const int nkbO = N >> 5;
#pragma unroll
  for (int i = 0; i < 4; ++i) {
#pragma unroll
    for (int j = 0; j < 4; ++j) {
      const int Cj = n0 + wc * 64 + j * 16 + lr;
      f32x4 v = acc[i][j];
#pragma unroll
      for (int r = 0; r < 4; ++r) {
        const int R = row0 + wr * 64 + i * 16 + kg * 4 + r;
        if (R >= rend) continue;  // 128-tile may overhang the 64-padded region
        float f = v[r];
        if (RELU) f = fmaxf(f, 0.f);
        if constexpr (OUTMODE == 0) {
          OutF[((size_t)sk * RALLOC + R) * N + Cj] = f;
        } else {
          const size_t el = ((size_t)(R >> 6) * nkbO + (Cj >> 5)) * ATILE_EL +
                            (size_t)(((Cj >> 3) & 3) * 64 + (R & 63)) * 8 + (Cj & 7);
          OutHi[el] = bf16_rn(f);
        }
      }
    }
  }
}

// ------------- apply: x[t] += w0*(P0+P1)[pos0] + w1*(P0+P1)[pos1] -------------
__global__ __launch_bounds__(256) void apply_kernel(
    const float* __restrict__ part, const int* __restrict__ pos,
    const float* __restrict__ wgt, float* __restrict__ x) {
  const int t = blockIdx.x;
  const int c = threadIdx.x * 4;
  const int p0 = pos[t * 2], p1 = pos[t * 2 + 1];
  const float w0 = wgt[t * 2], w1 = wgt[t * 2 + 1];
  const float* P1p = part + (size_t)RALLOC * DDIM;
  float4 xa = *(float4*)(x + (size_t)t * DDIM + c);
  float4 y0 = *(const float4*)(part + (size_t)p0 * DDIM + c);
  float4 y1 = *(const float4*)(part + (size_t)p1 * DDIM + c);
  const float4 b0 = *(const float4*)(P1p + (size_t)p0 * DDIM + c);
  const float4 b1 = *(const float4*)(P1p + (size_t)p1 * DDIM + c);
  y0.x += b0.x; y0.y += b0.y; y0.z += b0.z; y0.w += b0.w;
  y1.x += b1.x; y1.y += b1.y; y1.z += b1.z; y1.w += b1.w;
  xa.x += w0 * y0.x + w1 * y1.x;
  xa.y += w0 * y0.y + w1 * y1.y;
  xa.z += w0 * y0.z + w1 * y1.z;
  xa.w += w0 * y0.w + w1 * y1.w;
  *(float4*)(x + (size_t)t * DDIM + c) = xa;
}

extern "C" void kernel_launch(void* const* d_in, const int* in_sizes, int n_in,
                              void* d_out, int out_size, void* d_ws, size_t ws_size,
                              hipStream_t stream) {
  const float* x = (const float*)d_in[0];
  const float* protos = (const float*)d_in[1];
  const float* W1 = (const float*)d_in[2];
  const float* W2 = (const float*)d_in[3];
  float* xcur = (float*)d_out;

  // ws (~169 MB): W hi/lo 33.5 ea; Ag hi/lo 9.7 ea; h hi/lo 19.4 ea; part 38.8;
  // Ppart 4; P 0.5; meta
  u16* W_hi = (u16*)d_ws;
  u16* W_lo = W_hi + (size_t)NEXP * DDIM * FDIM;
  u16* Ag_hi = W_lo + (size_t)NEXP * DDIM * FDIM;
  u16* Ag_lo = Ag_hi + (size_t)RALLOC * DDIM;
  u16* h_hi = Ag_lo + (size_t)RALLOC * DDIM;
  u16* h_lo = h_hi + (size_t)RALLOC * FDIM;
  float* part = (float*)(h_lo + (size_t)RALLOC * FDIM);
  float* Ppart = part + (size_t)2 * RALLOC * DDIM;
  float* P = Ppart + (size_t)8 * NEXP * NEXP * FDIM;
  float* wgtA = P + (size_t)NEXP * NEXP * FDIM;
  float* wgtB = wgtA + T_TOKENS * 2;
  int* eidA = (int*)(wgtB + T_TOKENS * 2);
  int* eidB = eidA + T_TOKENS * 2;
  int* posA = eidB + T_TOKENS * 2;
  int* posB = posA + T_TOKENS * 2;
  int* cnt = posB + T_TOKENS * 2;
  int* offp = cnt + NEXP;
  int* row2token = offp + NEXP;

  hipMemcpyAsync(xcur, x, (size_t)T_TOKENS * DDIM * sizeof(float),
                 hipMemcpyDeviceToDevice, stream);

  const float* protos2 = protos + (size_t)NEXP * DDIM;  // layer-1 protos

  // ---------------- layer 0 ----------------
  route_kernel<<<T_TOKENS, 256, 0, stream>>>(xcur, protos, eidA, wgtA);
  compact_kernel<<<1, 256, 0, stream>>>(eidA, cnt, offp, row2token, posA);
  gather_kernel<true><<<RMAX, 256, 0, stream>>>(xcur, row2token, Ag_hi, Ag_lo);
  // GEMM1 (split, f32-grade): h = relu(x @ W1), hi+lo
  wconv_kernel<true><<<dim3(FDIM / 128, DDIM / 32, NEXP), 256, 0, stream>>>(
      W1, W_hi, W_lo, DDIM, FDIM);
  gemm_split<<<dim3(FDIM / 128, RMAX / 64, NEXP), 256, 0, stream>>>(
      Ag_hi, Ag_lo, W_hi, W_lo, h_hi, h_lo, cnt, offp, DDIM, FDIM);
  // W2 convert (hi only) + P partials; reduce P
  wconv_p_kernel<<<dim3(DDIM / 128, FDIM / 32, NEXP), 256, 0, stream>>>(
      W2, W_hi, protos2, Ppart, FDIM, DDIM);
  reduce_p_kernel<<<NEXP * NEXP * FDIM / 256, 256, 0, stream>>>(Ppart, P);
  // GEMM2 plain bf16, split-K2
  gemm_plain<false, 0, 2><<<dim3(DDIM / 128, RMAX / 128, NEXP * 2), 256, 0, stream>>>(
      h_hi, W_hi, nullptr, part, cnt, offp, FDIM, DDIM);
  // layer-1 routing from x0 + exact correction (before apply mutates xcur)
  route2_kernel<<<T_TOKENS, 256, 0, stream>>>(
      xcur, protos2, h_hi, h_lo, P, eidA, posA, wgtA, eidB, wgtB);
  apply_kernel<<<T_TOKENS, 256, 0, stream>>>(part, posA, wgtA, xcur);

  // ---------------- layer 1 (all plain bf16) ----------------
  compact_kernel<<<1, 256, 0, stream>>>(eidB, cnt, offp, row2token, posB);
  gather_kernel<false><<<RMAX, 256, 0, stream>>>(xcur, row2token, Ag_hi, nullptr);
  wconv_kernel<false><<<dim3(FDIM / 128, DDIM / 32, NEXP), 256, 0, stream>>>(
      W1 + (size_t)NEXP * DDIM * FDIM, W_hi, nullptr, DDIM, FDIM);
  gemm_plain<true, 2, 1><<<dim3(FDIM / 128, RMAX / 128, NEXP), 256, 0, stream>>>(
      Ag_hi, W_hi, h_hi, nullptr, cnt, offp, DDIM, FDIM);
  wconv_kernel<false><<<dim3(DDIM / 128, FDIM / 32, NEXP), 256, 0, stream>>>(
      W2 + (size_t)NEXP * FDIM * DDIM, W_hi, nullptr, FDIM, DDIM);
  gemm_plain<false, 0, 2><<<dim3(DDIM / 128, RMAX / 128, NEXP * 2), 256, 0, stream>>>(
      h_hi, W_hi, nullptr, part, cnt, offp, FDIM, DDIM);
  apply_kernel<<<T_TOKENS, 256, 0, stream>>>(part, posB, wgtB, xcur);
}

// Round 10
// 357.177 us; speedup vs baseline: 1.1001x; 1.0267x over previous
//
#include <hip/hip_runtime.h>
#include <hip/hip_bf16.h>
#include <cstdint>

// Problem constants (B=2,S=1024,D=1024; L=2,E=8,F=2048; k=2)
#define T_TOKENS 2048
#define DDIM 1024
#define FDIM 2048
#define NEXP 8
#define NLAYER 2
#define BMPAD 64           // per-expert row padding granularity
#define RMAX 4608          // 2048*2 + 8*63 = 4537 -> 64-multiple
#define RALLOC 4736        // +128 slack rows (128-row M-tiles may overhang)

// A-operand tiles: 64 rows x 32 k, 2048 el (4 KB), order ((ksel*64+row)*8 + (k&7)),
//   ksel=(k>>3)&3 -- exactly MFMA fragment order for 16x16x32 bf16.
// B-operand tiles: 128 cols x 32 k, 4096 el (8 KB), order ((ksel*128+col)*8 + (k&7)).
// Linear LDS copy of a tile is fragment-readable conflict-free (b128, 16B x 16 lanes).
#define ATILE_EL 2048
#define BTILE_EL 4096

typedef unsigned short u16;
typedef short bf16x8 __attribute__((ext_vector_type(8)));
typedef u16 u16x8 __attribute__((ext_vector_type(8)));
typedef u16 u16x4v __attribute__((ext_vector_type(4)));
typedef float f32x4 __attribute__((ext_vector_type(4)));

// counted-vmcnt pipeline primitives (T4): raw barrier, no compiler vmcnt(0) drain
#define VMCNT(n) asm volatile("s_waitcnt vmcnt(" #n ")" ::: "memory")
#define SB() __builtin_amdgcn_sched_barrier(0)
#define BAR() __builtin_amdgcn_s_barrier()

__device__ __forceinline__ u16 bf16_rn(float f) {
  unsigned u = __builtin_bit_cast(unsigned, f);
  u += 0x7fffu + ((u >> 16) & 1u);
  return (u16)(u >> 16);
}
__device__ __forceinline__ float bf16_f(u16 h) {
  unsigned u = ((unsigned)h) << 16;
  return __builtin_bit_cast(float, u);
}

__device__ __forceinline__ void gl16(const void* g, void* l) {
  __builtin_amdgcn_global_load_lds((const __attribute__((address_space(1))) void*)g,
                                   (__attribute__((address_space(3))) void*)l, 16, 0, 0);
}

// XCD-aware bijective swizzle: nwg divisible by 8 for all our GEMM grids.
__device__ __forceinline__ void xcd_swizzle(int& bx, int& by, int& bz) {
  const unsigned gx = gridDim.x, gy = gridDim.y;
  const unsigned lin = blockIdx.x + gx * (blockIdx.y + gy * blockIdx.z);
  const unsigned nwg = gx * gy * gridDim.z;
  const unsigned nl = (lin & 7u) * (nwg >> 3) + (lin >> 3);
  bx = nl % gx;
  const unsigned t = nl / gx;
  by = t % gy;
  bz = t / gy;
}

// ---------------- routing layer 0 ----------------
__global__ __launch_bounds__(256) void route_kernel(
    const float* __restrict__ x, const float* __restrict__ protos,
    int* __restrict__ eid, float* __restrict__ wgt) {
  const int t = blockIdx.x;
  const int tid = threadIdx.x;
  const float4* xr4 = (const float4*)(x + (size_t)t * DDIM);
  const float4* pr4 = (const float4*)protos;
  __shared__ float red[NEXP][256];
  const float4 xv = xr4[tid];
  float acc[NEXP];
#pragma unroll
  for (int e = 0; e < NEXP; ++e) {
    const float4 p = pr4[e * 256 + tid];
    acc[e] = xv.x * p.x + xv.y * p.y + xv.z * p.z + xv.w * p.w;
  }
#pragma unroll
  for (int e = 0; e < NEXP; ++e) red[e][tid] = acc[e];
  __syncthreads();
  for (int s = 128; s > 0; s >>= 1) {
    if (tid < s) {
#pragma unroll
      for (int e = 0; e < NEXP; ++e) red[e][tid] += red[e][tid + s];
    }
    __syncthreads();
  }
  if (tid == 0) {
    float m1 = -1.f, m2 = -1.f;
    int i1 = 0, i2 = 0;
#pragma unroll
    for (int e = 0; e < NEXP; ++e) {
      float s = fabsf(red[e][0]);
      if (s > m1) { m2 = m1; i2 = i1; m1 = s; i1 = e; }
      else if (s > m2) { m2 = s; i2 = e; }
    }
    float e2 = __expf(m2 - m1);
    float z = 1.f + e2;
    eid[t * 2] = i1;
    eid[t * 2 + 1] = i2;
    wgt[t * 2] = 1.f / z;
    wgt[t * 2 + 1] = e2 / z;
  }
}

// -------- routing layer 1: score2 = x0.p2 + sum_s w_s * (h[row_s] . P[e_s]) --------
__global__ __launch_bounds__(256) void route2_kernel(
    const float* __restrict__ x, const float* __restrict__ protos2,
    const u16* __restrict__ h_hi, const u16* __restrict__ h_lo,
    const float* __restrict__ P, const int* __restrict__ eidA,
    const int* __restrict__ pos, const float* __restrict__ wgtA,
    int* __restrict__ eidB, float* __restrict__ wgtB) {
  const int t = blockIdx.x;
  const int tid = threadIdx.x;
  __shared__ float red[NEXP][256];
  const float4 xv = ((const float4*)(x + (size_t)t * DDIM))[tid];
  float acc[NEXP];
#pragma unroll
  for (int e = 0; e < NEXP; ++e) {
    const float4 p = ((const float4*)protos2)[e * 256 + tid];
    acc[e] = xv.x * p.x + xv.y * p.y + xv.z * p.z + xv.w * p.w;
  }
  const int p0 = pos[t * 2], p1 = pos[t * 2 + 1];
  const int e0 = eidA[t * 2], e1 = eidA[t * 2 + 1];
  const float w0 = wgtA[t * 2], w1 = wgtA[t * 2 + 1];
  const int f0 = tid * 8;
  const int nkbF = FDIM >> 5;
  float h0[8], h1[8];
  {
    const size_t el0 = ((size_t)(p0 >> 6) * nkbF + (f0 >> 5)) * ATILE_EL +
                       (size_t)((((f0 >> 3) & 3) * 64 + (p0 & 63)) * 8);
    const size_t el1 = ((size_t)(p1 >> 6) * nkbF + (f0 >> 5)) * ATILE_EL +
                       (size_t)((((f0 >> 3) & 3) * 64 + (p1 & 63)) * 8);
    u16x8 a = *(const u16x8*)&h_hi[el0], b = *(const u16x8*)&h_lo[el0];
    u16x8 c = *(const u16x8*)&h_hi[el1], d = *(const u16x8*)&h_lo[el1];
#pragma unroll
    for (int j = 0; j < 8; ++j) {
      h0[j] = bf16_f(a[j]) + bf16_f(b[j]);
      h1[j] = bf16_f(c[j]) + bf16_f(d[j]);
    }
  }
#pragma unroll
  for (int e2 = 0; e2 < NEXP; ++e2) {
    const float* P0 = P + ((size_t)(e0 * NEXP + e2)) * FDIM + f0;
    const float* P1 = P + ((size_t)(e1 * NEXP + e2)) * FDIM + f0;
    float c = 0.f;
#pragma unroll
    for (int j = 0; j < 8; ++j) c += w0 * h0[j] * P0[j] + w1 * h1[j] * P1[j];
    acc[e2] += c;
  }
#pragma unroll
  for (int e = 0; e < NEXP; ++e) red[e][tid] = acc[e];
  __syncthreads();
  for (int s = 128; s > 0; s >>= 1) {
    if (tid < s) {
#pragma unroll
      for (int e = 0; e < NEXP; ++e) red[e][tid] += red[e][tid + s];
    }
    __syncthreads();
  }
  if (tid == 0) {
    float m1 = -1.f, m2 = -1.f;
    int i1 = 0, i2 = 0;
#pragma unroll
    for (int e = 0; e < NEXP; ++e) {
      float s = fabsf(red[e][0]);
      if (s > m1) { m2 = m1; i2 = i1; m1 = s; i1 = e; }
      else if (s > m2) { m2 = s; i2 = e; }
    }
    float e2 = __expf(m2 - m1);
    float z = 1.f + e2;
    eidB[t * 2] = i1;
    eidB[t * 2 + 1] = i2;
    wgtB[t * 2] = 1.f / z;
    wgtB[t * 2 + 1] = e2 / z;
  }
}

// ------------- compaction (padded to 64) -------------
__global__ __launch_bounds__(256) void compact_kernel(
    const int* __restrict__ eid, int* __restrict__ cnt, int* __restrict__ offp,
    int* __restrict__ row2token, int* __restrict__ pos) {
  __shared__ int lcnt[NEXP][256];
  __shared__ int s_off[NEXP], s_tot[NEXP];
  const int tid = threadIdx.x;
  const int base = tid * 16;

  int my[16];
#pragma unroll
  for (int i = 0; i < 4; ++i)
    *(int4*)&my[i * 4] = *(const int4*)(eid + base + i * 4);

#pragma unroll
  for (int e = 0; e < NEXP; ++e) {
    int c = 0;
#pragma unroll
    for (int i = 0; i < 16; ++i) c += (my[i] == e) ? 1 : 0;
    lcnt[e][tid] = c;
  }

  for (int r = tid; r < RMAX; r += 256) row2token[r] = -1;
  __syncthreads();

  if (tid < NEXP) {
    int run = 0;
    for (int i = 0; i < 256; ++i) {
      int v = lcnt[tid][i];
      lcnt[tid][i] = run;
      run += v;
    }
    s_tot[tid] = run;
  }
  __syncthreads();
  if (tid == 0) {
    int o = 0;
    for (int e = 0; e < NEXP; ++e) {
      s_off[e] = o;
      o += (s_tot[e] + BMPAD - 1) & ~(BMPAD - 1);
    }
  }
  __syncthreads();

  int myoff[NEXP];
#pragma unroll
  for (int e = 0; e < NEXP; ++e) myoff[e] = s_off[e] + lcnt[e][tid];
#pragma unroll
  for (int i = 0; i < 16; ++i) {
    int r = 0;
#pragma unroll
    for (int e = 0; e < NEXP; ++e) r = (my[i] == e) ? myoff[e] : r;
    row2token[r] = (base + i) >> 1;
    pos[base + i] = r;
#pragma unroll
    for (int e = 0; e < NEXP; ++e) myoff[e] += (my[i] == e) ? 1 : 0;
  }

  if (tid < NEXP) {
    cnt[tid] = s_tot[tid];
    offp[tid] = s_off[tid];
  }
}

// ------------- gather x rows -> bf16 hi(/lo) A-tiled buffers -------------
template <bool LO>
__global__ __launch_bounds__(256) void gather_kernel(
    const float* __restrict__ x, const int* __restrict__ row2token,
    u16* __restrict__ Ahi, u16* __restrict__ Alo) {
  const int r = blockIdx.x;
  const int t = row2token[r];
  const int c = threadIdx.x * 4;
  float4 v = make_float4(0.f, 0.f, 0.f, 0.f);
  if (t >= 0) v = *(const float4*)(x + (size_t)t * DDIM + c);
  float vv[4] = {v.x, v.y, v.z, v.w};
  u16x4v hi, lo;
#pragma unroll
  for (int i = 0; i < 4; ++i) {
    u16 h = bf16_rn(vv[i]);
    hi[i] = h;
    if (LO) lo[i] = bf16_rn(vv[i] - bf16_f(h));
  }
  const size_t el = ((size_t)(r >> 6) * (DDIM >> 5) + (c >> 5)) * ATILE_EL +
                    (size_t)(((c >> 3) & 3) * 64 + (r & 63)) * 8 + (c & 7);
  *(u16x4v*)(Ahi + el) = hi;
  if (LO) *(u16x4v*)(Alo + el) = lo;
}

// ------------- W convert: f32 [e][K][N] -> bf16 hi(/lo) B-tiled [e][N/128][K/32] -------------
template <bool LO>
__global__ __launch_bounds__(256) void wconv_kernel(
    const float* __restrict__ W, u16* __restrict__ Hi, u16* __restrict__ Lo,
    int K, int N) {
  const int e = blockIdx.z, nb = blockIdx.x, kb = blockIdx.y;
  const float* Wp = W + ((size_t)e * K + (size_t)kb * 32) * N + nb * 128;
  __shared__ float tile[32][129];
  const int t = threadIdx.x;
#pragma unroll
  for (int i = 0; i < 4; ++i) {
    const int f4 = i * 256 + t;
    const int kr = f4 >> 5;
    const int c4 = (f4 & 31) * 4;
    float4 v = *(const float4*)(Wp + (size_t)kr * N + c4);
    *(float4*)&tile[kr][c4] = v;
  }
  __syncthreads();
  const size_t tb = (((size_t)e * (N >> 7) + nb) * (K >> 5) + kb) * BTILE_EL;
#pragma unroll
  for (int j = 0; j < 2; ++j) {
    const int cid = j * 256 + t;
    const int n = cid & 127, ksel = cid >> 7;
    u16x8 hv, lv;
#pragma unroll
    for (int i = 0; i < 8; ++i) {
      float f = tile[ksel * 8 + i][n];
      u16 h = bf16_rn(f);
      hv[i] = h;
      if (LO) lv[i] = bf16_rn(f - bf16_f(h));
    }
    *(u16x8*)(Hi + tb + (size_t)cid * 8) = hv;
    if (LO) *(u16x8*)(Lo + tb + (size_t)cid * 8) = lv;
  }
}

// ------------- W2 convert (hi only) + P partials -------------
__global__ __launch_bounds__(256) void wconv_p_kernel(
    const float* __restrict__ W, u16* __restrict__ Hi,
    const float* __restrict__ proto2, float* __restrict__ Ppart, int K, int N) {
  const int e = blockIdx.z, nb = blockIdx.x, kb = blockIdx.y;
  const float* Wp = W + ((size_t)e * K + (size_t)kb * 32) * N + nb * 128;
  __shared__ float tile[32][129];
  __shared__ float pr[NEXP][128];
  const int t = threadIdx.x;
#pragma unroll
  for (int i = 0; i < 4; ++i) {
    const int f4 = i * 256 + t;
    const int kr = f4 >> 5;
    const int c4 = (f4 & 31) * 4;
    float4 v = *(const float4*)(Wp + (size_t)kr * N + c4);
    *(float4*)&tile[kr][c4] = v;
  }
  {
    const int idx = t * 4;
    const int e2 = idx >> 7, n = idx & 127;
    *(float4*)&pr[e2][n] = *(const float4*)(proto2 + (size_t)e2 * DDIM + nb * 128 + n);
  }
  __syncthreads();
  const size_t tb = (((size_t)e * (N >> 7) + nb) * (K >> 5) + kb) * BTILE_EL;
#pragma unroll
  for (int j = 0; j < 2; ++j) {
    const int cid = j * 256 + t;
    const int n = cid & 127, ksel = cid >> 7;
    u16x8 hv;
#pragma unroll
    for (int i = 0; i < 8; ++i) hv[i] = bf16_rn(tile[ksel * 8 + i][n]);
    *(u16x8*)(Hi + tb + (size_t)cid * 8) = hv;
  }
  const int e2 = t >> 5, f = t & 31;
  float s = 0.f;
#pragma unroll 16
  for (int n = 0; n < 128; ++n) s += tile[f][n] * pr[e2][n];
  Ppart[(((size_t)nb * NEXP + e) * NEXP + e2) * FDIM + kb * 32 + f] = s;
}

// ------------- reduce P partials over nb (deterministic order) -------------
__global__ __launch_bounds__(256) void reduce_p_kernel(
    const float* __restrict__ Ppart, float* __restrict__ P) {
  const int i = blockIdx.x * 256 + threadIdx.x;
  float s = 0.f;
#pragma unroll
  for (int nb = 0; nb < 8; ++nb) s += Ppart[(size_t)nb * (NEXP * NEXP * FDIM) + i];
  P[i] = s;
}

// ------------- SPLIT GEMM (f32-grade): 64x128 block, 32x64 waves, BK=32, dbuf -------------
// Counted-vmcnt pipeline: 6 gl16/wave/tile (symmetric), vmcnt(6) + raw barriers.
__global__ __launch_bounds__(256, 3) void gemm_split(
    const u16* __restrict__ Ahi, const u16* __restrict__ Alo,
    const u16* __restrict__ Bhi, const u16* __restrict__ Blo,
    u16* __restrict__ OutHi, u16* __restrict__ OutLo,
    const int* __restrict__ cnt, const int* __restrict__ offp, int K, int N) {
  int bx, by, bz;
  xcd_swizzle(bx, by, bz);
  const int e = bz;
  const int cp = (cnt[e] + 63) & ~63;
  if (by * 64 >= cp) return;
  const int row0 = offp[e] + by * 64;
  const int n0 = bx * 128;
  const int nkb = K >> 5;

  constexpr int BUF_EL = 12288;  // [AsH 4KB | AsL 4KB | BsH 8KB | BsL 8KB] = 24 KB
  __shared__ u16 lds[2 * BUF_EL];

  const int tid = threadIdx.x;
  const int lane = tid & 63;
  const int wid = tid >> 6;
  const int wr = wid >> 1, wc = wid & 1;     // 2x2 waves, 32x64 each
  const int lr = lane & 15, kg = lane >> 4;
  const int lo16 = lane << 4;

  f32x4 acc[2][4];
#pragma unroll
  for (int i = 0; i < 2; ++i)
#pragma unroll
    for (int j = 0; j < 4; ++j)
#pragma unroll
      for (int r = 0; r < 4; ++r) acc[i][j][r] = 0.f;

  const size_t abase = (size_t)(row0 >> 6) * nkb;
  const size_t bbase = ((size_t)e * (N >> 7) + (n0 >> 7)) * nkb;

  // symmetric staging: exactly 6 gl16 per wave per tile (vmcnt arithmetic)
  auto STAGE = [&](int kb, int b) {
    char* d = (char*)(lds + b * BUF_EL);
    const char* gah = (const char*)(Ahi + (abase + kb) * ATILE_EL);
    const char* gal = (const char*)(Alo + (abase + kb) * ATILE_EL);
    const char* gbh = (const char*)(Bhi + (bbase + kb) * BTILE_EL);
    const char* gbl = (const char*)(Blo + (bbase + kb) * BTILE_EL);
    if (wid == 0) {
      gl16(gah + 0 * 1024 + lo16, d + 0 * 1024);
      gl16(gah + 1 * 1024 + lo16, d + 1 * 1024);
      gl16(gah + 2 * 1024 + lo16, d + 2 * 1024);
      gl16(gah + 3 * 1024 + lo16, d + 3 * 1024);
      gl16(gal + 0 * 1024 + lo16, d + 4096 + 0 * 1024);
      gl16(gal + 1 * 1024 + lo16, d + 4096 + 1 * 1024);
    } else if (wid == 1) {
      gl16(gal + 2 * 1024 + lo16, d + 4096 + 2 * 1024);
      gl16(gal + 3 * 1024 + lo16, d + 4096 + 3 * 1024);
      gl16(gbh + 0 * 1024 + lo16, d + 8192 + 0 * 1024);
      gl16(gbh + 1 * 1024 + lo16, d + 8192 + 1 * 1024);
      gl16(gbh + 2 * 1024 + lo16, d + 8192 + 2 * 1024);
      gl16(gbh + 3 * 1024 + lo16, d + 8192 + 3 * 1024);
    } else if (wid == 2) {
      gl16(gbh + 4 * 1024 + lo16, d + 8192 + 4 * 1024);
      gl16(gbh + 5 * 1024 + lo16, d + 8192 + 5 * 1024);
      gl16(gbh + 6 * 1024 + lo16, d + 8192 + 6 * 1024);
      gl16(gbh + 7 * 1024 + lo16, d + 8192 + 7 * 1024);
      gl16(gbl + 0 * 1024 + lo16, d + 16384 + 0 * 1024);
      gl16(gbl + 1 * 1024 + lo16, d + 16384 + 1 * 1024);
    } else {
      gl16(gbl + 2 * 1024 + lo16, d + 16384 + 2 * 1024);
      gl16(gbl + 3 * 1024 + lo16, d + 16384 + 3 * 1024);
      gl16(gbl + 4 * 1024 + lo16, d + 16384 + 4 * 1024);
      gl16(gbl + 5 * 1024 + lo16, d + 16384 + 5 * 1024);
      gl16(gbl + 6 * 1024 + lo16, d + 16384 + 6 * 1024);
      gl16(gbl + 7 * 1024 + lo16, d + 16384 + 7 * 1024);
    }
  };

  STAGE(0, 0);
  int cur = 0;
  for (int kb = 0; kb < nkb; ++kb) {
    const bool pf = (kb + 1 < nkb);
    if (pf) STAGE(kb + 1, cur ^ 1);  // 6 new in flight; tile-kb's 6 are oldest
    if (pf) { VMCNT(6); } else { VMCNT(0); }  // own tile-kb loads landed
    SB(); BAR(); SB();  // all waves' tile-kb loads landed; prefetch stays in flight

    const u16* buf = lds + cur * BUF_EL;
    const u16* AsH = buf;
    const u16* AsL = buf + 2048;
    const u16* BsH = buf + 4096;
    const u16* BsL = buf + 8192;
    const int arow = (kg * 64 + wr * 32 + lr) * 8;
    const int bcol = (kg * 128 + wc * 64 + lr) * 8;

    bf16x8 ah0 = *(const bf16x8*)&AsH[arow];
    bf16x8 ah1 = *(const bf16x8*)&AsH[arow + 128];
    bf16x8 bh[4];
#pragma unroll
    for (int j = 0; j < 4; ++j) bh[j] = *(const bf16x8*)&BsH[bcol + j * 128];
#pragma unroll
    for (int j = 0; j < 4; ++j) {
      acc[0][j] = __builtin_amdgcn_mfma_f32_16x16x32_bf16(ah0, bh[j], acc[0][j], 0, 0, 0);
      acc[1][j] = __builtin_amdgcn_mfma_f32_16x16x32_bf16(ah1, bh[j], acc[1][j], 0, 0, 0);
    }
    bf16x8 al0 = *(const bf16x8*)&AsL[arow];
    bf16x8 al1 = *(const bf16x8*)&AsL[arow + 128];
#pragma unroll
    for (int j = 0; j < 4; ++j) {
      bf16x8 bl = *(const bf16x8*)&BsL[bcol + j * 128];
      acc[0][j] = __builtin_amdgcn_mfma_f32_16x16x32_bf16(ah0, bl, acc[0][j], 0, 0, 0);
      acc[1][j] = __builtin_amdgcn_mfma_f32_16x16x32_bf16(ah1, bl, acc[1][j], 0, 0, 0);
      acc[0][j] = __builtin_amdgcn_mfma_f32_16x16x32_bf16(al0, bh[j], acc[0][j], 0, 0, 0);
      acc[1][j] = __builtin_amdgcn_mfma_f32_16x16x32_bf16(al1, bh[j], acc[1][j], 0, 0, 0);
    }
    SB(); BAR(); SB();  // reads of buf done before next iter's STAGE overwrites it
    cur ^= 1;
  }

  // epilogue: relu + hi/lo A-tiled write
  const int nkbO = N >> 5;
#pragma unroll
  for (int i = 0; i < 2; ++i) {
#pragma unroll
    for (int j = 0; j < 4; ++j) {
      const int Cj = n0 + wc * 64 + j * 16 + lr;
      f32x4 v = acc[i][j];
#pragma unroll
      for (int r = 0; r < 4; ++r) {
        const int R = row0 + wr * 32 + i * 16 + kg * 4 + r;
        float f = fmaxf(v[r], 0.f);
        const size_t el = ((size_t)(R >> 6) * nkbO + (Cj >> 5)) * ATILE_EL +
                          (size_t)(((Cj >> 3) & 3) * 64 + (R & 63)) * 8 + (Cj & 7);
        u16 h = bf16_rn(f);
        OutHi[el] = h;
        OutLo[el] = bf16_rn(f - bf16_f(h));
      }
    }
  }
}

// ------------- PLAIN GEMM (bf16): 128x128 block, 64x64 waves, BK=32, dbuf -------------
// Counted-vmcnt pipeline: 4 gl16/wave/tile (symmetric), vmcnt(4) + raw barriers.
// OUTMODE 0: f32 part[sk]; 2: bf16 hi A-tiled. SKF: split-K factor.
template <bool RELU, int OUTMODE, int SKF>
__global__ __launch_bounds__(256, 4) void gemm_plain(
    const u16* __restrict__ Ahi, const u16* __restrict__ Bhi,
    u16* __restrict__ OutHi, float* __restrict__ OutF,
    const int* __restrict__ cnt, const int* __restrict__ offp, int K, int N) {
  int bx, by, bz;
  xcd_swizzle(bx, by, bz);
  const int e = bz / SKF, sk = bz % SKF;
  const int cp = (cnt[e] + 63) & ~63;
  if (by * 128 >= cp) return;
  const int row0 = offp[e] + by * 128;
  const int rend = offp[e] + cp;
  const int n0 = bx * 128;
  const int nkb = K >> 5;
  const int kbN = nkb / SKF;
  const int kb0 = sk * kbN;

  constexpr int BUF_EL = 8192;  // [A0 4KB | A1 4KB | B 8KB] = 16 KB
  __shared__ u16 lds[2 * BUF_EL];

  const int tid = threadIdx.x;
  const int lane = tid & 63;
  const int wid = tid >> 6;
  const int wr = wid >> 1, wc = wid & 1;     // 2x2 waves, 64x64 each
  const int lr = lane & 15, kg = lane >> 4;
  const int lo16 = lane << 4;

  f32x4 acc[4][4];
#pragma unroll
  for (int i = 0; i < 4; ++i)
#pragma unroll
    for (int j = 0; j < 4; ++j)
#pragma unroll
      for (int r = 0; r < 4; ++r) acc[i][j][r] = 0.f;

  const int at0 = row0 >> 6;  // two consecutive 64-row A tiles
  const size_t bbase = ((size_t)e * (N >> 7) + (n0 >> 7)) * nkb;

  auto STAGE = [&](int kb, int b) {
    char* d = (char*)(lds + b * BUF_EL);
    if (wid < 2) {
      const char* g = (const char*)(Ahi + ((size_t)(at0 + wid) * nkb + kb) * ATILE_EL);
      gl16(g + 0 * 1024 + lo16, d + wid * 4096 + 0 * 1024);
      gl16(g + 1 * 1024 + lo16, d + wid * 4096 + 1 * 1024);
      gl16(g + 2 * 1024 + lo16, d + wid * 4096 + 2 * 1024);
      gl16(g + 3 * 1024 + lo16, d + wid * 4096 + 3 * 1024);
    } else {
      const char* g = (const char*)(Bhi + (bbase + kb) * BTILE_EL) + (wid - 2) * 4096;
      gl16(g + 0 * 1024 + lo16, d + 8192 + (wid - 2) * 4096 + 0 * 1024);
      gl16(g + 1 * 1024 + lo16, d + 8192 + (wid - 2) * 4096 + 1 * 1024);
      gl16(g + 2 * 1024 + lo16, d + 8192 + (wid - 2) * 4096 + 2 * 1024);
      gl16(g + 3 * 1024 + lo16, d + 8192 + (wid - 2) * 4096 + 3 * 1024);
    }
  };

  STAGE(kb0, 0);
  int cur = 0;
  for (int kb = kb0; kb < kb0 + kbN; ++kb) {
    const bool pf = (kb + 1 < kb0 + kbN);
    if (pf) STAGE(kb + 1, cur ^ 1);
    if (pf) { VMCNT(4); } else { VMCNT(0); }
    SB(); BAR(); SB();

    const u16* buf = lds + cur * BUF_EL;
    const u16* AsH = buf + wr * 2048;
    const u16* BsH = buf + 4096;
    const int arow = (kg * 64 + lr) * 8;
    const int bcol = (kg * 128 + wc * 64 + lr) * 8;

    bf16x8 ah[4], bh[4];
#pragma unroll
    for (int i = 0; i < 4; ++i) ah[i] = *(const bf16x8*)&AsH[arow + i * 128];
#pragma unroll
    for (int j = 0; j < 4; ++j) bh[j] = *(const bf16x8*)&BsH[bcol + j * 128];
#pragma unroll
    for (int i = 0; i < 4; ++i)
#pragma unroll
      for (int j = 0; j < 4; ++j)
        acc[i][j] = __builtin_amdgcn_mfma_f32_16x16x32_bf16(ah[i], bh[j], acc[i][j], 0, 0, 0);
    SB(); BAR(); SB();
    cur ^= 1;
  }

  const int nkbO = N >> 5;
#pragma unroll
  for (int i = 0; i < 4; ++i) {
#pragma unroll
    for (int j = 0; j < 4; ++j) {
      const int Cj = n0 + wc * 64 + j * 16 + lr;
      f32x4 v = acc[i][j];
#pragma unroll
      for (int r = 0; r < 4; ++r) {
        const int R = row0 + wr * 64 + i * 16 + kg * 4 + r;
        if (R >= rend) continue;  // 128-tile may overhang the 64-padded region
        float f = v[r];
        if (RELU) f = fmaxf(f, 0.f);
        if constexpr (OUTMODE == 0) {
          OutF[((size_t)sk * RALLOC + R) * N + Cj] = f;
        } else {
          const size_t el = ((size_t)(R >> 6) * nkbO + (Cj >> 5)) * ATILE_EL +
                            (size_t)(((Cj >> 3) & 3) * 64 + (R & 63)) * 8 + (Cj & 7);
          OutHi[el] = bf16_rn(f);
        }
      }
    }
  }
}

// ------------- apply: x[t] += w0*(P0+P1)[pos0] + w1*(P0+P1)[pos1] -------------
__global__ __launch_bounds__(256) void apply_kernel(
    const float* __restrict__ part, const int* __restrict__ pos,
    const float* __restrict__ wgt, float* __restrict__ x) {
  const int t = blockIdx.x;
  const int c = threadIdx.x * 4;
  const int p0 = pos[t * 2], p1 = pos[t * 2 + 1];
  const float w0 = wgt[t * 2], w1 = wgt[t * 2 + 1];
  const float* P1p = part + (size_t)RALLOC * DDIM;
  float4 xa = *(float4*)(x + (size_t)t * DDIM + c);
  float4 y0 = *(const float4*)(part + (size_t)p0 * DDIM + c);
  float4 y1 = *(const float4*)(part + (size_t)p1 * DDIM + c);
  const float4 b0 = *(const float4*)(P1p + (size_t)p0 * DDIM + c);
  const float4 b1 = *(const float4*)(P1p + (size_t)p1 * DDIM + c);
  y0.x += b0.x; y0.y += b0.y; y0.z += b0.z; y0.w += b0.w;
  y1.x += b1.x; y1.y += b1.y; y1.z += b1.z; y1.w += b1.w;
  xa.x += w0 * y0.x + w1 * y1.x;
  xa.y += w0 * y0.y + w1 * y1.y;
  xa.z += w0 * y0.z + w1 * y1.z;
  xa.w += w0 * y0.w + w1 * y1.w;
  *(float4*)(x + (size_t)t * DDIM + c) = xa;
}

extern "C" void kernel_launch(void* const* d_in, const int* in_sizes, int n_in,
                              void* d_out, int out_size, void* d_ws, size_t ws_size,
                              hipStream_t stream) {
  const float* x = (const float*)d_in[0];
  const float* protos = (const float*)d_in[1];
  const float* W1 = (const float*)d_in[2];
  const float* W2 = (const float*)d_in[3];
  float* xcur = (float*)d_out;

  u16* W_hi = (u16*)d_ws;
  u16* W_lo = W_hi + (size_t)NEXP * DDIM * FDIM;
  u16* Ag_hi = W_lo + (size_t)NEXP * DDIM * FDIM;
  u16* Ag_lo = Ag_hi + (size_t)RALLOC * DDIM;
  u16* h_hi = Ag_lo + (size_t)RALLOC * DDIM;
  u16* h_lo = h_hi + (size_t)RALLOC * FDIM;
  float* part = (float*)(h_lo + (size_t)RALLOC * FDIM);
  float* Ppart = part + (size_t)2 * RALLOC * DDIM;
  float* P = Ppart + (size_t)8 * NEXP * NEXP * FDIM;
  float* wgtA = P + (size_t)NEXP * NEXP * FDIM;
  float* wgtB = wgtA + T_TOKENS * 2;
  int* eidA = (int*)(wgtB + T_TOKENS * 2);
  int* eidB = eidA + T_TOKENS * 2;
  int* posA = eidB + T_TOKENS * 2;
  int* posB = posA + T_TOKENS * 2;
  int* cnt = posB + T_TOKENS * 2;
  int* offp = cnt + NEXP;
  int* row2token = offp + NEXP;

  hipMemcpyAsync(xcur, x, (size_t)T_TOKENS * DDIM * sizeof(float),
                 hipMemcpyDeviceToDevice, stream);

  const float* protos2 = protos + (size_t)NEXP * DDIM;

  // ---------------- layer 0 ----------------
  route_kernel<<<T_TOKENS, 256, 0, stream>>>(xcur, protos, eidA, wgtA);
  compact_kernel<<<1, 256, 0, stream>>>(eidA, cnt, offp, row2token, posA);
  gather_kernel<true><<<RMAX, 256, 0, stream>>>(xcur, row2token, Ag_hi, Ag_lo);
  wconv_kernel<true><<<dim3(FDIM / 128, DDIM / 32, NEXP), 256, 0, stream>>>(
      W1, W_hi, W_lo, DDIM, FDIM);
  gemm_split<<<dim3(FDIM / 128, RMAX / 64, NEXP), 256, 0, stream>>>(
      Ag_hi, Ag_lo, W_hi, W_lo, h_hi, h_lo, cnt, offp, DDIM, FDIM);
  wconv_p_kernel<<<dim3(DDIM / 128, FDIM / 32, NEXP), 256, 0, stream>>>(
      W2, W_hi, protos2, Ppart, FDIM, DDIM);
  reduce_p_kernel<<<NEXP * NEXP * FDIM / 256, 256, 0, stream>>>(Ppart, P);
  gemm_plain<false, 0, 2><<<dim3(DDIM / 128, RMAX / 128, NEXP * 2), 256, 0, stream>>>(
      h_hi, W_hi, nullptr, part, cnt, offp, FDIM, DDIM);
  route2_kernel<<<T_TOKENS, 256, 0, stream>>>(
      xcur, protos2, h_hi, h_lo, P, eidA, posA, wgtA, eidB, wgtB);
  apply_kernel<<<T_TOKENS, 256, 0, stream>>>(part, posA, wgtA, xcur);

  // ---------------- layer 1 (all plain bf16) ----------------
  compact_kernel<<<1, 256, 0, stream>>>(eidB, cnt, offp, row2token, posB);
  gather_kernel<false><<<RMAX, 256, 0, stream>>>(xcur, row2token, Ag_hi, nullptr);
  wconv_kernel<false><<<dim3(FDIM / 128, DDIM / 32, NEXP), 256, 0, stream>>>(
      W1 + (size_t)NEXP * DDIM * FDIM, W_hi, nullptr, DDIM, FDIM);
  gemm_plain<true, 2, 1><<<dim3(FDIM / 128, RMAX / 128, NEXP), 256, 0, stream>>>(
      Ag_hi, W_hi, h_hi, nullptr, cnt, offp, DDIM, FDIM);
  wconv_kernel<false><<<dim3(DDIM / 128, FDIM / 32, NEXP), 256, 0, stream>>>(
      W2 + (size_t)NEXP * FDIM * DDIM, W_hi, nullptr, FDIM, DDIM);
  gemm_plain<false, 0, 2><<<dim3(DDIM / 128, RMAX / 128, NEXP * 2), 256, 0, stream>>>(
      h_hi, W_hi, nullptr, part, cnt, offp, FDIM, DDIM);
  apply_kernel<<<T_TOKENS, 256, 0, stream>>>(part, posB, wgtB, xcur);
}

// Round 11
// 331.347 us; speedup vs baseline: 1.1859x; 1.0780x over previous
//
#include <hip/hip_runtime.h>
#include <hip/hip_bf16.h>
#include <cstdint>

// Problem constants (B=2,S=1024,D=1024; L=2,E=8,F=2048; k=2)
#define T_TOKENS 2048
#define DDIM 1024
#define FDIM 2048
#define NEXP 8
#define BMPAD 64
#define RMAX 4608          // 2048*2 + 8*63 = 4537 -> 64-multiple
#define RALLOC 4736        // +128 slack rows (128-row M-tiles may overhang)

// A tiles: 64r x 32k bf16 (4 KB) in MFMA fragment order; B tiles: 128c x 32k (8 KB).
#define ATILE_EL 2048
#define BTILE_EL 4096

typedef unsigned short u16;
typedef short bf16x8 __attribute__((ext_vector_type(8)));
typedef u16 u16x8 __attribute__((ext_vector_type(8)));
typedef u16 u16x4v __attribute__((ext_vector_type(4)));
typedef float f32x4 __attribute__((ext_vector_type(4)));

#define VMCNT(n) asm volatile("s_waitcnt vmcnt(" #n ")" ::: "memory")
#define SB() __builtin_amdgcn_sched_barrier(0)
#define BAR() __builtin_amdgcn_s_barrier()

__device__ __forceinline__ u16 bf16_rn(float f) {
  unsigned u = __builtin_bit_cast(unsigned, f);
  u += 0x7fffu + ((u >> 16) & 1u);
  return (u16)(u >> 16);
}
__device__ __forceinline__ float bf16_f(u16 h) {
  unsigned u = ((unsigned)h) << 16;
  return __builtin_bit_cast(float, u);
}
__device__ __forceinline__ void gl16(const void* g, void* l) {
  __builtin_amdgcn_global_load_lds((const __attribute__((address_space(1))) void*)g,
                                   (__attribute__((address_space(3))) void*)l, 16, 0, 0);
}

// XCD-aware bijective swizzle over a role-local linear id (role offsets are 8-divisible).
template <int GX, int GY, int GZ>
__device__ __forceinline__ void swz3(unsigned lin, int& bx, int& by, int& bz) {
  constexpr unsigned nwg = (unsigned)GX * GY * GZ;
  const unsigned nl = (lin & 7u) * (nwg >> 3) + (lin >> 3);
  bx = nl % GX;
  const unsigned t = nl / GX;
  by = t % GY;
  bz = t / GY;
}

// ================= device bodies =================

// ---- W convert: f32 [e][K][N] -> bf16 hi(/lo) B-tiled; smem >= 32*129*4 B ----
template <bool LO>
__device__ __forceinline__ void wconv_dev(
    int nb, int kb, int e, const float* __restrict__ W, u16* __restrict__ Hi,
    u16* __restrict__ Lo, int K, int N, float* tile /*[32][129]*/) {
  const float* Wp = W + ((size_t)e * K + (size_t)kb * 32) * N + nb * 128;
  const int t = threadIdx.x;
#pragma unroll
  for (int i = 0; i < 4; ++i) {
    const int f4 = i * 256 + t;
    const int kr = f4 >> 5;
    const int c4 = (f4 & 31) * 4;
    float4 v = *(const float4*)(Wp + (size_t)kr * N + c4);
    *(float4*)&tile[kr * 129 + c4] = v;
  }
  __syncthreads();
  const size_t tb = (((size_t)e * (N >> 7) + nb) * (K >> 5) + kb) * BTILE_EL;
#pragma unroll
  for (int j = 0; j < 2; ++j) {
    const int cid = j * 256 + t;
    const int n = cid & 127, ksel = cid >> 7;
    u16x8 hv, lv;
#pragma unroll
    for (int i = 0; i < 8; ++i) {
      float f = tile[(ksel * 8 + i) * 129 + n];
      u16 h = bf16_rn(f);
      hv[i] = h;
      if (LO) lv[i] = bf16_rn(f - bf16_f(h));
    }
    *(u16x8*)(Hi + tb + (size_t)cid * 8) = hv;
    if (LO) *(u16x8*)(Lo + tb + (size_t)cid * 8) = lv;
  }
}

// ---- W2 convert (hi) + P partials; smem >= (32*129 + 8*128)*4 B ----
__device__ __forceinline__ void wconv_p_dev(
    int nb, int kb, int e, const float* __restrict__ W, u16* __restrict__ Hi,
    const float* __restrict__ proto2, float* __restrict__ Ppart, int K, int N,
    float* smem) {
  float* tile = smem;              // [32][129]
  float* pr = smem + 32 * 129;     // [8][128]
  const float* Wp = W + ((size_t)e * K + (size_t)kb * 32) * N + nb * 128;
  const int t = threadIdx.x;
#pragma unroll
  for (int i = 0; i < 4; ++i) {
    const int f4 = i * 256 + t;
    const int kr = f4 >> 5;
    const int c4 = (f4 & 31) * 4;
    float4 v = *(const float4*)(Wp + (size_t)kr * N + c4);
    *(float4*)&tile[kr * 129 + c4] = v;
  }
  {
    const int idx = t * 4;
    const int e2 = idx >> 7, n = idx & 127;
    *(float4*)&pr[e2 * 128 + n] =
        *(const float4*)(proto2 + (size_t)e2 * DDIM + nb * 128 + n);
  }
  __syncthreads();
  const size_t tb = (((size_t)e * (N >> 7) + nb) * (K >> 5) + kb) * BTILE_EL;
#pragma unroll
  for (int j = 0; j < 2; ++j) {
    const int cid = j * 256 + t;
    const int n = cid & 127, ksel = cid >> 7;
    u16x8 hv;
#pragma unroll
    for (int i = 0; i < 8; ++i) hv[i] = bf16_rn(tile[(ksel * 8 + i) * 129 + n]);
    *(u16x8*)(Hi + tb + (size_t)cid * 8) = hv;
  }
  const int e2 = t >> 5, f = t & 31;
  float s = 0.f;
#pragma unroll 16
  for (int n = 0; n < 128; ++n) s += tile[f * 129 + n] * pr[e2 * 128 + n];
  Ppart[(((size_t)nb * NEXP + e) * NEXP + e2) * FDIM + kb * 32 + f] = s;
}

// ---- gather one row -> bf16 hi(/lo) A-tiled ----
template <bool LO>
__device__ __forceinline__ void gather_dev(
    int r, const float* __restrict__ x, const int* __restrict__ row2token,
    u16* __restrict__ Ahi, u16* __restrict__ Alo) {
  const int t = row2token[r];
  const int c = threadIdx.x * 4;
  float4 v = make_float4(0.f, 0.f, 0.f, 0.f);
  if (t >= 0) v = *(const float4*)(x + (size_t)t * DDIM + c);
  float vv[4] = {v.x, v.y, v.z, v.w};
  u16x4v hi, lo;
#pragma unroll
  for (int i = 0; i < 4; ++i) {
    u16 h = bf16_rn(vv[i]);
    hi[i] = h;
    if (LO) lo[i] = bf16_rn(vv[i] - bf16_f(h));
  }
  const size_t el = ((size_t)(r >> 6) * (DDIM >> 5) + (c >> 5)) * ATILE_EL +
                    (size_t)(((c >> 3) & 3) * 64 + (r & 63)) * 8 + (c & 7);
  *(u16x4v*)(Ahi + el) = hi;
  if (LO) *(u16x4v*)(Alo + el) = lo;
}

// ---- SPLIT GEMM body: 64x128 block, 32x64 waves, BK=32, dbuf, counted vmcnt ----
__device__ __forceinline__ void gemm_split_dev(
    unsigned lin, u16* lds, const u16* __restrict__ Ahi, const u16* __restrict__ Alo,
    const u16* __restrict__ Bhi, const u16* __restrict__ Blo,
    u16* __restrict__ OutHi, u16* __restrict__ OutLo,
    const int* __restrict__ cnt, const int* __restrict__ offp, int K, int N) {
  int bx, by, bz;
  swz3<FDIM / 128, RMAX / 64, NEXP>(lin, bx, by, bz);
  const int e = bz;
  const int cp = (cnt[e] + 63) & ~63;
  if (by * 64 >= cp) return;
  const int row0 = offp[e] + by * 64;
  const int n0 = bx * 128;
  const int nkb = K >> 5;
  constexpr int BUF_EL = 12288;

  const int tid = threadIdx.x;
  const int lane = tid & 63;
  const int wid = tid >> 6;
  const int wr = wid >> 1, wc = wid & 1;
  const int lr = lane & 15, kg = lane >> 4;
  const int lo16 = lane << 4;

  f32x4 acc[2][4];
#pragma unroll
  for (int i = 0; i < 2; ++i)
#pragma unroll
    for (int j = 0; j < 4; ++j)
#pragma unroll
      for (int r = 0; r < 4; ++r) acc[i][j][r] = 0.f;

  const size_t abase = (size_t)(row0 >> 6) * nkb;
  const size_t bbase = ((size_t)e * (N >> 7) + (n0 >> 7)) * nkb;

  auto STAGE = [&](int kb, int b) {  // exactly 6 gl16 per wave
    char* d = (char*)(lds + b * BUF_EL);
    const char* gah = (const char*)(Ahi + (abase + kb) * ATILE_EL);
    const char* gal = (const char*)(Alo + (abase + kb) * ATILE_EL);
    const char* gbh = (const char*)(Bhi + (bbase + kb) * BTILE_EL);
    const char* gbl = (const char*)(Blo + (bbase + kb) * BTILE_EL);
    if (wid == 0) {
      gl16(gah + 0 * 1024 + lo16, d + 0 * 1024);
      gl16(gah + 1 * 1024 + lo16, d + 1 * 1024);
      gl16(gah + 2 * 1024 + lo16, d + 2 * 1024);
      gl16(gah + 3 * 1024 + lo16, d + 3 * 1024);
      gl16(gal + 0 * 1024 + lo16, d + 4096 + 0 * 1024);
      gl16(gal + 1 * 1024 + lo16, d + 4096 + 1 * 1024);
    } else if (wid == 1) {
      gl16(gal + 2 * 1024 + lo16, d + 4096 + 2 * 1024);
      gl16(gal + 3 * 1024 + lo16, d + 4096 + 3 * 1024);
      gl16(gbh + 0 * 1024 + lo16, d + 8192 + 0 * 1024);
      gl16(gbh + 1 * 1024 + lo16, d + 8192 + 1 * 1024);
      gl16(gbh + 2 * 1024 + lo16, d + 8192 + 2 * 1024);
      gl16(gbh + 3 * 1024 + lo16, d + 8192 + 3 * 1024);
    } else if (wid == 2) {
      gl16(gbh + 4 * 1024 + lo16, d + 8192 + 4 * 1024);
      gl16(gbh + 5 * 1024 + lo16, d + 8192 + 5 * 1024);
      gl16(gbh + 6 * 1024 + lo16, d + 8192 + 6 * 1024);
      gl16(gbh + 7 * 1024 + lo16, d + 8192 + 7 * 1024);
      gl16(gbl + 0 * 1024 + lo16, d + 16384 + 0 * 1024);
      gl16(gbl + 1 * 1024 + lo16, d + 16384 + 1 * 1024);
    } else {
      gl16(gbl + 2 * 1024 + lo16, d + 16384 + 2 * 1024);
      gl16(gbl + 3 * 1024 + lo16, d + 16384 + 3 * 1024);
      gl16(gbl + 4 * 1024 + lo16, d + 16384 + 4 * 1024);
      gl16(gbl + 5 * 1024 + lo16, d + 16384 + 5 * 1024);
      gl16(gbl + 6 * 1024 + lo16, d + 16384 + 6 * 1024);
      gl16(gbl + 7 * 1024 + lo16, d + 16384 + 7 * 1024);
    }
  };

  STAGE(0, 0);
  int cur = 0;
  for (int kb = 0; kb < nkb; ++kb) {
    const bool pf = (kb + 1 < nkb);
    if (pf) STAGE(kb + 1, cur ^ 1);
    if (pf) { VMCNT(6); } else { VMCNT(0); }
    SB(); BAR(); SB();

    const u16* buf = lds + cur * BUF_EL;
    const u16* AsH = buf;
    const u16* AsL = buf + 2048;
    const u16* BsH = buf + 4096;
    const u16* BsL = buf + 8192;
    const int arow = (kg * 64 + wr * 32 + lr) * 8;
    const int bcol = (kg * 128 + wc * 64 + lr) * 8;

    bf16x8 ah0 = *(const bf16x8*)&AsH[arow];
    bf16x8 ah1 = *(const bf16x8*)&AsH[arow + 128];
    bf16x8 bh[4];
#pragma unroll
    for (int j = 0; j < 4; ++j) bh[j] = *(const bf16x8*)&BsH[bcol + j * 128];
#pragma unroll
    for (int j = 0; j < 4; ++j) {
      acc[0][j] = __builtin_amdgcn_mfma_f32_16x16x32_bf16(ah0, bh[j], acc[0][j], 0, 0, 0);
      acc[1][j] = __builtin_amdgcn_mfma_f32_16x16x32_bf16(ah1, bh[j], acc[1][j], 0, 0, 0);
    }
    bf16x8 al0 = *(const bf16x8*)&AsL[arow];
    bf16x8 al1 = *(const bf16x8*)&AsL[arow + 128];
#pragma unroll
    for (int j = 0; j < 4; ++j) {
      bf16x8 bl = *(const bf16x8*)&BsL[bcol + j * 128];
      acc[0][j] = __builtin_amdgcn_mfma_f32_16x16x32_bf16(ah0, bl, acc[0][j], 0, 0, 0);
      acc[1][j] = __builtin_amdgcn_mfma_f32_16x16x32_bf16(ah1, bl, acc[1][j], 0, 0, 0);
      acc[0][j] = __builtin_amdgcn_mfma_f32_16x16x32_bf16(al0, bh[j], acc[0][j], 0, 0, 0);
      acc[1][j] = __builtin_amdgcn_mfma_f32_16x16x32_bf16(al1, bh[j], acc[1][j], 0, 0, 0);
    }
    SB(); BAR(); SB();
    cur ^= 1;
  }

  const int nkbO = N >> 5;
#pragma unroll
  for (int i = 0; i < 2; ++i) {
#pragma unroll
    for (int j = 0; j < 4; ++j) {
      const int Cj = n0 + wc * 64 + j * 16 + lr;
      f32x4 v = acc[i][j];
#pragma unroll
      for (int r = 0; r < 4; ++r) {
        const int R = row0 + wr * 32 + i * 16 + kg * 4 + r;
        float f = fmaxf(v[r], 0.f);
        const size_t el = ((size_t)(R >> 6) * nkbO + (Cj >> 5)) * ATILE_EL +
                          (size_t)(((Cj >> 3) & 3) * 64 + (R & 63)) * 8 + (Cj & 7);
        u16 h = bf16_rn(f);
        OutHi[el] = h;
        OutLo[el] = bf16_rn(f - bf16_f(h));
      }
    }
  }
}

// ---- PLAIN GEMM body: 128x128 block, 64x64 waves, BK=32, dbuf, counted vmcnt ----
template <int GX, int GY, bool RELU, int OUTMODE>  // OUTMODE 0: f32 row-major; 2: bf16 hi A-tiled
__device__ __forceinline__ void gemm_plain_dev(
    unsigned lin, u16* lds, const u16* __restrict__ Ahi, const u16* __restrict__ Bhi,
    u16* __restrict__ OutHi, float* __restrict__ OutF,
    const int* __restrict__ cnt, const int* __restrict__ offp, int K, int N) {
  int bx, by, bz;
  swz3<GX, GY, NEXP>(lin, bx, by, bz);
  const int e = bz;
  const int cp = (cnt[e] + 63) & ~63;
  if (by * 128 >= cp) return;
  const int row0 = offp[e] + by * 128;
  const int rend = offp[e] + cp;
  const int n0 = bx * 128;
  const int nkb = K >> 5;
  constexpr int BUF_EL = 8192;

  const int tid = threadIdx.x;
  const int lane = tid & 63;
  const int wid = tid >> 6;
  const int wr = wid >> 1, wc = wid & 1;
  const int lr = lane & 15, kg = lane >> 4;
  const int lo16 = lane << 4;

  f32x4 acc[4][4];
#pragma unroll
  for (int i = 0; i < 4; ++i)
#pragma unroll
    for (int j = 0; j < 4; ++j)
#pragma unroll
      for (int r = 0; r < 4; ++r) acc[i][j][r] = 0.f;

  const int at0 = row0 >> 6;
  const size_t bbase = ((size_t)e * (N >> 7) + (n0 >> 7)) * nkb;

  auto STAGE = [&](int kb, int b) {  // exactly 4 gl16 per wave
    char* d = (char*)(lds + b * BUF_EL);
    if (wid < 2) {
      const char* g = (const char*)(Ahi + ((size_t)(at0 + wid) * nkb + kb) * ATILE_EL);
      gl16(g + 0 * 1024 + lo16, d + wid * 4096 + 0 * 1024);
      gl16(g + 1 * 1024 + lo16, d + wid * 4096 + 1 * 1024);
      gl16(g + 2 * 1024 + lo16, d + wid * 4096 + 2 * 1024);
      gl16(g + 3 * 1024 + lo16, d + wid * 4096 + 3 * 1024);
    } else {
      const char* g = (const char*)(Bhi + (bbase + kb) * BTILE_EL) + (wid - 2) * 4096;
      gl16(g + 0 * 1024 + lo16, d + 8192 + (wid - 2) * 4096 + 0 * 1024);
      gl16(g + 1 * 1024 + lo16, d + 8192 + (wid - 2) * 4096 + 1 * 1024);
      gl16(g + 2 * 1024 + lo16, d + 8192 + (wid - 2) * 4096 + 2 * 1024);
      gl16(g + 3 * 1024 + lo16, d + 8192 + (wid - 2) * 4096 + 3 * 1024);
    }
  };

  STAGE(0, 0);
  int cur = 0;
  for (int kb = 0; kb < nkb; ++kb) {
    const bool pf = (kb + 1 < nkb);
    if (pf) STAGE(kb + 1, cur ^ 1);
    if (pf) { VMCNT(4); } else { VMCNT(0); }
    SB(); BAR(); SB();

    const u16* buf = lds + cur * BUF_EL;
    const u16* AsH = buf + wr * 2048;
    const u16* BsH = buf + 4096;
    const int arow = (kg * 64 + lr) * 8;
    const int bcol = (kg * 128 + wc * 64 + lr) * 8;

    bf16x8 ah[4], bh[4];
#pragma unroll
    for (int i = 0; i < 4; ++i) ah[i] = *(const bf16x8*)&AsH[arow + i * 128];
#pragma unroll
    for (int j = 0; j < 4; ++j) bh[j] = *(const bf16x8*)&BsH[bcol + j * 128];
#pragma unroll
    for (int i = 0; i < 4; ++i)
#pragma unroll
      for (int j = 0; j < 4; ++j)
        acc[i][j] = __builtin_amdgcn_mfma_f32_16x16x32_bf16(ah[i], bh[j], acc[i][j], 0, 0, 0);
    SB(); BAR(); SB();
    cur ^= 1;
  }

  const int nkbO = N >> 5;
#pragma unroll
  for (int i = 0; i < 4; ++i) {
#pragma unroll
    for (int j = 0; j < 4; ++j) {
      const int Cj = n0 + wc * 64 + j * 16 + lr;
      f32x4 v = acc[i][j];
#pragma unroll
      for (int r = 0; r < 4; ++r) {
        const int R = row0 + wr * 64 + i * 16 + kg * 4 + r;
        if (R >= rend) continue;
        float f = v[r];
        if (RELU) f = fmaxf(f, 0.f);
        if constexpr (OUTMODE == 0) {
          OutF[(size_t)R * N + Cj] = f;
        } else {
          const size_t el = ((size_t)(R >> 6) * nkbO + (Cj >> 5)) * ATILE_EL +
                            (size_t)(((Cj >> 3) & 3) * 64 + (R & 63)) * 8 + (Cj & 7);
          OutHi[el] = bf16_rn(f);
        }
      }
    }
  }
}

// ================= global kernels =================

__global__ __launch_bounds__(256) void route_kernel(
    const float* __restrict__ x, const float* __restrict__ protos,
    int* __restrict__ eid, float* __restrict__ wgt) {
  const int t = blockIdx.x;
  const int tid = threadIdx.x;
  __shared__ float red[NEXP][256];
  const float4 xv = ((const float4*)(x + (size_t)t * DDIM))[tid];
  float acc[NEXP];
#pragma unroll
  for (int e = 0; e < NEXP; ++e) {
    const float4 p = ((const float4*)protos)[e * 256 + tid];
    acc[e] = xv.x * p.x + xv.y * p.y + xv.z * p.z + xv.w * p.w;
  }
#pragma unroll
  for (int e = 0; e < NEXP; ++e) red[e][tid] = acc[e];
  __syncthreads();
  for (int s = 128; s > 0; s >>= 1) {
    if (tid < s) {
#pragma unroll
      for (int e = 0; e < NEXP; ++e) red[e][tid] += red[e][tid + s];
    }
    __syncthreads();
  }
  if (tid == 0) {
    float m1 = -1.f, m2 = -1.f;
    int i1 = 0, i2 = 0;
#pragma unroll
    for (int e = 0; e < NEXP; ++e) {
      float s = fabsf(red[e][0]);
      if (s > m1) { m2 = m1; i2 = i1; m1 = s; i1 = e; }
      else if (s > m2) { m2 = s; i2 = e; }
    }
    float e2 = __expf(m2 - m1);
    float z = 1.f + e2;
    eid[t * 2] = i1;
    eid[t * 2 + 1] = i2;
    wgt[t * 2] = 1.f / z;
    wgt[t * 2 + 1] = e2 / z;
  }
}

__global__ __launch_bounds__(256) void route2_kernel(
    const float* __restrict__ x, const float* __restrict__ protos2,
    const u16* __restrict__ h_hi, const u16* __restrict__ h_lo,
    const float* __restrict__ P, const int* __restrict__ eidA,
    const int* __restrict__ pos, const float* __restrict__ wgtA,
    int* __restrict__ eidB, float* __restrict__ wgtB) {
  const int t = blockIdx.x;
  const int tid = threadIdx.x;
  __shared__ float red[NEXP][256];
  const float4 xv = ((const float4*)(x + (size_t)t * DDIM))[tid];
  float acc[NEXP];
#pragma unroll
  for (int e = 0; e < NEXP; ++e) {
    const float4 p = ((const float4*)protos2)[e * 256 + tid];
    acc[e] = xv.x * p.x + xv.y * p.y + xv.z * p.z + xv.w * p.w;
  }
  const int p0 = pos[t * 2], p1 = pos[t * 2 + 1];
  const int e0 = eidA[t * 2], e1 = eidA[t * 2 + 1];
  const float w0 = wgtA[t * 2], w1 = wgtA[t * 2 + 1];
  const int f0 = tid * 8;
  const int nkbF = FDIM >> 5;
  float h0[8], h1[8];
  {
    const size_t el0 = ((size_t)(p0 >> 6) * nkbF + (f0 >> 5)) * ATILE_EL +
                       (size_t)((((f0 >> 3) & 3) * 64 + (p0 & 63)) * 8);
    const size_t el1 = ((size_t)(p1 >> 6) * nkbF + (f0 >> 5)) * ATILE_EL +
                       (size_t)((((f0 >> 3) & 3) * 64 + (p1 & 63)) * 8);
    u16x8 a = *(const u16x8*)&h_hi[el0], b = *(const u16x8*)&h_lo[el0];
    u16x8 c = *(const u16x8*)&h_hi[el1], d = *(const u16x8*)&h_lo[el1];
#pragma unroll
    for (int j = 0; j < 8; ++j) {
      h0[j] = bf16_f(a[j]) + bf16_f(b[j]);
      h1[j] = bf16_f(c[j]) + bf16_f(d[j]);
    }
  }
#pragma unroll
  for (int e2 = 0; e2 < NEXP; ++e2) {
    const float* P0 = P + ((size_t)(e0 * NEXP + e2)) * FDIM + f0;
    const float* P1 = P + ((size_t)(e1 * NEXP + e2)) * FDIM + f0;
    float c = 0.f;
#pragma unroll
    for (int j = 0; j < 8; ++j) c += w0 * h0[j] * P0[j] + w1 * h1[j] * P1[j];
    acc[e2] += c;
  }
#pragma unroll
  for (int e = 0; e < NEXP; ++e) red[e][tid] = acc[e];
  __syncthreads();
  for (int s = 128; s > 0; s >>= 1) {
    if (tid < s) {
#pragma unroll
      for (int e = 0; e < NEXP; ++e) red[e][tid] += red[e][tid + s];
    }
    __syncthreads();
  }
  if (tid == 0) {
    float m1 = -1.f, m2 = -1.f;
    int i1 = 0, i2 = 0;
#pragma unroll
    for (int e = 0; e < NEXP; ++e) {
      float s = fabsf(red[e][0]);
      if (s > m1) { m2 = m1; i2 = i1; m1 = s; i1 = e; }
      else if (s > m2) { m2 = s; i2 = e; }
    }
    float e2 = __expf(m2 - m1);
    float z = 1.f + e2;
    eidB[t * 2] = i1;
    eidB[t * 2 + 1] = i2;
    wgtB[t * 2] = 1.f / z;
    wgtB[t * 2 + 1] = e2 / z;
  }
}

__device__ __forceinline__ void compact_dev(
    const int* __restrict__ eid, int* __restrict__ cnt, int* __restrict__ offp,
    int* __restrict__ row2token, int* __restrict__ pos, int* lcnt /* [8*256+16] ints */) {
  int* s_off = lcnt + NEXP * 256;
  int* s_tot = s_off + NEXP;
  const int tid = threadIdx.x;
  const int base = tid * 16;
  int my[16];
#pragma unroll
  for (int i = 0; i < 4; ++i)
    *(int4*)&my[i * 4] = *(const int4*)(eid + base + i * 4);
#pragma unroll
  for (int e = 0; e < NEXP; ++e) {
    int c = 0;
#pragma unroll
    for (int i = 0; i < 16; ++i) c += (my[i] == e) ? 1 : 0;
    lcnt[e * 256 + tid] = c;
  }
  for (int r = tid; r < RMAX; r += 256) row2token[r] = -1;
  __syncthreads();
  if (tid < NEXP) {
    int run = 0;
    for (int i = 0; i < 256; ++i) {
      int v = lcnt[tid * 256 + i];
      lcnt[tid * 256 + i] = run;
      run += v;
    }
    s_tot[tid] = run;
  }
  __syncthreads();
  if (tid == 0) {
    int o = 0;
    for (int e = 0; e < NEXP; ++e) {
      s_off[e] = o;
      o += (s_tot[e] + BMPAD - 1) & ~(BMPAD - 1);
    }
  }
  __syncthreads();
  int myoff[NEXP];
#pragma unroll
  for (int e = 0; e < NEXP; ++e) myoff[e] = s_off[e] + lcnt[e * 256 + tid];
#pragma unroll
  for (int i = 0; i < 16; ++i) {
    int r = 0;
#pragma unroll
    for (int e = 0; e < NEXP; ++e) r = (my[i] == e) ? myoff[e] : r;
    row2token[r] = (base + i) >> 1;
    pos[base + i] = r;
#pragma unroll
    for (int e = 0; e < NEXP; ++e) myoff[e] += (my[i] == e) ? 1 : 0;
  }
  if (tid < NEXP) {
    cnt[tid] = s_tot[tid];
    offp[tid] = s_off[tid];
  }
}

__global__ __launch_bounds__(256) void compact_kernel(
    const int* __restrict__ eid, int* __restrict__ cnt, int* __restrict__ offp,
    int* __restrict__ row2token, int* __restrict__ pos) {
  __shared__ int lcnt[NEXP * 256 + 16];
  compact_dev(eid, cnt, offp, row2token, pos, lcnt);
}

// C1: wconv W1l0 (hi+lo, 4096 blocks) then gather hi+lo (4608 blocks)
__global__ __launch_bounds__(256) void fusedC1_kernel(
    const float* __restrict__ W1, u16* __restrict__ W_hi, u16* __restrict__ W_lo,
    const float* __restrict__ x, const int* __restrict__ row2token,
    u16* __restrict__ Ag_hi, u16* __restrict__ Ag_lo) {
  __shared__ float smem[32 * 129];
  const unsigned lin = blockIdx.x;
  if (lin < 4096u) {
    const int nb = lin % 16;
    const int kb = (lin / 16) % 32;
    const int e = lin / 512;
    wconv_dev<true>(nb, kb, e, W1, W_hi, W_lo, DDIM, FDIM, smem);
  } else {
    gather_dev<true>((int)(lin - 4096u), x, row2token, Ag_hi, Ag_lo);
  }
}

// C2: gemm_split (9216) then wconv_p W2l0 -> W2A (4096)
__global__ __launch_bounds__(256, 3) void fusedC2_kernel(
    const u16* __restrict__ Ag_hi, const u16* __restrict__ Ag_lo,
    const u16* __restrict__ W_hi, const u16* __restrict__ W_lo,
    u16* __restrict__ h_hi, u16* __restrict__ h_lo,
    const int* __restrict__ cnt, const int* __restrict__ offp,
    const float* __restrict__ W2, u16* __restrict__ W2A,
    const float* __restrict__ proto2, float* __restrict__ Ppart) {
  __shared__ u16 lds[2 * 12288];  // 48 KB (covers wconv_p's 20.6 KB too)
  const unsigned lin = blockIdx.x;
  if (lin < 9216u) {
    gemm_split_dev(lin, lds, Ag_hi, Ag_lo, W_hi, W_lo, h_hi, h_lo, cnt, offp,
                   DDIM, FDIM);
  } else {
    const unsigned l2 = lin - 9216u;
    const int nb = l2 % 8;
    const int kb = (l2 / 8) % 64;
    const int e = l2 / 512;
    wconv_p_dev(nb, kb, e, W2, W2A, proto2, Ppart, FDIM, DDIM, (float*)lds);
  }
}

// C3: gemm_plain GEMM2-l0 (2304) | wconv W1l1->W_lo (4096) | wconv W2l1->W_hi (4096) | reduce_p (512)
__global__ __launch_bounds__(256, 4) void fusedC3_kernel(
    const u16* __restrict__ h_hi, const u16* __restrict__ W2A,
    float* __restrict__ part, const int* __restrict__ cnt, const int* __restrict__ offp,
    const float* __restrict__ W1b, u16* __restrict__ W_lo,
    const float* __restrict__ W2b, u16* __restrict__ W_hi,
    const float* __restrict__ Ppart, float* __restrict__ P) {
  __shared__ u16 lds[2 * 8192];  // 32 KB (covers wconv's 16.5 KB)
  const unsigned lin = blockIdx.x;
  if (lin < 2304u) {
    gemm_plain_dev<DDIM / 128, RMAX / 128, false, 0>(
        lin, lds, h_hi, W2A, nullptr, part, cnt, offp, FDIM, DDIM);
  } else if (lin < 6400u) {
    const unsigned l2 = lin - 2304u;
    wconv_dev<false>(l2 % 16, (l2 / 16) % 32, l2 / 512, W1b, W_lo, nullptr,
                     DDIM, FDIM, (float*)lds);
  } else if (lin < 10496u) {
    const unsigned l2 = lin - 6400u;
    wconv_dev<false>(l2 % 8, (l2 / 8) % 64, l2 / 512, W2b, W_hi, nullptr,
                     FDIM, DDIM, (float*)lds);
  } else {
    const int i = (int)(lin - 10496u) * 256 + threadIdx.x;
    float s = 0.f;
#pragma unroll
    for (int nb = 0; nb < 8; ++nb) s += Ppart[(size_t)nb * (NEXP * NEXP * FDIM) + i];
    P[i] = s;
  }
}

// D: apply (2048) | compact B (1)
__global__ __launch_bounds__(256) void fusedD_kernel(
    const float* __restrict__ part, const int* __restrict__ pos,
    const float* __restrict__ wgt, float* __restrict__ x,
    const int* __restrict__ eidB, int* __restrict__ cnt, int* __restrict__ offp,
    int* __restrict__ row2token, int* __restrict__ posB) {
  __shared__ int lcnt[NEXP * 256 + 16];
  const unsigned lin = blockIdx.x;
  if (lin < 2048u) {
    const int t = lin;
    const int c = threadIdx.x * 4;
    const int p0 = pos[t * 2], p1 = pos[t * 2 + 1];
    const float w0 = wgt[t * 2], w1 = wgt[t * 2 + 1];
    float4 xa = *(float4*)(x + (size_t)t * DDIM + c);
    const float4 y0 = *(const float4*)(part + (size_t)p0 * DDIM + c);
    const float4 y1 = *(const float4*)(part + (size_t)p1 * DDIM + c);
    xa.x += w0 * y0.x + w1 * y1.x;
    xa.y += w0 * y0.y + w1 * y1.y;
    xa.z += w0 * y0.z + w1 * y1.z;
    xa.w += w0 * y0.w + w1 * y1.w;
    *(float4*)(x + (size_t)t * DDIM + c) = xa;
  } else {
    compact_dev(eidB, cnt, offp, row2token, posB, lcnt);
  }
}

__global__ __launch_bounds__(256) void gather_kernel(
    const float* __restrict__ x, const int* __restrict__ row2token,
    u16* __restrict__ Ahi) {
  gather_dev<false>(blockIdx.x, x, row2token, Ahi, nullptr);
}

template <int GX, bool RELU, int OUTMODE>
__global__ __launch_bounds__(256, 4) void gemm_plain_kernel(
    const u16* __restrict__ Ahi, const u16* __restrict__ Bhi,
    u16* __restrict__ OutHi, float* __restrict__ OutF,
    const int* __restrict__ cnt, const int* __restrict__ offp, int K, int N) {
  __shared__ u16 lds[2 * 8192];
  gemm_plain_dev<GX, RMAX / 128, RELU, OUTMODE>(blockIdx.x, lds, Ahi, Bhi, OutHi,
                                                OutF, cnt, offp, K, N);
}

__global__ __launch_bounds__(256) void apply_kernel(
    const float* __restrict__ part, const int* __restrict__ pos,
    const float* __restrict__ wgt, float* __restrict__ x) {
  const int t = blockIdx.x;
  const int c = threadIdx.x * 4;
  const int p0 = pos[t * 2], p1 = pos[t * 2 + 1];
  const float w0 = wgt[t * 2], w1 = wgt[t * 2 + 1];
  float4 xa = *(float4*)(x + (size_t)t * DDIM + c);
  const float4 y0 = *(const float4*)(part + (size_t)p0 * DDIM + c);
  const float4 y1 = *(const float4*)(part + (size_t)p1 * DDIM + c);
  xa.x += w0 * y0.x + w1 * y1.x;
  xa.y += w0 * y0.y + w1 * y1.y;
  xa.z += w0 * y0.z + w1 * y1.z;
  xa.w += w0 * y0.w + w1 * y1.w;
  *(float4*)(x + (size_t)t * DDIM + c) = xa;
}

extern "C" void kernel_launch(void* const* d_in, const int* in_sizes, int n_in,
                              void* d_out, int out_size, void* d_ws, size_t ws_size,
                              hipStream_t stream) {
  const float* x = (const float*)d_in[0];
  const float* protos = (const float*)d_in[1];
  const float* W1 = (const float*)d_in[2];
  const float* W2 = (const float*)d_in[3];
  float* xcur = (float*)d_out;

  // ws (~183 MB): W_hi 33.5 | W_lo 33.5 | W2A 33.5 | Ag hi/lo 9.7 ea | h hi/lo 19.4 ea
  //             | part 19.4 | Ppart 4 | P 0.5 | meta
  u16* W_hi = (u16*)d_ws;
  u16* W_lo = W_hi + (size_t)NEXP * DDIM * FDIM;
  u16* W2A = W_lo + (size_t)NEXP * DDIM * FDIM;
  u16* Ag_hi = W2A + (size_t)NEXP * DDIM * FDIM;
  u16* Ag_lo = Ag_hi + (size_t)RALLOC * DDIM;
  u16* h_hi = Ag_lo + (size_t)RALLOC * DDIM;
  u16* h_lo = h_hi + (size_t)RALLOC * FDIM;
  float* part = (float*)(h_lo + (size_t)RALLOC * FDIM);
  float* Ppart = part + (size_t)RALLOC * DDIM;
  float* P = Ppart + (size_t)8 * NEXP * NEXP * FDIM;
  float* wgtA = P + (size_t)NEXP * NEXP * FDIM;
  float* wgtB = wgtA + T_TOKENS * 2;
  int* eidA = (int*)(wgtB + T_TOKENS * 2);
  int* eidB = eidA + T_TOKENS * 2;
  int* posA = eidB + T_TOKENS * 2;
  int* posB = posA + T_TOKENS * 2;
  int* cnt = posB + T_TOKENS * 2;
  int* offp = cnt + NEXP;
  int* row2token = offp + NEXP;

  hipMemcpyAsync(xcur, x, (size_t)T_TOKENS * DDIM * sizeof(float),
                 hipMemcpyDeviceToDevice, stream);

  const float* protos2 = protos + (size_t)NEXP * DDIM;
  const float* W1b = W1 + (size_t)NEXP * DDIM * FDIM;
  const float* W2b = W2 + (size_t)NEXP * FDIM * DDIM;

  // ---------------- layer 0 ----------------
  route_kernel<<<T_TOKENS, 256, 0, stream>>>(xcur, protos, eidA, wgtA);
  compact_kernel<<<1, 256, 0, stream>>>(eidA, cnt, offp, row2token, posA);
  fusedC1_kernel<<<4096 + RMAX, 256, 0, stream>>>(
      W1, W_hi, W_lo, xcur, row2token, Ag_hi, Ag_lo);
  fusedC2_kernel<<<9216 + 4096, 256, 0, stream>>>(
      Ag_hi, Ag_lo, W_hi, W_lo, h_hi, h_lo, cnt, offp, W2, W2A, protos2, Ppart);
  fusedC3_kernel<<<2304 + 4096 + 4096 + 512, 256, 0, stream>>>(
      h_hi, W2A, part, cnt, offp, W1b, W_lo, W2b, W_hi, Ppart, P);
  route2_kernel<<<T_TOKENS, 256, 0, stream>>>(
      xcur, protos2, h_hi, h_lo, P, eidA, posA, wgtA, eidB, wgtB);
  fusedD_kernel<<<2048 + 1, 256, 0, stream>>>(
      part, posA, wgtA, xcur, eidB, cnt, offp, row2token, posB);

  // ---------------- layer 1 (all plain bf16; W1l1=W_lo, W2l1=W_hi) ----------------
  gather_kernel<<<RMAX, 256, 0, stream>>>(xcur, row2token, Ag_hi);
  gemm_plain_kernel<FDIM / 128, true, 2><<<(FDIM / 128) * (RMAX / 128) * NEXP, 256, 0, stream>>>(
      Ag_hi, W_lo, h_hi, nullptr, cnt, offp, DDIM, FDIM);
  gemm_plain_kernel<DDIM / 128, false, 0><<<(DDIM / 128) * (RMAX / 128) * NEXP, 256, 0, stream>>>(
      h_hi, W_hi, nullptr, part, cnt, offp, FDIM, DDIM);
  apply_kernel<<<T_TOKENS, 256, 0, stream>>>(part, posB, wgtB, xcur);
}

// Round 13
// 331.329 us; speedup vs baseline: 1.1859x; 1.0001x over previous
//
#include <hip/hip_runtime.h>
#include <hip/hip_bf16.h>
#include <cstdint>

// Problem constants (B=2,S=1024,D=1024; L=2,E=8,F=2048; k=2)
#define T_TOKENS 2048
#define DDIM 1024
#define FDIM 2048
#define NEXP 8
#define BMPAD 64
#define RMAX 4608          // 2048*2 + 8*63 = 4537 -> 64-multiple
#define RALLOC 4736        // +128 slack rows (128-row M-tiles may overhang)

// A tiles: 64r x 32k bf16 (4 KB) in MFMA fragment order; B tiles: 128c x 32k (8 KB).
#define ATILE_EL 2048
#define BTILE_EL 4096

typedef unsigned short u16;
typedef short bf16x8 __attribute__((ext_vector_type(8)));
typedef u16 u16x8 __attribute__((ext_vector_type(8)));
typedef u16 u16x4v __attribute__((ext_vector_type(4)));
typedef float f32x4 __attribute__((ext_vector_type(4)));

#define VMCNT(n) asm volatile("s_waitcnt vmcnt(" #n ")" ::: "memory")
#define SB() __builtin_amdgcn_sched_barrier(0)
#define BAR() __builtin_amdgcn_s_barrier()

__device__ __forceinline__ u16 bf16_rn(float f) {
  unsigned u = __builtin_bit_cast(unsigned, f);
  u += 0x7fffu + ((u >> 16) & 1u);
  return (u16)(u >> 16);
}
__device__ __forceinline__ float bf16_f(u16 h) {
  unsigned u = ((unsigned)h) << 16;
  return __builtin_bit_cast(float, u);
}
__device__ __forceinline__ void gl16(const void* g, void* l) {
  __builtin_amdgcn_global_load_lds((const __attribute__((address_space(1))) void*)g,
                                   (__attribute__((address_space(3))) void*)l, 16, 0, 0);
}

// XCD-aware bijective swizzle (role-local linear id; nwg divisible by 8).
template <int GX, int GY, int GZ>
__device__ __forceinline__ void swz3(unsigned lin, int& bx, int& by, int& bz) {
  constexpr unsigned nwg = (unsigned)GX * GY * GZ;
  const unsigned nl = (lin & 7u) * (nwg >> 3) + (lin >> 3);
  bx = nl % GX;
  const unsigned t = nl / GX;
  by = t % GY;
  bz = t / GY;
}

// ================= device bodies =================

// ---- routing: top-2 of |x.proto| + softmax; red = smem float[8*256] ----
__device__ __forceinline__ void route_dev(
    int t, const float* __restrict__ x, const float* __restrict__ protos,
    int* __restrict__ eid, float* __restrict__ wgt, float* red) {
  const int tid = threadIdx.x;
  const float4 xv = ((const float4*)(x + (size_t)t * DDIM))[tid];
  float acc[NEXP];
#pragma unroll
  for (int e = 0; e < NEXP; ++e) {
    const float4 p = ((const float4*)protos)[e * 256 + tid];
    acc[e] = xv.x * p.x + xv.y * p.y + xv.z * p.z + xv.w * p.w;
  }
#pragma unroll
  for (int e = 0; e < NEXP; ++e) red[e * 256 + tid] = acc[e];
  __syncthreads();
  for (int s = 128; s > 0; s >>= 1) {
    if (tid < s) {
#pragma unroll
      for (int e = 0; e < NEXP; ++e) red[e * 256 + tid] += red[e * 256 + tid + s];
    }
    __syncthreads();
  }
  if (tid == 0) {
    float m1 = -1.f, m2 = -1.f;
    int i1 = 0, i2 = 0;
#pragma unroll
    for (int e = 0; e < NEXP; ++e) {
      float s = fabsf(red[e * 256]);
      if (s > m1) { m2 = m1; i2 = i1; m1 = s; i1 = e; }
      else if (s > m2) { m2 = s; i2 = e; }
    }
    float e2 = __expf(m2 - m1);
    float z = 1.f + e2;
    eid[t * 2] = i1;
    eid[t * 2 + 1] = i2;
    wgt[t * 2] = 1.f / z;
    wgt[t * 2 + 1] = e2 / z;
  }
}

// ---- W convert: f32 [e][K][N] -> bf16 hi(/lo) B-tiled; smem >= 32*129 floats ----
template <bool LO>
__device__ __forceinline__ void wconv_dev(
    int nb, int kb, int e, const float* __restrict__ W, u16* __restrict__ Hi,
    u16* __restrict__ Lo, int K, int N, float* tile) {
  const float* Wp = W + ((size_t)e * K + (size_t)kb * 32) * N + nb * 128;
  const int t = threadIdx.x;
#pragma unroll
  for (int i = 0; i < 4; ++i) {
    const int f4 = i * 256 + t;
    const int kr = f4 >> 5;
    const int c4 = (f4 & 31) * 4;
    float4 v = *(const float4*)(Wp + (size_t)kr * N + c4);
    *(float4*)&tile[kr * 129 + c4] = v;
  }
  __syncthreads();
  const size_t tb = (((size_t)e * (N >> 7) + nb) * (K >> 5) + kb) * BTILE_EL;
#pragma unroll
  for (int j = 0; j < 2; ++j) {
    const int cid = j * 256 + t;
    const int n = cid & 127, ksel = cid >> 7;
    u16x8 hv, lv;
#pragma unroll
    for (int i = 0; i < 8; ++i) {
      float f = tile[(ksel * 8 + i) * 129 + n];
      u16 h = bf16_rn(f);
      hv[i] = h;
      if (LO) lv[i] = bf16_rn(f - bf16_f(h));
    }
    *(u16x8*)(Hi + tb + (size_t)cid * 8) = hv;
    if (LO) *(u16x8*)(Lo + tb + (size_t)cid * 8) = lv;
  }
}

// ---- W2 convert (hi) + P partials; smem >= (32*129 + 8*128) floats ----
__device__ __forceinline__ void wconv_p_dev(
    int nb, int kb, int e, const float* __restrict__ W, u16* __restrict__ Hi,
    const float* __restrict__ proto2, float* __restrict__ Ppart, int K, int N,
    float* smem) {
  float* tile = smem;              // [32][129]
  float* pr = smem + 32 * 129;     // [8][128]
  const float* Wp = W + ((size_t)e * K + (size_t)kb * 32) * N + nb * 128;
  const int t = threadIdx.x;
#pragma unroll
  for (int i = 0; i < 4; ++i) {
    const int f4 = i * 256 + t;
    const int kr = f4 >> 5;
    const int c4 = (f4 & 31) * 4;
    float4 v = *(const float4*)(Wp + (size_t)kr * N + c4);
    *(float4*)&tile[kr * 129 + c4] = v;
  }
  {
    const int idx = t * 4;
    const int e2 = idx >> 7, n = idx & 127;
    *(float4*)&pr[e2 * 128 + n] =
        *(const float4*)(proto2 + (size_t)e2 * DDIM + nb * 128 + n);
  }
  __syncthreads();
  const size_t tb = (((size_t)e * (N >> 7) + nb) * (K >> 5) + kb) * BTILE_EL;
#pragma unroll
  for (int j = 0; j < 2; ++j) {
    const int cid = j * 256 + t;
    const int n = cid & 127, ksel = cid >> 7;
    u16x8 hv;
#pragma unroll
    for (int i = 0; i < 8; ++i) hv[i] = bf16_rn(tile[(ksel * 8 + i) * 129 + n]);
    *(u16x8*)(Hi + tb + (size_t)cid * 8) = hv;
  }
  const int e2 = t >> 5, f = t & 31;
  float s = 0.f;
#pragma unroll 16
  for (int n = 0; n < 128; ++n) s += tile[f * 129 + n] * pr[e2 * 128 + n];
  Ppart[(((size_t)nb * NEXP + e) * NEXP + e2) * FDIM + kb * 32 + f] = s;
}

// ---- gather one row -> bf16 hi(/lo) A-tiled ----
template <bool LO>
__device__ __forceinline__ void gather_dev(
    int r, const float* __restrict__ x, const int* __restrict__ row2token,
    u16* __restrict__ Ahi, u16* __restrict__ Alo) {
  const int t = row2token[r];
  const int c = threadIdx.x * 4;
  float4 v = make_float4(0.f, 0.f, 0.f, 0.f);
  if (t >= 0) v = *(const float4*)(x + (size_t)t * DDIM + c);
  float vv[4] = {v.x, v.y, v.z, v.w};
  u16x4v hi, lo;
#pragma unroll
  for (int i = 0; i < 4; ++i) {
    u16 h = bf16_rn(vv[i]);
    hi[i] = h;
    if (LO) lo[i] = bf16_rn(vv[i] - bf16_f(h));
  }
  const size_t el = ((size_t)(r >> 6) * (DDIM >> 5) + (c >> 5)) * ATILE_EL +
                    (size_t)(((c >> 3) & 3) * 64 + (r & 63)) * 8 + (c & 7);
  *(u16x4v*)(Ahi + el) = hi;
  if (LO) *(u16x4v*)(Alo + el) = lo;
}

// ---- SPLIT GEMM body: 64x128 block, 32x64 waves, BK=32, dbuf, counted vmcnt ----
__device__ __forceinline__ void gemm_split_dev(
    unsigned lin, u16* lds, const u16* __restrict__ Ahi, const u16* __restrict__ Alo,
    const u16* __restrict__ Bhi, const u16* __restrict__ Blo,
    u16* __restrict__ OutHi, u16* __restrict__ OutLo,
    const int* __restrict__ cnt, const int* __restrict__ offp, int K, int N) {
  int bx, by, bz;
  swz3<FDIM / 128, RMAX / 64, NEXP>(lin, bx, by, bz);
  const int e = bz;
  const int cp = (cnt[e] + 63) & ~63;
  if (by * 64 >= cp) return;
  const int row0 = offp[e] + by * 64;
  const int n0 = bx * 128;
  const int nkb = K >> 5;
  constexpr int BUF_EL = 12288;

  const int tid = threadIdx.x;
  const int lane = tid & 63;
  const int wid = tid >> 6;
  const int wr = wid >> 1, wc = wid & 1;
  const int lr = lane & 15, kg = lane >> 4;
  const int lo16 = lane << 4;

  f32x4 acc[2][4];
#pragma unroll
  for (int i = 0; i < 2; ++i)
#pragma unroll
    for (int j = 0; j < 4; ++j)
#pragma unroll
      for (int r = 0; r < 4; ++r) acc[i][j][r] = 0.f;

  const size_t abase = (size_t)(row0 >> 6) * nkb;
  const size_t bbase = ((size_t)e * (N >> 7) + (n0 >> 7)) * nkb;

  auto STAGE = [&](int kb, int b) {  // exactly 6 gl16 per wave
    char* d = (char*)(lds + b * BUF_EL);
    const char* gah = (const char*)(Ahi + (abase + kb) * ATILE_EL);
    const char* gal = (const char*)(Alo + (abase + kb) * ATILE_EL);
    const char* gbh = (const char*)(Bhi + (bbase + kb) * BTILE_EL);
    const char* gbl = (const char*)(Blo + (bbase + kb) * BTILE_EL);
    if (wid == 0) {
      gl16(gah + 0 * 1024 + lo16, d + 0 * 1024);
      gl16(gah + 1 * 1024 + lo16, d + 1 * 1024);
      gl16(gah + 2 * 1024 + lo16, d + 2 * 1024);
      gl16(gah + 3 * 1024 + lo16, d + 3 * 1024);
      gl16(gal + 0 * 1024 + lo16, d + 4096 + 0 * 1024);
      gl16(gal + 1 * 1024 + lo16, d + 4096 + 1 * 1024);
    } else if (wid == 1) {
      gl16(gal + 2 * 1024 + lo16, d + 4096 + 2 * 1024);
      gl16(gal + 3 * 1024 + lo16, d + 4096 + 3 * 1024);
      gl16(gbh + 0 * 1024 + lo16, d + 8192 + 0 * 1024);
      gl16(gbh + 1 * 1024 + lo16, d + 8192 + 1 * 1024);
      gl16(gbh + 2 * 1024 + lo16, d + 8192 + 2 * 1024);
      gl16(gbh + 3 * 1024 + lo16, d + 8192 + 3 * 1024);
    } else if (wid == 2) {
      gl16(gbh + 4 * 1024 + lo16, d + 8192 + 4 * 1024);
      gl16(gbh + 5 * 1024 + lo16, d + 8192 + 5 * 1024);
      gl16(gbh + 6 * 1024 + lo16, d + 8192 + 6 * 1024);
      gl16(gbh + 7 * 1024 + lo16, d + 8192 + 7 * 1024);
      gl16(gbl + 0 * 1024 + lo16, d + 16384 + 0 * 1024);
      gl16(gbl + 1 * 1024 + lo16, d + 16384 + 1 * 1024);
    } else {
      gl16(gbl + 2 * 1024 + lo16, d + 16384 + 2 * 1024);
      gl16(gbl + 3 * 1024 + lo16, d + 16384 + 3 * 1024);
      gl16(gbl + 4 * 1024 + lo16, d + 16384 + 4 * 1024);
      gl16(gbl + 5 * 1024 + lo16, d + 16384 + 5 * 1024);
      gl16(gbl + 6 * 1024 + lo16, d + 16384 + 6 * 1024);
      gl16(gbl + 7 * 1024 + lo16, d + 16384 + 7 * 1024);
    }
  };

  STAGE(0, 0);
  int cur = 0;
  for (int kb = 0; kb < nkb; ++kb) {
    const bool pf = (kb + 1 < nkb);
    if (pf) STAGE(kb + 1, cur ^ 1);
    if (pf) { VMCNT(6); } else { VMCNT(0); }
    SB(); BAR(); SB();

    const u16* buf = lds + cur * BUF_EL;
    const u16* AsH = buf;
    const u16* AsL = buf + 2048;
    const u16* BsH = buf + 4096;
    const u16* BsL = buf + 8192;
    const int arow = (kg * 64 + wr * 32 + lr) * 8;
    const int bcol = (kg * 128 + wc * 64 + lr) * 8;

    bf16x8 ah0 = *(const bf16x8*)&AsH[arow];
    bf16x8 ah1 = *(const bf16x8*)&AsH[arow + 128];
    bf16x8 bh[4];
#pragma unroll
    for (int j = 0; j < 4; ++j) bh[j] = *(const bf16x8*)&BsH[bcol + j * 128];
#pragma unroll
    for (int j = 0; j < 4; ++j) {
      acc[0][j] = __builtin_amdgcn_mfma_f32_16x16x32_bf16(ah0, bh[j], acc[0][j], 0, 0, 0);
      acc[1][j] = __builtin_amdgcn_mfma_f32_16x16x32_bf16(ah1, bh[j], acc[1][j], 0, 0, 0);
    }
    bf16x8 al0 = *(const bf16x8*)&AsL[arow];
    bf16x8 al1 = *(const bf16x8*)&AsL[arow + 128];
#pragma unroll
    for (int j = 0; j < 4; ++j) {
      bf16x8 bl = *(const bf16x8*)&BsL[bcol + j * 128];
      acc[0][j] = __builtin_amdgcn_mfma_f32_16x16x32_bf16(ah0, bl, acc[0][j], 0, 0, 0);
      acc[1][j] = __builtin_amdgcn_mfma_f32_16x16x32_bf16(ah1, bl, acc[1][j], 0, 0, 0);
      acc[0][j] = __builtin_amdgcn_mfma_f32_16x16x32_bf16(al0, bh[j], acc[0][j], 0, 0, 0);
      acc[1][j] = __builtin_amdgcn_mfma_f32_16x16x32_bf16(al1, bh[j], acc[1][j], 0, 0, 0);
    }
    SB(); BAR(); SB();
    cur ^= 1;
  }

  const int nkbO = N >> 5;
#pragma unroll
  for (int i = 0; i < 2; ++i) {
#pragma unroll
    for (int j = 0; j < 4; ++j) {
      const int Cj = n0 + wc * 64 + j * 16 + lr;
      f32x4 v = acc[i][j];
#pragma unroll
      for (int r = 0; r < 4; ++r) {
        const int R = row0 + wr * 32 + i * 16 + kg * 4 + r;
        float f = fmaxf(v[r], 0.f);
        const size_t el = ((size_t)(R >> 6) * nkbO + (Cj >> 5)) * ATILE_EL +
                          (size_t)(((Cj >> 3) & 3) * 64 + (R & 63)) * 8 + (Cj & 7);
        u16 h = bf16_rn(f);
        OutHi[el] = h;
        OutLo[el] = bf16_rn(f - bf16_f(h));
      }
    }
  }
}

// ---- PLAIN GEMM body: 128x128 block, 64x64 waves, BK=32, dbuf, counted vmcnt ----
template <int GX, int GY, bool RELU, int OUTMODE>  // OUTMODE 0: f32 row-major; 2: bf16 hi A-tiled
__device__ __forceinline__ void gemm_plain_dev(
    unsigned lin, u16* lds, const u16* __restrict__ Ahi, const u16* __restrict__ Bhi,
    u16* __restrict__ OutHi, float* __restrict__ OutF,
    const int* __restrict__ cnt, const int* __restrict__ offp, int K, int N) {
  int bx, by, bz;
  swz3<GX, GY, NEXP>(lin, bx, by, bz);
  const int e = bz;
  const int cp = (cnt[e] + 63) & ~63;
  if (by * 128 >= cp) return;
  const int row0 = offp[e] + by * 128;
  const int rend = offp[e] + cp;
  const int n0 = bx * 128;
  const int nkb = K >> 5;
  constexpr int BUF_EL = 8192;

  const int tid = threadIdx.x;
  const int lane = tid & 63;
  const int wid = tid >> 6;
  const int wr = wid >> 1, wc = wid & 1;
  const int lr = lane & 15, kg = lane >> 4;
  const int lo16 = lane << 4;

  f32x4 acc[4][4];
#pragma unroll
  for (int i = 0; i < 4; ++i)
#pragma unroll
    for (int j = 0; j < 4; ++j)
#pragma unroll
      for (int r = 0; r < 4; ++r) acc[i][j][r] = 0.f;

  const int at0 = row0 >> 6;
  const size_t bbase = ((size_t)e * (N >> 7) + (n0 >> 7)) * nkb;

  auto STAGE = [&](int kb, int b) {  // exactly 4 gl16 per wave
    char* d = (char*)(lds + b * BUF_EL);
    if (wid < 2) {
      const char* g = (const char*)(Ahi + ((size_t)(at0 + wid) * nkb + kb) * ATILE_EL);
      gl16(g + 0 * 1024 + lo16, d + wid * 4096 + 0 * 1024);
      gl16(g + 1 * 1024 + lo16, d + wid * 4096 + 1 * 1024);
      gl16(g + 2 * 1024 + lo16, d + wid * 4096 + 2 * 1024);
      gl16(g + 3 * 1024 + lo16, d + wid * 4096 + 3 * 1024);
    } else {
      const char* g = (const char*)(Bhi + (bbase + kb) * BTILE_EL) + (wid - 2) * 4096;
      gl16(g + 0 * 1024 + lo16, d + 8192 + (wid - 2) * 4096 + 0 * 1024);
      gl16(g + 1 * 1024 + lo16, d + 8192 + (wid - 2) * 4096 + 1 * 1024);
      gl16(g + 2 * 1024 + lo16, d + 8192 + (wid - 2) * 4096 + 2 * 1024);
      gl16(g + 3 * 1024 + lo16, d + 8192 + (wid - 2) * 4096 + 3 * 1024);
    }
  };

  STAGE(0, 0);
  int cur = 0;
  for (int kb = 0; kb < nkb; ++kb) {
    const bool pf = (kb + 1 < nkb);
    if (pf) STAGE(kb + 1, cur ^ 1);
    if (pf) { VMCNT(4); } else { VMCNT(0); }
    SB(); BAR(); SB();

    const u16* buf = lds + cur * BUF_EL;
    const u16* AsH = buf + wr * 2048;
    const u16* BsH = buf + 4096;
    const int arow = (kg * 64 + lr) * 8;
    const int bcol = (kg * 128 + wc * 64 + lr) * 8;

    bf16x8 ah[4], bh[4];
#pragma unroll
    for (int i = 0; i < 4; ++i) ah[i] = *(const bf16x8*)&AsH[arow + i * 128];
#pragma unroll
    for (int j = 0; j < 4; ++j) bh[j] = *(const bf16x8*)&BsH[bcol + j * 128];
#pragma unroll
    for (int i = 0; i < 4; ++i)
#pragma unroll
      for (int j = 0; j < 4; ++j)
        acc[i][j] = __builtin_amdgcn_mfma_f32_16x16x32_bf16(ah[i], bh[j], acc[i][j], 0, 0, 0);
    SB(); BAR(); SB();
    cur ^= 1;
  }

  const int nkbO = N >> 5;
#pragma unroll
  for (int i = 0; i < 4; ++i) {
#pragma unroll
    for (int j = 0; j < 4; ++j) {
      const int Cj = n0 + wc * 64 + j * 16 + lr;
      f32x4 v = acc[i][j];
#pragma unroll
      for (int r = 0; r < 4; ++r) {
        const int R = row0 + wr * 64 + i * 16 + kg * 4 + r;
        if (R >= rend) continue;
        float f = v[r];
        if (RELU) f = fmaxf(f, 0.f);
        if constexpr (OUTMODE == 0) {
          OutF[(size_t)R * N + Cj] = f;
        } else {
          const size_t el = ((size_t)(R >> 6) * nkbO + (Cj >> 5)) * ATILE_EL +
                            (size_t)(((Cj >> 3) & 3) * 64 + (R & 63)) * 8 + (Cj & 7);
          OutHi[el] = bf16_rn(f);
        }
      }
    }
  }
}

__device__ __forceinline__ void compact_dev(
    const int* __restrict__ eid, int* __restrict__ cnt, int* __restrict__ offp,
    int* __restrict__ row2token, int* __restrict__ pos, int* lcnt) {
  int* s_off = lcnt + NEXP * 256;
  int* s_tot = s_off + NEXP;
  const int tid = threadIdx.x;
  const int base = tid * 16;
  int my[16];
#pragma unroll
  for (int i = 0; i < 4; ++i)
    *(int4*)&my[i * 4] = *(const int4*)(eid + base + i * 4);
#pragma unroll
  for (int e = 0; e < NEXP; ++e) {
    int c = 0;
#pragma unroll
    for (int i = 0; i < 16; ++i) c += (my[i] == e) ? 1 : 0;
    lcnt[e * 256 + tid] = c;
  }
  for (int r = tid; r < RMAX; r += 256) row2token[r] = -1;
  __syncthreads();
  if (tid < NEXP) {
    int run = 0;
    for (int i = 0; i < 256; ++i) {
      int v = lcnt[tid * 256 + i];
      lcnt[tid * 256 + i] = run;
      run += v;
    }
    s_tot[tid] = run;
  }
  __syncthreads();
  if (tid == 0) {
    int o = 0;
    for (int e = 0; e < NEXP; ++e) {
      s_off[e] = o;
      o += (s_tot[e] + BMPAD - 1) & ~(BMPAD - 1);
    }
  }
  __syncthreads();
  int myoff[NEXP];
#pragma unroll
  for (int e = 0; e < NEXP; ++e) myoff[e] = s_off[e] + lcnt[e * 256 + tid];
#pragma unroll
  for (int i = 0; i < 16; ++i) {
    int r = 0;
#pragma unroll
    for (int e = 0; e < NEXP; ++e) r = (my[i] == e) ? myoff[e] : r;
    row2token[r] = (base + i) >> 1;
    pos[base + i] = r;
#pragma unroll
    for (int e = 0; e < NEXP; ++e) myoff[e] += (my[i] == e) ? 1 : 0;
  }
  if (tid < NEXP) {
    cnt[tid] = s_tot[tid];
    offp[tid] = s_off[tid];
  }
}

// ================= global kernels =================

// K1: route (2048) | wconv_p W2l0->W2A (4096) | wconv W1l0 hi+lo (4096)
__global__ __launch_bounds__(256) void fusedK1_kernel(
    const float* __restrict__ xin, const float* __restrict__ protos,
    int* __restrict__ eidA, float* __restrict__ wgtA,
    const float* __restrict__ W2, u16* __restrict__ W2A,
    const float* __restrict__ proto2, float* __restrict__ Ppart,
    const float* __restrict__ W1, u16* __restrict__ W_hi, u16* __restrict__ W_lo) {
  __shared__ float smem[32 * 129 + 8 * 128];
  const unsigned lin = blockIdx.x;
  if (lin < 2048u) {
    route_dev((int)lin, xin, protos, eidA, wgtA, smem);
  } else if (lin < 6144u) {
    const unsigned l2 = lin - 2048u;
    wconv_p_dev(l2 % 8, (l2 / 8) % 64, l2 / 512, W2, W2A, proto2, Ppart,
                FDIM, DDIM, smem);
  } else {
    const unsigned l3 = lin - 6144u;
    wconv_dev<true>(l3 % 16, (l3 / 16) % 32, l3 / 512, W1, W_hi, W_lo,
                    DDIM, FDIM, smem);
  }
}

__global__ __launch_bounds__(256) void compact_kernel(
    const int* __restrict__ eid, int* __restrict__ cnt, int* __restrict__ offp,
    int* __restrict__ row2token, int* __restrict__ pos) {
  __shared__ int lcnt[NEXP * 256 + 16];
  compact_dev(eid, cnt, offp, row2token, pos, lcnt);
}

// K3: gather hi+lo (4608) | reduce_p (512)
__global__ __launch_bounds__(256) void fusedK3_kernel(
    const float* __restrict__ xin, const int* __restrict__ row2token,
    u16* __restrict__ Ag_hi, u16* __restrict__ Ag_lo,
    const float* __restrict__ Ppart, float* __restrict__ P) {
  const unsigned lin = blockIdx.x;
  if (lin < (unsigned)RMAX) {
    gather_dev<true>((int)lin, xin, row2token, Ag_hi, Ag_lo);
  } else {
    const int i = (int)(lin - RMAX) * 256 + threadIdx.x;
    float s = 0.f;
#pragma unroll
    for (int nb = 0; nb < 8; ++nb) s += Ppart[(size_t)nb * (NEXP * NEXP * FDIM) + i];
    P[i] = s;
  }
}

// C2: pure split GEMM1-l0 (9216 blocks), 48 KB LDS, 3 blocks/CU
__global__ __launch_bounds__(256, 3) void fusedC2_kernel(
    const u16* __restrict__ Ag_hi, const u16* __restrict__ Ag_lo,
    const u16* __restrict__ W_hi, const u16* __restrict__ W_lo,
    u16* __restrict__ h_hi, u16* __restrict__ h_lo,
    const int* __restrict__ cnt, const int* __restrict__ offp) {
  __shared__ u16 lds[2 * 12288];  // 48 KB
  gemm_split_dev(blockIdx.x, lds, Ag_hi, Ag_lo, W_hi, W_lo, h_hi, h_lo, cnt, offp,
                 DDIM, FDIM);
}

// C3: gemm_plain GEMM2-l0 (2304) | wconv W1l1->W_lo (4096) | wconv W2l1->W_hi (4096)
__global__ __launch_bounds__(256, 4) void fusedC3_kernel(
    const u16* __restrict__ h_hi, const u16* __restrict__ W2A,
    float* __restrict__ part, const int* __restrict__ cnt, const int* __restrict__ offp,
    const float* __restrict__ W1b, u16* __restrict__ W_lo,
    const float* __restrict__ W2b, u16* __restrict__ W_hi) {
  __shared__ u16 lds[2 * 8192];  // 32 KB (covers wconv's 16.5 KB)
  const unsigned lin = blockIdx.x;
  if (lin < 2304u) {
    gemm_plain_dev<DDIM / 128, RMAX / 128, false, 0>(
        lin, lds, h_hi, W2A, nullptr, part, cnt, offp, FDIM, DDIM);
  } else if (lin < 6400u) {
    const unsigned l2 = lin - 2304u;
    wconv_dev<false>(l2 % 16, (l2 / 16) % 32, l2 / 512, W1b, W_lo, nullptr,
                     DDIM, FDIM, (float*)lds);
  } else {
    const unsigned l2 = lin - 6400u;
    wconv_dev<false>(l2 % 8, (l2 / 8) % 64, l2 / 512, W2b, W_hi, nullptr,
                     FDIM, DDIM, (float*)lds);
  }
}

__global__ __launch_bounds__(256) void route2_kernel(
    const float* __restrict__ x, const float* __restrict__ protos2,
    const u16* __restrict__ h_hi, const u16* __restrict__ h_lo,
    const float* __restrict__ P, const int* __restrict__ eidA,
    const int* __restrict__ pos, const float* __restrict__ wgtA,
    int* __restrict__ eidB, float* __restrict__ wgtB) {
  const int t = blockIdx.x;
  const int tid = threadIdx.x;
  __shared__ float red[NEXP][256];
  const float4 xv = ((const float4*)(x + (size_t)t * DDIM))[tid];
  float acc[NEXP];
#pragma unroll
  for (int e = 0; e < NEXP; ++e) {
    const float4 p = ((const float4*)protos2)[e * 256 + tid];
    acc[e] = xv.x * p.x + xv.y * p.y + xv.z * p.z + xv.w * p.w;
  }
  const int p0 = pos[t * 2], p1 = pos[t * 2 + 1];
  const int e0 = eidA[t * 2], e1 = eidA[t * 2 + 1];
  const float w0 = wgtA[t * 2], w1 = wgtA[t * 2 + 1];
  const int f0 = tid * 8;
  const int nkbF = FDIM >> 5;
  float h0[8], h1[8];
  {
    const size_t el0 = ((size_t)(p0 >> 6) * nkbF + (f0 >> 5)) * ATILE_EL +
                       (size_t)((((f0 >> 3) & 3) * 64 + (p0 & 63)) * 8);
    const size_t el1 = ((size_t)(p1 >> 6) * nkbF + (f0 >> 5)) * ATILE_EL +
                       (size_t)((((f0 >> 3) & 3) * 64 + (p1 & 63)) * 8);
    u16x8 a = *(const u16x8*)&h_hi[el0], b = *(const u16x8*)&h_lo[el0];
    u16x8 c = *(const u16x8*)&h_hi[el1], d = *(const u16x8*)&h_lo[el1];
#pragma unroll
    for (int j = 0; j < 8; ++j) {
      h0[j] = bf16_f(a[j]) + bf16_f(b[j]);
      h1[j] = bf16_f(c[j]) + bf16_f(d[j]);
    }
  }
#pragma unroll
  for (int e2 = 0; e2 < NEXP; ++e2) {
    const float* P0 = P + ((size_t)(e0 * NEXP + e2)) * FDIM + f0;
    const float* P1 = P + ((size_t)(e1 * NEXP + e2)) * FDIM + f0;
    float c = 0.f;
#pragma unroll
    for (int j = 0; j < 8; ++j) c += w0 * h0[j] * P0[j] + w1 * h1[j] * P1[j];
    acc[e2] += c;
  }
#pragma unroll
  for (int e = 0; e < NEXP; ++e) red[e][tid] = acc[e];
  __syncthreads();
  for (int s = 128; s > 0; s >>= 1) {
    if (tid < s) {
#pragma unroll
      for (int e = 0; e < NEXP; ++e) red[e][tid] += red[e][tid + s];
    }
    __syncthreads();
  }
  if (tid == 0) {
    float m1 = -1.f, m2 = -1.f;
    int i1 = 0, i2 = 0;
#pragma unroll
    for (int e = 0; e < NEXP; ++e) {
      float s = fabsf(red[e][0]);
      if (s > m1) { m2 = m1; i2 = i1; m1 = s; i1 = e; }
      else if (s > m2) { m2 = s; i2 = e; }
    }
    float e2 = __expf(m2 - m1);
    float z = 1.f + e2;
    eidB[t * 2] = i1;
    eidB[t * 2 + 1] = i2;
    wgtB[t * 2] = 1.f / z;
    wgtB[t * 2 + 1] = e2 / z;
  }
}

// D: apply layer-0 (xcur = xin + w.y; 2048) | compact B (1)
__global__ __launch_bounds__(256) void fusedD_kernel(
    const float* __restrict__ part, const int* __restrict__ pos,
    const float* __restrict__ wgt, const float* __restrict__ xin,
    float* __restrict__ xcur,
    const int* __restrict__ eidB, int* __restrict__ cnt, int* __restrict__ offp,
    int* __restrict__ row2token, int* __restrict__ posB) {
  __shared__ int lcnt[NEXP * 256 + 16];
  const unsigned lin = blockIdx.x;
  if (lin < 2048u) {
    const int t = lin;
    const int c = threadIdx.x * 4;
    const int p0 = pos[t * 2], p1 = pos[t * 2 + 1];
    const float w0 = wgt[t * 2], w1 = wgt[t * 2 + 1];
    float4 xa = *(const float4*)(xin + (size_t)t * DDIM + c);
    const float4 y0 = *(const float4*)(part + (size_t)p0 * DDIM + c);
    const float4 y1 = *(const float4*)(part + (size_t)p1 * DDIM + c);
    xa.x += w0 * y0.x + w1 * y1.x;
    xa.y += w0 * y0.y + w1 * y1.y;
    xa.z += w0 * y0.z + w1 * y1.z;
    xa.w += w0 * y0.w + w1 * y1.w;
    *(float4*)(xcur + (size_t)t * DDIM + c) = xa;
  } else {
    compact_dev(eidB, cnt, offp, row2token, posB, lcnt);
  }
}

__global__ __launch_bounds__(256) void gather_kernel(
    const float* __restrict__ x, const int* __restrict__ row2token,
    u16* __restrict__ Ahi) {
  gather_dev<false>(blockIdx.x, x, row2token, Ahi, nullptr);
}

template <int GX, bool RELU, int OUTMODE>
__global__ __launch_bounds__(256, 4) void gemm_plain_kernel(
    const u16* __restrict__ Ahi, const u16* __restrict__ Bhi,
    u16* __restrict__ OutHi, float* __restrict__ OutF,
    const int* __restrict__ cnt, const int* __restrict__ offp, int K, int N) {
  __shared__ u16 lds[2 * 8192];
  gemm_plain_dev<GX, RMAX / 128, RELU, OUTMODE>(blockIdx.x, lds, Ahi, Bhi, OutHi,
                                                OutF, cnt, offp, K, N);
}

__global__ __launch_bounds__(256) void apply_kernel(
    const float* __restrict__ part, const int* __restrict__ pos,
    const float* __restrict__ wgt, float* __restrict__ x) {
  const int t = blockIdx.x;
  const int c = threadIdx.x * 4;
  const int p0 = pos[t * 2], p1 = pos[t * 2 + 1];
  const float w0 = wgt[t * 2], w1 = wgt[t * 2 + 1];
  float4 xa = *(float4*)(x + (size_t)t * DDIM + c);
  const float4 y0 = *(const float4*)(part + (size_t)p0 * DDIM + c);
  const float4 y1 = *(const float4*)(part + (size_t)p1 * DDIM + c);
  xa.x += w0 * y0.x + w1 * y1.x;
  xa.y += w0 * y0.y + w1 * y1.y;
  xa.z += w0 * y0.z + w1 * y1.z;
  xa.w += w0 * y0.w + w1 * y1.w;
  *(float4*)(x + (size_t)t * DDIM + c) = xa;
}

extern "C" void kernel_launch(void* const* d_in, const int* in_sizes, int n_in,
                              void* d_out, int out_size, void* d_ws, size_t ws_size,
                              hipStream_t stream) {
  const float* xin = (const float*)d_in[0];
  const float* protos = (const float*)d_in[1];
  const float* W1 = (const float*)d_in[2];
  const float* W2 = (const float*)d_in[3];
  float* xcur = (float*)d_out;

  u16* W_hi = (u16*)d_ws;
  u16* W_lo = W_hi + (size_t)NEXP * DDIM * FDIM;
  u16* W2A = W_lo + (size_t)NEXP * DDIM * FDIM;
  u16* Ag_hi = W2A + (size_t)NEXP * DDIM * FDIM;
  u16* Ag_lo = Ag_hi + (size_t)RALLOC * DDIM;
  u16* h_hi = Ag_lo + (size_t)RALLOC * DDIM;
  u16* h_lo = h_hi + (size_t)RALLOC * FDIM;
  float* part = (float*)(h_lo + (size_t)RALLOC * FDIM);
  float* Ppart = part + (size_t)RALLOC * DDIM;
  float* P = Ppart + (size_t)8 * NEXP * NEXP * FDIM;
  float* wgtA = P + (size_t)NEXP * NEXP * FDIM;
  float* wgtB = wgtA + T_TOKENS * 2;
  int* eidA = (int*)(wgtB + T_TOKENS * 2);
  int* eidB = eidA + T_TOKENS * 2;
  int* posA = eidB + T_TOKENS * 2;
  int* posB = posA + T_TOKENS * 2;
  int* cnt = posB + T_TOKENS * 2;
  int* offp = cnt + NEXP;
  int* row2token = offp + NEXP;

  const float* protos2 = protos + (size_t)NEXP * DDIM;
  const float* W1b = W1 + (size_t)NEXP * DDIM * FDIM;
  const float* W2b = W2 + (size_t)NEXP * FDIM * DDIM;

  // ---------------- layer 0 ----------------
  fusedK1_kernel<<<2048 + 4096 + 4096, 256, 0, stream>>>(
      xin, protos, eidA, wgtA, W2, W2A, protos2, Ppart, W1, W_hi, W_lo);
  compact_kernel<<<1, 256, 0, stream>>>(eidA, cnt, offp, row2token, posA);
  fusedK3_kernel<<<RMAX + 512, 256, 0, stream>>>(
      xin, row2token, Ag_hi, Ag_lo, Ppart, P);
  fusedC2_kernel<<<(FDIM / 128) * (RMAX / 64) * NEXP, 256, 0, stream>>>(
      Ag_hi, Ag_lo, W_hi, W_lo, h_hi, h_lo, cnt, offp);
  fusedC3_kernel<<<2304 + 4096 + 4096, 256, 0, stream>>>(
      h_hi, W2A, part, cnt, offp, W1b, W_lo, W2b, W_hi);
  route2_kernel<<<T_TOKENS, 256, 0, stream>>>(
      xin, protos2, h_hi, h_lo, P, eidA, posA, wgtA, eidB, wgtB);
  fusedD_kernel<<<2048 + 1, 256, 0, stream>>>(
      part, posA, wgtA, xin, xcur, eidB, cnt, offp, row2token, posB);

  // ---------------- layer 1 (all plain bf16; W1l1=W_lo, W2l1=W_hi) ----------------
  gather_kernel<<<RMAX, 256, 0, stream>>>(xcur, row2token, Ag_hi);
  gemm_plain_kernel<FDIM / 128, true, 2>
      <<<(FDIM / 128) * (RMAX / 128) * NEXP, 256, 0, stream>>>(
          Ag_hi, W_lo, h_hi, nullptr, cnt, offp, DDIM, FDIM);
  gemm_plain_kernel<DDIM / 128, false, 0>
      <<<(DDIM / 128) * (RMAX / 128) * NEXP, 256, 0, stream>>>(
          h_hi, W_hi, nullptr, part, cnt, offp, FDIM, DDIM);
  apply_kernel<<<T_TOKENS, 256, 0, stream>>>(part, posB, wgtB, xcur);
}

// Round 14
// 315.293 us; speedup vs baseline: 1.2462x; 1.0509x over previous
//
#include <hip/hip_runtime.h>
#include <hip/hip_bf16.h>
#include <cstdint>

// Problem constants (B=2,S=1024,D=1024; L=2,E=8,F=2048; k=2)
#define T_TOKENS 2048
#define DDIM 1024
#define FDIM 2048
#define NEXP 8
#define BMPAD 64
#define RMAX 4608          // 2048*2 + 8*63 = 4537 -> 64-multiple
#define RALLOC 4736        // +128 slack rows (128-row M-tiles may overhang)

// A tiles: 64r x 32k bf16 (4 KB) in MFMA fragment order; B tiles: 128c x 32k (8 KB).
#define ATILE_EL 2048
#define BTILE_EL 4096
#define WLDP 132           // wconv LDS tile row stride (floats; 4-aligned for float4)

typedef unsigned short u16;
typedef short bf16x8 __attribute__((ext_vector_type(8)));
typedef u16 u16x8 __attribute__((ext_vector_type(8)));
typedef u16 u16x4v __attribute__((ext_vector_type(4)));
typedef float f32x4 __attribute__((ext_vector_type(4)));

#define VMCNT(n) asm volatile("s_waitcnt vmcnt(" #n ")" ::: "memory")
#define SB() __builtin_amdgcn_sched_barrier(0)
#define BAR() __builtin_amdgcn_s_barrier()

__device__ __forceinline__ u16 bf16_rn(float f) {
  unsigned u = __builtin_bit_cast(unsigned, f);
  u += 0x7fffu + ((u >> 16) & 1u);
  return (u16)(u >> 16);
}
__device__ __forceinline__ float bf16_f(u16 h) {
  unsigned u = ((unsigned)h) << 16;
  return __builtin_bit_cast(float, u);
}
__device__ __forceinline__ void gl16(const void* g, void* l) {
  __builtin_amdgcn_global_load_lds((const __attribute__((address_space(1))) void*)g,
                                   (__attribute__((address_space(3))) void*)l, 16, 0, 0);
}

// XCD-aware bijective swizzle (role-local linear id; nwg divisible by 8).
template <int GX, int GY, int GZ>
__device__ __forceinline__ void swz3(unsigned lin, int& bx, int& by, int& bz) {
  constexpr unsigned nwg = (unsigned)GX * GY * GZ;
  const unsigned nl = (lin & 7u) * (nwg >> 3) + (lin >> 3);
  bx = nl % GX;
  const unsigned t = nl / GX;
  by = t % GY;
  bz = t / GY;
}

// ================= device bodies =================

// ---- routing: top-2 of |x.proto| + softmax; red = smem float[8*256] ----
__device__ __forceinline__ void route_dev(
    int t, const float* __restrict__ x, const float* __restrict__ protos,
    int* __restrict__ eid, float* __restrict__ wgt, float* red) {
  const int tid = threadIdx.x;
  const float4 xv = ((const float4*)(x + (size_t)t * DDIM))[tid];
  float acc[NEXP];
#pragma unroll
  for (int e = 0; e < NEXP; ++e) {
    const float4 p = ((const float4*)protos)[e * 256 + tid];
    acc[e] = xv.x * p.x + xv.y * p.y + xv.z * p.z + xv.w * p.w;
  }
#pragma unroll
  for (int e = 0; e < NEXP; ++e) red[e * 256 + tid] = acc[e];
  __syncthreads();
  for (int s = 128; s > 0; s >>= 1) {
    if (tid < s) {
#pragma unroll
      for (int e = 0; e < NEXP; ++e) red[e * 256 + tid] += red[e * 256 + tid + s];
    }
    __syncthreads();
  }
  if (tid == 0) {
    float m1 = -1.f, m2 = -1.f;
    int i1 = 0, i2 = 0;
#pragma unroll
    for (int e = 0; e < NEXP; ++e) {
      float s = fabsf(red[e * 256]);
      if (s > m1) { m2 = m1; i2 = i1; m1 = s; i1 = e; }
      else if (s > m2) { m2 = s; i2 = e; }
    }
    float e2 = __expf(m2 - m1);
    float z = 1.f + e2;
    eid[t * 2] = i1;
    eid[t * 2 + 1] = i2;
    wgt[t * 2] = 1.f / z;
    wgt[t * 2 + 1] = e2 / z;
  }
}

// ---- W convert: f32 [e][K][N] -> bf16 hi(/lo) B-tiled; smem >= 32*WLDP floats ----
template <bool LO>
__device__ __forceinline__ void wconv_dev(
    int nb, int kb, int e, const float* __restrict__ W, u16* __restrict__ Hi,
    u16* __restrict__ Lo, int K, int N, float* tile) {
  const float* Wp = W + ((size_t)e * K + (size_t)kb * 32) * N + nb * 128;
  const int t = threadIdx.x;
#pragma unroll
  for (int i = 0; i < 4; ++i) {
    const int f4 = i * 256 + t;
    const int kr = f4 >> 5;
    const int c4 = (f4 & 31) * 4;
    float4 v = *(const float4*)(Wp + (size_t)kr * N + c4);
    *(float4*)&tile[kr * WLDP + c4] = v;
  }
  __syncthreads();
  const size_t tb = (((size_t)e * (N >> 7) + nb) * (K >> 5) + kb) * BTILE_EL;
#pragma unroll
  for (int j = 0; j < 2; ++j) {
    const int cid = j * 256 + t;
    const int n = cid & 127, ksel = cid >> 7;
    u16x8 hv, lv;
#pragma unroll
    for (int i = 0; i < 8; ++i) {
      float f = tile[(ksel * 8 + i) * WLDP + n];
      u16 h = bf16_rn(f);
      hv[i] = h;
      if (LO) lv[i] = bf16_rn(f - bf16_f(h));
    }
    *(u16x8*)(Hi + tb + (size_t)cid * 8) = hv;
    if (LO) *(u16x8*)(Lo + tb + (size_t)cid * 8) = lv;
  }
}

// ---- W2 convert (hi) + P partials; smem >= (32*WLDP + 8*128) floats ----
__device__ __forceinline__ void wconv_p_dev(
    int nb, int kb, int e, const float* __restrict__ W, u16* __restrict__ Hi,
    const float* __restrict__ proto2, float* __restrict__ Ppart, int K, int N,
    float* smem) {
  float* tile = smem;               // [32][WLDP]
  float* pr = smem + 32 * WLDP;     // [8][128]
  const float* Wp = W + ((size_t)e * K + (size_t)kb * 32) * N + nb * 128;
  const int t = threadIdx.x;
#pragma unroll
  for (int i = 0; i < 4; ++i) {
    const int f4 = i * 256 + t;
    const int kr = f4 >> 5;
    const int c4 = (f4 & 31) * 4;
    float4 v = *(const float4*)(Wp + (size_t)kr * N + c4);
    *(float4*)&tile[kr * WLDP + c4] = v;
  }
  {
    const int idx = t * 4;
    const int e2 = idx >> 7, n = idx & 127;
    *(float4*)&pr[e2 * 128 + n] =
        *(const float4*)(proto2 + (size_t)e2 * DDIM + nb * 128 + n);
  }
  __syncthreads();
  const size_t tb = (((size_t)e * (N >> 7) + nb) * (K >> 5) + kb) * BTILE_EL;
#pragma unroll
  for (int j = 0; j < 2; ++j) {
    const int cid = j * 256 + t;
    const int n = cid & 127, ksel = cid >> 7;
    u16x8 hv;
#pragma unroll
    for (int i = 0; i < 8; ++i) hv[i] = bf16_rn(tile[(ksel * 8 + i) * WLDP + n]);
    *(u16x8*)(Hi + tb + (size_t)cid * 8) = hv;
  }
  // P partial: thread (e2 = t>>5, f = t&31); float4 LDS reads, rotated (2-way = free)
  const int e2 = t >> 5, f = t & 31;
  float s = 0.f;
#pragma unroll
  for (int ii = 0; ii < 32; ++ii) {
    const int n4 = ((ii + f) & 31) * 4;
    const float4 tv = *(const float4*)&tile[f * WLDP + n4];
    const float4 pv = *(const float4*)&pr[e2 * 128 + n4];
    s += tv.x * pv.x + tv.y * pv.y + tv.z * pv.z + tv.w * pv.w;
  }
  Ppart[(((size_t)nb * NEXP + e) * NEXP + e2) * FDIM + kb * 32 + f] = s;
}

// ---- gather one row -> bf16 hi(/lo) A-tiled ----
template <bool LO>
__device__ __forceinline__ void gather_dev(
    int r, const float* __restrict__ x, const int* __restrict__ row2token,
    u16* __restrict__ Ahi, u16* __restrict__ Alo) {
  const int t = row2token[r];
  const int c = threadIdx.x * 4;
  float4 v = make_float4(0.f, 0.f, 0.f, 0.f);
  if (t >= 0) v = *(const float4*)(x + (size_t)t * DDIM + c);
  float vv[4] = {v.x, v.y, v.z, v.w};
  u16x4v hi, lo;
#pragma unroll
  for (int i = 0; i < 4; ++i) {
    u16 h = bf16_rn(vv[i]);
    hi[i] = h;
    if (LO) lo[i] = bf16_rn(vv[i] - bf16_f(h));
  }
  const size_t el = ((size_t)(r >> 6) * (DDIM >> 5) + (c >> 5)) * ATILE_EL +
                    (size_t)(((c >> 3) & 3) * 64 + (r & 63)) * 8 + (c & 7);
  *(u16x4v*)(Ahi + el) = hi;
  if (LO) *(u16x4v*)(Alo + el) = lo;
}

// ---- routing layer 1: score2 = x0.p2 + sum_s w_s * (h[row_s] . P[e_s]); red=8KB ----
__device__ __forceinline__ void route2_dev(
    int t, const float* __restrict__ x, const float* __restrict__ protos2,
    const u16* __restrict__ h_hi, const u16* __restrict__ h_lo,
    const float* __restrict__ P, const int* __restrict__ eidA,
    const int* __restrict__ pos, const float* __restrict__ wgtA,
    int* __restrict__ eidB, float* __restrict__ wgtB, float* red) {
  const int tid = threadIdx.x;
  const float4 xv = ((const float4*)(x + (size_t)t * DDIM))[tid];
  float acc[NEXP];
#pragma unroll
  for (int e = 0; e < NEXP; ++e) {
    const float4 p = ((const float4*)protos2)[e * 256 + tid];
    acc[e] = xv.x * p.x + xv.y * p.y + xv.z * p.z + xv.w * p.w;
  }
  const int p0 = pos[t * 2], p1 = pos[t * 2 + 1];
  const int e0 = eidA[t * 2], e1 = eidA[t * 2 + 1];
  const float w0 = wgtA[t * 2], w1 = wgtA[t * 2 + 1];
  const int f0 = tid * 8;
  const int nkbF = FDIM >> 5;
  float h0[8], h1[8];
  {
    const size_t el0 = ((size_t)(p0 >> 6) * nkbF + (f0 >> 5)) * ATILE_EL +
                       (size_t)((((f0 >> 3) & 3) * 64 + (p0 & 63)) * 8);
    const size_t el1 = ((size_t)(p1 >> 6) * nkbF + (f0 >> 5)) * ATILE_EL +
                       (size_t)((((f0 >> 3) & 3) * 64 + (p1 & 63)) * 8);
    u16x8 a = *(const u16x8*)&h_hi[el0], b = *(const u16x8*)&h_lo[el0];
    u16x8 c = *(const u16x8*)&h_hi[el1], d = *(const u16x8*)&h_lo[el1];
#pragma unroll
    for (int j = 0; j < 8; ++j) {
      h0[j] = bf16_f(a[j]) + bf16_f(b[j]);
      h1[j] = bf16_f(c[j]) + bf16_f(d[j]);
    }
  }
#pragma unroll
  for (int e2 = 0; e2 < NEXP; ++e2) {
    const float* P0 = P + ((size_t)(e0 * NEXP + e2)) * FDIM + f0;
    const float* P1 = P + ((size_t)(e1 * NEXP + e2)) * FDIM + f0;
    float c = 0.f;
#pragma unroll
    for (int j = 0; j < 8; ++j) c += w0 * h0[j] * P0[j] + w1 * h1[j] * P1[j];
    acc[e2] += c;
  }
#pragma unroll
  for (int e = 0; e < NEXP; ++e) red[e * 256 + tid] = acc[e];
  __syncthreads();
  for (int s = 128; s > 0; s >>= 1) {
    if (tid < s) {
#pragma unroll
      for (int e = 0; e < NEXP; ++e) red[e * 256 + tid] += red[e * 256 + tid + s];
    }
    __syncthreads();
  }
  if (tid == 0) {
    float m1 = -1.f, m2 = -1.f;
    int i1 = 0, i2 = 0;
#pragma unroll
    for (int e = 0; e < NEXP; ++e) {
      float s = fabsf(red[e * 256]);
      if (s > m1) { m2 = m1; i2 = i1; m1 = s; i1 = e; }
      else if (s > m2) { m2 = s; i2 = e; }
    }
    float e2 = __expf(m2 - m1);
    float z = 1.f + e2;
    eidB[t * 2] = i1;
    eidB[t * 2 + 1] = i2;
    wgtB[t * 2] = 1.f / z;
    wgtB[t * 2 + 1] = e2 / z;
  }
}

// ---- SPLIT GEMM body: 64x128 block, 32x64 waves, BK=32, dbuf, counted vmcnt ----
__device__ __forceinline__ void gemm_split_dev(
    unsigned lin, u16* lds, const u16* __restrict__ Ahi, const u16* __restrict__ Alo,
    const u16* __restrict__ Bhi, const u16* __restrict__ Blo,
    u16* __restrict__ OutHi, u16* __restrict__ OutLo,
    const int* __restrict__ cnt, const int* __restrict__ offp, int K, int N) {
  int bx, by, bz;
  swz3<FDIM / 128, RMAX / 64, NEXP>(lin, bx, by, bz);
  const int e = bz;
  const int cp = (cnt[e] + 63) & ~63;
  if (by * 64 >= cp) return;
  const int row0 = offp[e] + by * 64;
  const int n0 = bx * 128;
  const int nkb = K >> 5;
  constexpr int BUF_EL = 12288;

  const int tid = threadIdx.x;
  const int lane = tid & 63;
  const int wid = tid >> 6;
  const int wr = wid >> 1, wc = wid & 1;
  const int lr = lane & 15, kg = lane >> 4;
  const int lo16 = lane << 4;

  f32x4 acc[2][4];
#pragma unroll
  for (int i = 0; i < 2; ++i)
#pragma unroll
    for (int j = 0; j < 4; ++j)
#pragma unroll
      for (int r = 0; r < 4; ++r) acc[i][j][r] = 0.f;

  const size_t abase = (size_t)(row0 >> 6) * nkb;
  const size_t bbase = ((size_t)e * (N >> 7) + (n0 >> 7)) * nkb;

  auto STAGE = [&](int kb, int b) {  // exactly 6 gl16 per wave
    char* d = (char*)(lds + b * BUF_EL);
    const char* gah = (const char*)(Ahi + (abase + kb) * ATILE_EL);
    const char* gal = (const char*)(Alo + (abase + kb) * ATILE_EL);
    const char* gbh = (const char*)(Bhi + (bbase + kb) * BTILE_EL);
    const char* gbl = (const char*)(Blo + (bbase + kb) * BTILE_EL);
    if (wid == 0) {
      gl16(gah + 0 * 1024 + lo16, d + 0 * 1024);
      gl16(gah + 1 * 1024 + lo16, d + 1 * 1024);
      gl16(gah + 2 * 1024 + lo16, d + 2 * 1024);
      gl16(gah + 3 * 1024 + lo16, d + 3 * 1024);
      gl16(gal + 0 * 1024 + lo16, d + 4096 + 0 * 1024);
      gl16(gal + 1 * 1024 + lo16, d + 4096 + 1 * 1024);
    } else if (wid == 1) {
      gl16(gal + 2 * 1024 + lo16, d + 4096 + 2 * 1024);
      gl16(gal + 3 * 1024 + lo16, d + 4096 + 3 * 1024);
      gl16(gbh + 0 * 1024 + lo16, d + 8192 + 0 * 1024);
      gl16(gbh + 1 * 1024 + lo16, d + 8192 + 1 * 1024);
      gl16(gbh + 2 * 1024 + lo16, d + 8192 + 2 * 1024);
      gl16(gbh + 3 * 1024 + lo16, d + 8192 + 3 * 1024);
    } else if (wid == 2) {
      gl16(gbh + 4 * 1024 + lo16, d + 8192 + 4 * 1024);
      gl16(gbh + 5 * 1024 + lo16, d + 8192 + 5 * 1024);
      gl16(gbh + 6 * 1024 + lo16, d + 8192 + 6 * 1024);
      gl16(gbh + 7 * 1024 + lo16, d + 8192 + 7 * 1024);
      gl16(gbl + 0 * 1024 + lo16, d + 16384 + 0 * 1024);
      gl16(gbl + 1 * 1024 + lo16, d + 16384 + 1 * 1024);
    } else {
      gl16(gbl + 2 * 1024 + lo16, d + 16384 + 2 * 1024);
      gl16(gbl + 3 * 1024 + lo16, d + 16384 + 3 * 1024);
      gl16(gbl + 4 * 1024 + lo16, d + 16384 + 4 * 1024);
      gl16(gbl + 5 * 1024 + lo16, d + 16384 + 5 * 1024);
      gl16(gbl + 6 * 1024 + lo16, d + 16384 + 6 * 1024);
      gl16(gbl + 7 * 1024 + lo16, d + 16384 + 7 * 1024);
    }
  };

  STAGE(0, 0);
  int cur = 0;
  for (int kb = 0; kb < nkb; ++kb) {
    const bool pf = (kb + 1 < nkb);
    if (pf) STAGE(kb + 1, cur ^ 1);
    if (pf) { VMCNT(6); } else { VMCNT(0); }
    SB(); BAR(); SB();

    const u16* buf = lds + cur * BUF_EL;
    const u16* AsH = buf;
    const u16* AsL = buf + 2048;
    const u16* BsH = buf + 4096;
    const u16* BsL = buf + 8192;
    const int arow = (kg * 64 + wr * 32 + lr) * 8;
    const int bcol = (kg * 128 + wc * 64 + lr) * 8;

    bf16x8 ah0 = *(const bf16x8*)&AsH[arow];
    bf16x8 ah1 = *(const bf16x8*)&AsH[arow + 128];
    bf16x8 bh[4];
#pragma unroll
    for (int j = 0; j < 4; ++j) bh[j] = *(const bf16x8*)&BsH[bcol + j * 128];
#pragma unroll
    for (int j = 0; j < 4; ++j) {
      acc[0][j] = __builtin_amdgcn_mfma_f32_16x16x32_bf16(ah0, bh[j], acc[0][j], 0, 0, 0);
      acc[1][j] = __builtin_amdgcn_mfma_f32_16x16x32_bf16(ah1, bh[j], acc[1][j], 0, 0, 0);
    }
    bf16x8 al0 = *(const bf16x8*)&AsL[arow];
    bf16x8 al1 = *(const bf16x8*)&AsL[arow + 128];
#pragma unroll
    for (int j = 0; j < 4; ++j) {
      bf16x8 bl = *(const bf16x8*)&BsL[bcol + j * 128];
      acc[0][j] = __builtin_amdgcn_mfma_f32_16x16x32_bf16(ah0, bl, acc[0][j], 0, 0, 0);
      acc[1][j] = __builtin_amdgcn_mfma_f32_16x16x32_bf16(ah1, bl, acc[1][j], 0, 0, 0);
      acc[0][j] = __builtin_amdgcn_mfma_f32_16x16x32_bf16(al0, bh[j], acc[0][j], 0, 0, 0);
      acc[1][j] = __builtin_amdgcn_mfma_f32_16x16x32_bf16(al1, bh[j], acc[1][j], 0, 0, 0);
    }
    SB(); BAR(); SB();
    cur ^= 1;
  }

  const int nkbO = N >> 5;
#pragma unroll
  for (int i = 0; i < 2; ++i) {
#pragma unroll
    for (int j = 0; j < 4; ++j) {
      const int Cj = n0 + wc * 64 + j * 16 + lr;
      f32x4 v = acc[i][j];
#pragma unroll
      for (int r = 0; r < 4; ++r) {
        const int R = row0 + wr * 32 + i * 16 + kg * 4 + r;
        float f = fmaxf(v[r], 0.f);
        const size_t el = ((size_t)(R >> 6) * nkbO + (Cj >> 5)) * ATILE_EL +
                          (size_t)(((Cj >> 3) & 3) * 64 + (R & 63)) * 8 + (Cj & 7);
        u16 h = bf16_rn(f);
        OutHi[el] = h;
        OutLo[el] = bf16_rn(f - bf16_f(h));
      }
    }
  }
}

// ---- PLAIN GEMM body: 128x128 block, 64x64 waves, BK=32, dbuf, counted vmcnt ----
template <int GX, int GY, bool RELU, int OUTMODE>  // OUTMODE 0: f32 row-major; 2: bf16 hi A-tiled
__device__ __forceinline__ void gemm_plain_dev(
    unsigned lin, u16* lds, const u16* __restrict__ Ahi, const u16* __restrict__ Bhi,
    u16* __restrict__ OutHi, float* __restrict__ OutF,
    const int* __restrict__ cnt, const int* __restrict__ offp, int K, int N) {
  int bx, by, bz;
  swz3<GX, GY, NEXP>(lin, bx, by, bz);
  const int e = bz;
  const int cp = (cnt[e] + 63) & ~63;
  if (by * 128 >= cp) return;
  const int row0 = offp[e] + by * 128;
  const int rend = offp[e] + cp;
  const int n0 = bx * 128;
  const int nkb = K >> 5;
  constexpr int BUF_EL = 8192;

  const int tid = threadIdx.x;
  const int lane = tid & 63;
  const int wid = tid >> 6;
  const int wr = wid >> 1, wc = wid & 1;
  const int lr = lane & 15, kg = lane >> 4;
  const int lo16 = lane << 4;

  f32x4 acc[4][4];
#pragma unroll
  for (int i = 0; i < 4; ++i)
#pragma unroll
    for (int j = 0; j < 4; ++j)
#pragma unroll
      for (int r = 0; r < 4; ++r) acc[i][j][r] = 0.f;

  const int at0 = row0 >> 6;
  const size_t bbase = ((size_t)e * (N >> 7) + (n0 >> 7)) * nkb;

  auto STAGE = [&](int kb, int b) {  // exactly 4 gl16 per wave
    char* d = (char*)(lds + b * BUF_EL);
    if (wid < 2) {
      const char* g = (const char*)(Ahi + ((size_t)(at0 + wid) * nkb + kb) * ATILE_EL);
      gl16(g + 0 * 1024 + lo16, d + wid * 4096 + 0 * 1024);
      gl16(g + 1 * 1024 + lo16, d + wid * 4096 + 1 * 1024);
      gl16(g + 2 * 1024 + lo16, d + wid * 4096 + 2 * 1024);
      gl16(g + 3 * 1024 + lo16, d + wid * 4096 + 3 * 1024);
    } else {
      const char* g = (const char*)(Bhi + (bbase + kb) * BTILE_EL) + (wid - 2) * 4096;
      gl16(g + 0 * 1024 + lo16, d + 8192 + (wid - 2) * 4096 + 0 * 1024);
      gl16(g + 1 * 1024 + lo16, d + 8192 + (wid - 2) * 4096 + 1 * 1024);
      gl16(g + 2 * 1024 + lo16, d + 8192 + (wid - 2) * 4096 + 2 * 1024);
      gl16(g + 3 * 1024 + lo16, d + 8192 + (wid - 2) * 4096 + 3 * 1024);
    }
  };

  STAGE(0, 0);
  int cur = 0;
  for (int kb = 0; kb < nkb; ++kb) {
    const bool pf = (kb + 1 < nkb);
    if (pf) STAGE(kb + 1, cur ^ 1);
    if (pf) { VMCNT(4); } else { VMCNT(0); }
    SB(); BAR(); SB();

    const u16* buf = lds + cur * BUF_EL;
    const u16* AsH = buf + wr * 2048;
    const u16* BsH = buf + 4096;
    const int arow = (kg * 64 + lr) * 8;
    const int bcol = (kg * 128 + wc * 64 + lr) * 8;

    bf16x8 ah[4], bh[4];
#pragma unroll
    for (int i = 0; i < 4; ++i) ah[i] = *(const bf16x8*)&AsH[arow + i * 128];
#pragma unroll
    for (int j = 0; j < 4; ++j) bh[j] = *(const bf16x8*)&BsH[bcol + j * 128];
#pragma unroll
    for (int i = 0; i < 4; ++i)
#pragma unroll
      for (int j = 0; j < 4; ++j)
        acc[i][j] = __builtin_amdgcn_mfma_f32_16x16x32_bf16(ah[i], bh[j], acc[i][j], 0, 0, 0);
    SB(); BAR(); SB();
    cur ^= 1;
  }

  const int nkbO = N >> 5;
#pragma unroll
  for (int i = 0; i < 4; ++i) {
#pragma unroll
    for (int j = 0; j < 4; ++j) {
      const int Cj = n0 + wc * 64 + j * 16 + lr;
      f32x4 v = acc[i][j];
#pragma unroll
      for (int r = 0; r < 4; ++r) {
        const int R = row0 + wr * 64 + i * 16 + kg * 4 + r;
        if (R >= rend) continue;
        float f = v[r];
        if (RELU) f = fmaxf(f, 0.f);
        if constexpr (OUTMODE == 0) {
          OutF[(size_t)R * N + Cj] = f;
        } else {
          const size_t el = ((size_t)(R >> 6) * nkbO + (Cj >> 5)) * ATILE_EL +
                            (size_t)(((Cj >> 3) & 3) * 64 + (R & 63)) * 8 + (Cj & 7);
          OutHi[el] = bf16_rn(f);
        }
      }
    }
  }
}

__device__ __forceinline__ void compact_dev(
    const int* __restrict__ eid, int* __restrict__ cnt, int* __restrict__ offp,
    int* __restrict__ row2token, int* __restrict__ pos, int* lcnt) {
  int* s_off = lcnt + NEXP * 256;
  int* s_tot = s_off + NEXP;
  const int tid = threadIdx.x;
  const int base = tid * 16;
  int my[16];
#pragma unroll
  for (int i = 0; i < 4; ++i)
    *(int4*)&my[i * 4] = *(const int4*)(eid + base + i * 4);
#pragma unroll
  for (int e = 0; e < NEXP; ++e) {
    int c = 0;
#pragma unroll
    for (int i = 0; i < 16; ++i) c += (my[i] == e) ? 1 : 0;
    lcnt[e * 256 + tid] = c;
  }
  for (int r = tid; r < RMAX; r += 256) row2token[r] = -1;
  __syncthreads();
  if (tid < NEXP) {
    int run = 0;
    for (int i = 0; i < 256; ++i) {
      int v = lcnt[tid * 256 + i];
      lcnt[tid * 256 + i] = run;
      run += v;
    }
    s_tot[tid] = run;
  }
  __syncthreads();
  if (tid == 0) {
    int o = 0;
    for (int e = 0; e < NEXP; ++e) {
      s_off[e] = o;
      o += (s_tot[e] + BMPAD - 1) & ~(BMPAD - 1);
    }
  }
  __syncthreads();
  int myoff[NEXP];
#pragma unroll
  for (int e = 0; e < NEXP; ++e) myoff[e] = s_off[e] + lcnt[e * 256 + tid];
#pragma unroll
  for (int i = 0; i < 16; ++i) {
    int r = 0;
#pragma unroll
    for (int e = 0; e < NEXP; ++e) r = (my[i] == e) ? myoff[e] : r;
    row2token[r] = (base + i) >> 1;
    pos[base + i] = r;
#pragma unroll
    for (int e = 0; e < NEXP; ++e) myoff[e] += (my[i] == e) ? 1 : 0;
  }
  if (tid < NEXP) {
    cnt[tid] = s_tot[tid];
    offp[tid] = s_off[tid];
  }
}

// ================= global kernels =================

// K1: route (2048) | wconv_p W2l0->W2A (4096) | wconv W1l0 hi+lo (4096)
__global__ __launch_bounds__(256) void fusedK1_kernel(
    const float* __restrict__ xin, const float* __restrict__ protos,
    int* __restrict__ eidA, float* __restrict__ wgtA,
    const float* __restrict__ W2, u16* __restrict__ W2A,
    const float* __restrict__ proto2, float* __restrict__ Ppart,
    const float* __restrict__ W1, u16* __restrict__ W_hi, u16* __restrict__ W_lo) {
  __shared__ float smem[32 * WLDP + 8 * 128];
  const unsigned lin = blockIdx.x;
  if (lin < 2048u) {
    route_dev((int)lin, xin, protos, eidA, wgtA, smem);
  } else if (lin < 6144u) {
    const unsigned l2 = lin - 2048u;
    wconv_p_dev(l2 % 8, (l2 / 8) % 64, l2 / 512, W2, W2A, proto2, Ppart,
                FDIM, DDIM, smem);
  } else {
    const unsigned l3 = lin - 6144u;
    wconv_dev<true>(l3 % 16, (l3 / 16) % 32, l3 / 512, W1, W_hi, W_lo,
                    DDIM, FDIM, smem);
  }
}

__global__ __launch_bounds__(256) void compact_kernel(
    const int* __restrict__ eid, int* __restrict__ cnt, int* __restrict__ offp,
    int* __restrict__ row2token, int* __restrict__ pos) {
  __shared__ int lcnt[NEXP * 256 + 16];
  compact_dev(eid, cnt, offp, row2token, pos, lcnt);
}

// K3: gather hi+lo (4608) | reduce_p (512)
__global__ __launch_bounds__(256) void fusedK3_kernel(
    const float* __restrict__ xin, const int* __restrict__ row2token,
    u16* __restrict__ Ag_hi, u16* __restrict__ Ag_lo,
    const float* __restrict__ Ppart, float* __restrict__ P) {
  const unsigned lin = blockIdx.x;
  if (lin < (unsigned)RMAX) {
    gather_dev<true>((int)lin, xin, row2token, Ag_hi, Ag_lo);
  } else {
    const int i = (int)(lin - RMAX) * 256 + threadIdx.x;
    float s = 0.f;
#pragma unroll
    for (int nb = 0; nb < 8; ++nb) s += Ppart[(size_t)nb * (NEXP * NEXP * FDIM) + i];
    P[i] = s;
  }
}

// C2: pure split GEMM1-l0 (9216 blocks), 48 KB LDS, 3 blocks/CU
__global__ __launch_bounds__(256, 3) void fusedC2_kernel(
    const u16* __restrict__ Ag_hi, const u16* __restrict__ Ag_lo,
    const u16* __restrict__ W_hi, const u16* __restrict__ W_lo,
    u16* __restrict__ h_hi, u16* __restrict__ h_lo,
    const int* __restrict__ cnt, const int* __restrict__ offp) {
  __shared__ u16 lds[2 * 12288];  // 48 KB
  gemm_split_dev(blockIdx.x, lds, Ag_hi, Ag_lo, W_hi, W_lo, h_hi, h_lo, cnt, offp,
                 DDIM, FDIM);
}

// C3: gemm_plain GEMM2-l0 (2304) | wconv W1l1->W_lo (4096) | wconv W2l1->W_hi (4096)
//   | route2 (2048)
__global__ __launch_bounds__(256, 4) void fusedC3_kernel(
    const u16* __restrict__ h_hi, const u16* __restrict__ h_lo,
    const u16* __restrict__ W2A,
    float* __restrict__ part, const int* __restrict__ cnt, const int* __restrict__ offp,
    const float* __restrict__ W1b, u16* __restrict__ W_lo,
    const float* __restrict__ W2b, u16* __restrict__ W_hi,
    const float* __restrict__ xin, const float* __restrict__ protos2,
    const float* __restrict__ P, const int* __restrict__ eidA,
    const int* __restrict__ posA, const float* __restrict__ wgtA,
    int* __restrict__ eidB, float* __restrict__ wgtB) {
  __shared__ u16 lds[2 * 8192];  // 32 KB (covers wconv 16.9 KB / route2 8 KB)
  const unsigned lin = blockIdx.x;
  if (lin < 2304u) {
    gemm_plain_dev<DDIM / 128, RMAX / 128, false, 0>(
        lin, lds, h_hi, W2A, nullptr, part, cnt, offp, FDIM, DDIM);
  } else if (lin < 6400u) {
    const unsigned l2 = lin - 2304u;
    wconv_dev<false>(l2 % 16, (l2 / 16) % 32, l2 / 512, W1b, W_lo, nullptr,
                     DDIM, FDIM, (float*)lds);
  } else if (lin < 10496u) {
    const unsigned l2 = lin - 6400u;
    wconv_dev<false>(l2 % 8, (l2 / 8) % 64, l2 / 512, W2b, W_hi, nullptr,
                     FDIM, DDIM, (float*)lds);
  } else {
    route2_dev((int)(lin - 10496u), xin, protos2, h_hi, h_lo, P, eidA, posA, wgtA,
               eidB, wgtB, (float*)lds);
  }
}

// D: apply layer-0 (xcur = xin + w.y; 2048) | compact B (1)
__global__ __launch_bounds__(256) void fusedD_kernel(
    const float* __restrict__ part, const int* __restrict__ pos,
    const float* __restrict__ wgt, const float* __restrict__ xin,
    float* __restrict__ xcur,
    const int* __restrict__ eidB, int* __restrict__ cnt, int* __restrict__ offp,
    int* __restrict__ row2token, int* __restrict__ posB) {
  __shared__ int lcnt[NEXP * 256 + 16];
  const unsigned lin = blockIdx.x;
  if (lin < 2048u) {
    const int t = lin;
    const int c = threadIdx.x * 4;
    const int p0 = pos[t * 2], p1 = pos[t * 2 + 1];
    const float w0 = wgt[t * 2], w1 = wgt[t * 2 + 1];
    float4 xa = *(const float4*)(xin + (size_t)t * DDIM + c);
    const float4 y0 = *(const float4*)(part + (size_t)p0 * DDIM + c);
    const float4 y1 = *(const float4*)(part + (size_t)p1 * DDIM + c);
    xa.x += w0 * y0.x + w1 * y1.x;
    xa.y += w0 * y0.y + w1 * y1.y;
    xa.z += w0 * y0.z + w1 * y1.z;
    xa.w += w0 * y0.w + w1 * y1.w;
    *(float4*)(xcur + (size_t)t * DDIM + c) = xa;
  } else {
    compact_dev(eidB, cnt, offp, row2token, posB, lcnt);
  }
}

__global__ __launch_bounds__(256) void gather_kernel(
    const float* __restrict__ x, const int* __restrict__ row2token,
    u16* __restrict__ Ahi) {
  gather_dev<false>(blockIdx.x, x, row2token, Ahi, nullptr);
}

template <int GX, bool RELU, int OUTMODE>
__global__ __launch_bounds__(256, 4) void gemm_plain_kernel(
    const u16* __restrict__ Ahi, const u16* __restrict__ Bhi,
    u16* __restrict__ OutHi, float* __restrict__ OutF,
    const int* __restrict__ cnt, const int* __restrict__ offp, int K, int N) {
  __shared__ u16 lds[2 * 8192];
  gemm_plain_dev<GX, RMAX / 128, RELU, OUTMODE>(blockIdx.x, lds, Ahi, Bhi, OutHi,
                                                OutF, cnt, offp, K, N);
}

__global__ __launch_bounds__(256) void apply_kernel(
    const float* __restrict__ part, const int* __restrict__ pos,
    const float* __restrict__ wgt, float* __restrict__ x) {
  const int t = blockIdx.x;
  const int c = threadIdx.x * 4;
  const int p0 = pos[t * 2], p1 = pos[t * 2 + 1];
  const float w0 = wgt[t * 2], w1 = wgt[t * 2 + 1];
  float4 xa = *(float4*)(x + (size_t)t * DDIM + c);
  const float4 y0 = *(const float4*)(part + (size_t)p0 * DDIM + c);
  const float4 y1 = *(const float4*)(part + (size_t)p1 * DDIM + c);
  xa.x += w0 * y0.x + w1 * y1.x;
  xa.y += w0 * y0.y + w1 * y1.y;
  xa.z += w0 * y0.z + w1 * y1.z;
  xa.w += w0 * y0.w + w1 * y1.w;
  *(float4*)(x + (size_t)t * DDIM + c) = xa;
}

extern "C" void kernel_launch(void* const* d_in, const int* in_sizes, int n_in,
                              void* d_out, int out_size, void* d_ws, size_t ws_size,
                              hipStream_t stream) {
  const float* xin = (const float*)d_in[0];
  const float* protos = (const float*)d_in[1];
  const float* W1 = (const float*)d_in[2];
  const float* W2 = (const float*)d_in[3];
  float* xcur = (float*)d_out;

  u16* W_hi = (u16*)d_ws;
  u16* W_lo = W_hi + (size_t)NEXP * DDIM * FDIM;
  u16* W2A = W_lo + (size_t)NEXP * DDIM * FDIM;
  u16* Ag_hi = W2A + (size_t)NEXP * DDIM * FDIM;
  u16* Ag_lo = Ag_hi + (size_t)RALLOC * DDIM;
  u16* h_hi = Ag_lo + (size_t)RALLOC * DDIM;
  u16* h_lo = h_hi + (size_t)RALLOC * FDIM;
  float* part = (float*)(h_lo + (size_t)RALLOC * FDIM);
  float* Ppart = part + (size_t)RALLOC * DDIM;
  float* P = Ppart + (size_t)8 * NEXP * NEXP * FDIM;
  float* wgtA = P + (size_t)NEXP * NEXP * FDIM;
  float* wgtB = wgtA + T_TOKENS * 2;
  int* eidA = (int*)(wgtB + T_TOKENS * 2);
  int* eidB = eidA + T_TOKENS * 2;
  int* posA = eidB + T_TOKENS * 2;
  int* posB = posA + T_TOKENS * 2;
  int* cnt = posB + T_TOKENS * 2;
  int* offp = cnt + NEXP;
  int* row2token = offp + NEXP;

  const float* protos2 = protos + (size_t)NEXP * DDIM;
  const float* W1b = W1 + (size_t)NEXP * DDIM * FDIM;
  const float* W2b = W2 + (size_t)NEXP * FDIM * DDIM;

  // ---------------- layer 0 ----------------
  fusedK1_kernel<<<2048 + 4096 + 4096, 256, 0, stream>>>(
      xin, protos, eidA, wgtA, W2, W2A, protos2, Ppart, W1, W_hi, W_lo);
  compact_kernel<<<1, 256, 0, stream>>>(eidA, cnt, offp, row2token, posA);
  fusedK3_kernel<<<RMAX + 512, 256, 0, stream>>>(
      xin, row2token, Ag_hi, Ag_lo, Ppart, P);
  fusedC2_kernel<<<(FDIM / 128) * (RMAX / 64) * NEXP, 256, 0, stream>>>(
      Ag_hi, Ag_lo, W_hi, W_lo, h_hi, h_lo, cnt, offp);
  fusedC3_kernel<<<2304 + 4096 + 4096 + 2048, 256, 0, stream>>>(
      h_hi, h_lo, W2A, part, cnt, offp, W1b, W_lo, W2b, W_hi,
      xin, protos2, P, eidA, posA, wgtA, eidB, wgtB);
  fusedD_kernel<<<2048 + 1, 256, 0, stream>>>(
      part, posA, wgtA, xin, xcur, eidB, cnt, offp, row2token, posB);

  // ---------------- layer 1 (all plain bf16; W1l1=W_lo, W2l1=W_hi) ----------------
  gather_kernel<<<RMAX, 256, 0, stream>>>(xcur, row2token, Ag_hi);
  gemm_plain_kernel<FDIM / 128, true, 2>
      <<<(FDIM / 128) * (RMAX / 128) * NEXP, 256, 0, stream>>>(
          Ag_hi, W_lo, h_hi, nullptr, cnt, offp, DDIM, FDIM);
  gemm_plain_kernel<DDIM / 128, false, 0>
      <<<(DDIM / 128) * (RMAX / 128) * NEXP, 256, 0, stream>>>(
          h_hi, W_hi, nullptr, part, cnt, offp, FDIM, DDIM);
  apply_kernel<<<T_TOKENS, 256, 0, stream>>>(part, posB, wgtB, xcur);
}